// Round 1
// baseline (1037.376 us; speedup 1.0000x reference)
//
#include <hip/hip_runtime.h>
#include <math.h>

// Problem constants (from reference): T=4096, IN=512, K=64, V=64, H=4096
#define T_DIM 4096
#define IN_DIM 512
#define K_DIM 64
#define V_DIM 64
#define H_DIM 4096
#define CHUNKS 256
#define CLEN 16   // T_DIM / CHUNKS

typedef __attribute__((ext_vector_type(8))) short short8;  // 8 bf16 = 4 VGPRs
typedef __attribute__((ext_vector_type(4))) float f32x4;

// ---------------- activations ----------------
__device__ __forceinline__ float phi_act(float v){
    return v > 0.f ? (v + 1.f) : (expm1f(v) + 1.f);
}
__device__ __forceinline__ float mish_act(float v){
    float sp = fmaxf(v, 0.f) + log1pf(expf(-fabsf(v)));
    return v * tanhf(sp);
}
// fp32 -> bf16 round-to-nearest-even (bit trick)
__device__ __forceinline__ unsigned short f2bf(float f){
    union { float f; unsigned int u; } x; x.f = f;
    unsigned int u = x.u + 0x7fffu + ((x.u >> 16) & 1u);
    return (unsigned short)(u >> 16);
}

// async 16B global->LDS (dest = wave-uniform base + lane*16; layout must be contiguous per lane)
__device__ __forceinline__ void async16(const unsigned short* g, unsigned short* l){
    __builtin_amdgcn_global_load_lds(
        (const __attribute__((address_space(1))) unsigned int*)g,
        (__attribute__((address_space(3))) unsigned int*)l,
        16, 0, 0);
}

// ---------------- fp32 -> bf16 conversion, 4 elems/thread ----------------
__global__ __launch_bounds__(256) void cvt_bf16(const float* __restrict__ in,
                                                unsigned short* __restrict__ out, int n4){
    int i = blockIdx.x * 256 + threadIdx.x;
    if (i >= n4) return;
    float4 v = ((const float4*)in)[i];
    ushort4 o;
    o.x = f2bf(v.x); o.y = f2bf(v.y); o.z = f2bf(v.z); o.w = f2bf(v.w);
    ((ushort4*)out)[i] = o;
}

// ---------------- bf16 MFMA GEMM (128x128 tile, m97 structure) ----------------
// Kept for the small-K GEMM1 (K=64). See previous round for details.
__global__ __launch_bounds__(256) void gemm_mfma_bt(
    const unsigned short* __restrict__ A0, const unsigned short* __restrict__ B0, int K0,
    const unsigned short* __restrict__ A1, const unsigned short* __restrict__ B1, int K1,
    const float* __restrict__ bias0, const float* __restrict__ bias1,
    void* __restrict__ Y, int N, int act, int out_bf16)
{
    constexpr int BK = 64;
    __shared__ unsigned short As[128 * BK];
    __shared__ unsigned short Bs[128 * BK];
    const int tid  = threadIdx.x;
    const int lane = tid & 63;
    const int wm   = (tid >> 6 & 1) * 64;     // wave m-offset in tile
    const int wn   = (tid >> 7) * 64;         // wave n-offset in tile
    const int bm   = blockIdx.x * 128;
    const int bn   = blockIdx.y * 128;
    const int l15  = lane & 15;
    const int quad = lane >> 4;

    f32x4 acc[4][4] = {};

    for (int seg = 0; seg < 2; ++seg){
        const unsigned short* A = seg ? A1 : A0;
        const unsigned short* B = seg ? B1 : B0;
        const int Kd = seg ? K1 : K0;
        if (Kd <= 0 || A == nullptr) continue;
        for (int k0 = 0; k0 < Kd; k0 += BK){
            __syncthreads();  // previous tile's ds_reads must drain before restage
            #pragma unroll
            for (int it = 0; it < 4; ++it){   // 1024 chunks of 16B per matrix, 4 per thread
                const int c  = it * 256 + tid;        // LDS chunk index (byte off = c*16)
                const int r  = c >> 3;                // row 0..127
                const int kc = (c & 7) ^ (r & 7);     // swizzled global k-chunk
                async16(A + (size_t)(bm + r) * Kd + k0 + kc * 8, &As[c * 8]);
            }
            #pragma unroll
            for (int it = 0; it < 4; ++it){
                const int c  = it * 256 + tid;
                const int r  = c >> 3;
                const int kc = (c & 7) ^ (r & 7);
                async16(B + (size_t)(bn + r) * Kd + k0 + kc * 8, &Bs[c * 8]);
            }
            __syncthreads();  // s_waitcnt vmcnt(0) before s_barrier -> staging complete
            #pragma unroll
            for (int ks = 0; ks < 2; ++ks){
                short8 af[4], bf[4];
                #pragma unroll
                for (int mi = 0; mi < 4; ++mi){
                    const int row = wm + mi * 16 + l15;
                    const int kq  = ks * 4 + quad;            // k-chunk 0..7
                    af[mi] = *(const short8*)&As[(row * 8 + (kq ^ (row & 7))) * 8];
                }
                #pragma unroll
                for (int ni = 0; ni < 4; ++ni){
                    const int row = wn + ni * 16 + l15;
                    const int kq  = ks * 4 + quad;
                    bf[ni] = *(const short8*)&Bs[(row * 8 + (kq ^ (row & 7))) * 8];
                }
                #pragma unroll
                for (int mi = 0; mi < 4; ++mi)
                    #pragma unroll
                    for (int ni = 0; ni < 4; ++ni)
                        acc[mi][ni] = __builtin_amdgcn_mfma_f32_16x16x32_bf16(
                            af[mi], bf[ni], acc[mi][ni], 0, 0, 0);
            }
        }
    }

    // epilogue: C/D mapping col=lane&15, row=quad*4+reg
    #pragma unroll
    for (int ni = 0; ni < 4; ++ni){
        const int col = bn + wn + ni * 16 + l15;
        float bb = 0.f;
        if (bias0) bb += bias0[col];
        if (bias1) bb += bias1[col];
        #pragma unroll
        for (int mi = 0; mi < 4; ++mi){
            #pragma unroll
            for (int r = 0; r < 4; ++r){
                const int row = bm + wm + mi * 16 + quad * 4 + r;
                float v = acc[mi][ni][r] + bb;
                if (act == 2) v = mish_act(v);
                if (out_bf16) ((unsigned short*)Y)[(size_t)row * N + col] = f2bf(v);
                else          ((float*)Y)[(size_t)row * N + col] = v;
            }
        }
    }
}

// ---------------- 256x256 pipelined bf16 MFMA GEMM (counted-vmcnt, T2+T3/T4+T5) ----------------
// BM=BN=256, BK=64. 512 threads = 8 waves as 2(M)x4(N); per-wave output 128x64
// (8x4 fragments of mfma_f32_16x16x32_bf16, acc = 128 VGPR). LDS = 2 K-tile
// double-buffers x (A 256x64 + B 256x64) bf16 = 128 KiB -> 1 block/CU, grid 16x16 = 256
// blocks = whole grid co-resident.
//
// Schedule (race-safe by construction):
//   prologue: stage(tile0->buf0); stage(tile1->buf1); s_waitcnt vmcnt(8); s_barrier
//   loop t:   4 quadrant phases reading buf[t&1]:
//                {ds_read frags; s_barrier; setprio(1); 16 MFMA; setprio(0); s_barrier}
//             after last phase barrier (all waves' reads of buf[t&1] drained):
//                stage(tile t+2 -> buf[t&1]);  s_waitcnt vmcnt(8);  s_barrier
//   vmcnt(8) leaves tile t+2's 8 loads IN FLIGHT across the barrier (never drains to 0
//   in steady state) while guaranteeing tile t+1 has landed for this wave; the raw
//   s_barrier (no implicit vmcnt(0), unlike __syncthreads) then makes it visible to all.
// LDS XOR-swizzle identical to the proven 128x128 kernel (slot s of row r holds global
// k-chunk s^(r&7); source-side pre-swizzle keeps global_load_lds's linear lane->LDS map).
__global__ __launch_bounds__(512, 2) void gemm256(
    const unsigned short* __restrict__ A, const unsigned short* __restrict__ B, int Kd,
    const float* __restrict__ bias,
    void* __restrict__ Y, int N, int act, int out_bf16, int accum)
{
    constexpr int BK = 64;
    __shared__ unsigned short As[2][256 * BK];   // 2 x 32 KiB
    __shared__ unsigned short Bs[2][256 * BK];   // 2 x 32 KiB
    const int tid  = threadIdx.x;
    const int lane = tid & 63;
    const int w    = tid >> 6;          // wave 0..7
    const int wr   = w >> 2;            // 0..1  (M half)
    const int wc   = w & 3;             // 0..3  (N quarter)
    const int bm   = blockIdx.x * 256;
    const int bn   = blockIdx.y * 256;
    const int l15  = lane & 15;
    const int quad = lane >> 4;
    const int NT   = Kd / BK;

    f32x4 acc[8][4] = {};

    // stage one K-tile (A + B, 64 KiB) into buffer bi: 8 x global_load_lds(16B)/thread
    auto stage = [&](int kt, int bi){
        const int k0 = kt * BK;
        #pragma unroll
        for (int it = 0; it < 4; ++it){
            const int c  = it * 512 + tid;        // chunk 0..2047 (16B units)
            const int r  = c >> 3;                // row 0..255
            const int kc = (c & 7) ^ (r & 7);     // swizzled global k-chunk
            async16(A + (size_t)(bm + r) * Kd + k0 + kc * 8, &As[bi][c * 8]);
        }
        #pragma unroll
        for (int it = 0; it < 4; ++it){
            const int c  = it * 512 + tid;
            const int r  = c >> 3;
            const int kc = (c & 7) ^ (r & 7);
            async16(B + (size_t)(bn + r) * Kd + k0 + kc * 8, &Bs[bi][c * 8]);
        }
    };

    stage(0, 0);
    if (NT > 1){
        stage(1, 1);
        asm volatile("s_waitcnt vmcnt(8)" ::: "memory");   // tile 0 landed; tile 1 in flight
    } else {
        asm volatile("s_waitcnt vmcnt(0)" ::: "memory");
    }
    __builtin_amdgcn_s_barrier();

    for (int t = 0; t < NT; ++t){
        const unsigned short* as = As[t & 1];
        const unsigned short* bs = Bs[t & 1];
        short8 bf[4][2];
        #pragma unroll
        for (int q = 0; q < 4; ++q){
            if (q == 0){
                #pragma unroll
                for (int ni = 0; ni < 4; ++ni)
                    #pragma unroll
                    for (int ks = 0; ks < 2; ++ks){
                        const int row = wc * 64 + ni * 16 + l15;
                        const int kq  = ks * 4 + quad;
                        bf[ni][ks] = *(const short8*)&bs[(row * 8 + (kq ^ (row & 7))) * 8];
                    }
            }
            short8 af[2][2];
            #pragma unroll
            for (int mi2 = 0; mi2 < 2; ++mi2)
                #pragma unroll
                for (int ks = 0; ks < 2; ++ks){
                    const int row = wr * 128 + (q * 2 + mi2) * 16 + l15;
                    const int kq  = ks * 4 + quad;
                    af[mi2][ks] = *(const short8*)&as[(row * 8 + (kq ^ (row & 7))) * 8];
                }
            __builtin_amdgcn_s_barrier();          // phase alignment (role-split for setprio)
            __builtin_amdgcn_s_setprio(1);
            #pragma unroll
            for (int mi2 = 0; mi2 < 2; ++mi2)
                #pragma unroll
                for (int ni = 0; ni < 4; ++ni)
                    #pragma unroll
                    for (int ks = 0; ks < 2; ++ks)
                        acc[q * 2 + mi2][ni] = __builtin_amdgcn_mfma_f32_16x16x32_bf16(
                            af[mi2][ks], bf[ni][ks], acc[q * 2 + mi2][ni], 0, 0, 0);
            __builtin_amdgcn_s_setprio(0);
            __builtin_amdgcn_s_barrier();          // all waves done with this phase's frags
        }
        // after the phase-3 trailing barrier every wave's reads of buf[t&1] have drained
        if (t + 1 < NT){
            if (t + 2 < NT){
                stage(t + 2, t & 1);                              // overwrite the dead buffer
                asm volatile("s_waitcnt vmcnt(8)" ::: "memory");  // t+1 landed; t+2 in flight
            } else {
                asm volatile("s_waitcnt vmcnt(0)" ::: "memory");  // drain last prefetch
            }
            __builtin_amdgcn_s_barrier();
        }
    }

    // epilogue: C/D mapping col=lane&15, row=quad*4+reg
    #pragma unroll
    for (int ni = 0; ni < 4; ++ni){
        const int col = bn + wc * 64 + ni * 16 + l15;
        const float bb = bias ? bias[col] : 0.f;
        #pragma unroll
        for (int mi = 0; mi < 8; ++mi){
            #pragma unroll
            for (int r = 0; r < 4; ++r){
                const int row = bm + wr * 128 + mi * 16 + quad * 4 + r;
                float v = acc[mi][ni][r] + bb;
                if (act == 2) v = mish_act(v);
                if (out_bf16) ((unsigned short*)Y)[(size_t)row * N + col] = f2bf(v);
                else {
                    float* yp = (float*)Y + (size_t)row * N + col;
                    *yp = accum ? (*yp + v) : v;
                }
            }
        }
    }
}

// ---------------- fp32 GEMM (small projections):  Y = act(x @ W^T [+ bias]) ----------------
__global__ __launch_bounds__(256) void gemm_xwt(
    const float* __restrict__ A0, const float* __restrict__ B0, int K0,
    const float* __restrict__ bias0,
    float* __restrict__ Y, int N, int act)
{
    __shared__ float As[16][68];
    __shared__ float Bs[16][68];
    const int tid  = threadIdx.x;
    const int bm   = blockIdx.x * 64;
    const int bn   = blockIdx.y * 64;
    const int lrow = tid >> 2;
    const int lk4  = (tid & 3) * 4;
    const int tm   = (tid >> 4) * 4;
    const int tn   = (tid & 15) * 4;
    float acc[4][4] = {};

    const float* aptr = A0 + (size_t)(bm + lrow) * K0 + lk4;
    const float* bptr = B0 + (size_t)(bn + lrow) * K0 + lk4;
    for (int k0 = 0; k0 < K0; k0 += 16){
        const float4 av = *(const float4*)(aptr + k0);
        const float4 bv = *(const float4*)(bptr + k0);
        __syncthreads();
        As[lk4+0][lrow]=av.x; As[lk4+1][lrow]=av.y; As[lk4+2][lrow]=av.z; As[lk4+3][lrow]=av.w;
        Bs[lk4+0][lrow]=bv.x; Bs[lk4+1][lrow]=bv.y; Bs[lk4+2][lrow]=bv.z; Bs[lk4+3][lrow]=bv.w;
        __syncthreads();
        #pragma unroll
        for (int kk = 0; kk < 16; ++kk){
            const float4 a = *(const float4*)&As[kk][tm];
            const float4 b = *(const float4*)&Bs[kk][tn];
            acc[0][0] += a.x*b.x; acc[0][1] += a.x*b.y; acc[0][2] += a.x*b.z; acc[0][3] += a.x*b.w;
            acc[1][0] += a.y*b.x; acc[1][1] += a.y*b.y; acc[1][2] += a.y*b.z; acc[1][3] += a.y*b.w;
            acc[2][0] += a.z*b.x; acc[2][1] += a.z*b.y; acc[2][2] += a.z*b.z; acc[2][3] += a.z*b.w;
            acc[3][0] += a.w*b.x; acc[3][1] += a.w*b.y; acc[3][2] += a.w*b.z; acc[3][3] += a.w*b.w;
        }
    }
    float badd[4] = {0.f, 0.f, 0.f, 0.f};
    if (bias0){
        badd[0] = bias0[bn+tn+0]; badd[1] = bias0[bn+tn+1];
        badd[2] = bias0[bn+tn+2]; badd[3] = bias0[bn+tn+3];
    }
    #pragma unroll
    for (int i = 0; i < 4; ++i){
        float r0 = acc[i][0] + badd[0];
        float r1 = acc[i][1] + badd[1];
        float r2 = acc[i][2] + badd[2];
        float r3 = acc[i][3] + badd[3];
        if (act == 1){ r0 = phi_act(r0); r1 = phi_act(r1); r2 = phi_act(r2); r3 = phi_act(r3); }
        *(float4*)&Y[(size_t)(bm + tm + i) * N + bn + tn] = make_float4(r0, r1, r2, r3);
    }
}

// ---------------- segmented scan, pass A ----------------
__global__ __launch_bounds__(256) void scan_passA(
    const float* __restrict__ kbuf, const float* __restrict__ vbuf,
    const int* __restrict__ start,
    float* __restrict__ chunkS, float* __restrict__ chunkZ, int* __restrict__ chunkFlag)
{
    const int c   = blockIdx.x;
    const int tid = threadIdx.x;
    const int j   = tid >> 2;
    const int i0  = (tid & 3) * 16;
    __shared__ float k_lds[64], v_lds[64];
    float s_loc[16];
    #pragma unroll
    for (int e = 0; e < 16; ++e) s_loc[e] = 0.f;
    float z_loc = 0.f;
    int flag = 0;
    const int t0 = c * CLEN;
    for (int tt = 0; tt < CLEN; ++tt){
        const int t = t0 + tt;
        if (tid < 64)       k_lds[tid]      = kbuf[(size_t)t*K_DIM + tid];
        else if (tid < 128) v_lds[tid - 64] = vbuf[(size_t)t*V_DIM + tid - 64];
        __syncthreads();
        const int st = start[t];
        if (st){
            #pragma unroll
            for (int e = 0; e < 16; ++e) s_loc[e] = 0.f;
            z_loc = 0.f;
            flag = 1;
        }
        const float vj = v_lds[j];
        #pragma unroll
        for (int e = 0; e < 16; ++e) s_loc[e] += k_lds[i0 + e] * vj;
        if (tid < 64) z_loc += k_lds[tid];
        __syncthreads();
    }
    #pragma unroll
    for (int e = 0; e < 16; ++e) chunkS[(size_t)c*4096 + (i0 + e)*64 + j] = s_loc[e];
    if (tid < 64) chunkZ[c*64 + tid] = z_loc;
    if (tid == 0) chunkFlag[c] = flag;
}

// ---------------- pass B: exclusive cross-chunk combine ----------------
__global__ __launch_bounds__(256) void scan_passB(
    const float* __restrict__ chunkS, const float* __restrict__ chunkZ, const int* __restrict__ chunkFlag,
    const float* __restrict__ s0, const float* __restrict__ z0,
    float* __restrict__ carryS, float* __restrict__ carryZ)
{
    const int ij = blockIdx.x * 256 + threadIdx.x;
    float e = s0[ij];
    for (int c = 0; c < CHUNKS; ++c){
        carryS[(size_t)c*4096 + ij] = e;
        const int f   = chunkFlag[c];
        const float s = chunkS[(size_t)c*4096 + ij];
        e = f ? s : (e + s);
    }
    if (ij < 64){
        float ez = z0[ij];
        for (int c = 0; c < CHUNKS; ++c){
            carryZ[c*64 + ij] = ez;
            const int f   = chunkFlag[c];
            const float z = chunkZ[c*64 + ij];
            ez = f ? z : (ez + z);
        }
    }
}

// ---------------- pass C: replay with carry; emit s[t], z[t], att out (bf16) ----------------
__global__ __launch_bounds__(256) void scan_passC(
    const float* __restrict__ kbuf, const float* __restrict__ vbuf, const float* __restrict__ qbuf,
    const int* __restrict__ start,
    const float* __restrict__ carryS, const float* __restrict__ carryZ,
    float* __restrict__ s_out, float* __restrict__ z_out, unsigned short* __restrict__ attout)
{
    const int c   = blockIdx.x;
    const int tid = threadIdx.x;
    const int j   = tid >> 2;
    const int g   = tid & 3;
    const int i0  = g * 16;
    __shared__ float k_lds[64], v_lds[64], q_lds[64];
    __shared__ float numer_lds[64];
    __shared__ float stage[4096];
    float s_loc[16];
    #pragma unroll
    for (int e = 0; e < 16; ++e) s_loc[e] = carryS[(size_t)c*4096 + (i0 + e)*64 + j];
    float z_loc = (tid < 64) ? carryZ[c*64 + tid] : 0.f;

    const int t0 = c * CLEN;
    for (int tt = 0; tt < CLEN; ++tt){
        const int t = t0 + tt;
        if (tid < 64)       k_lds[tid]       = kbuf[(size_t)t*K_DIM + tid];
        else if (tid < 128) v_lds[tid - 64]  = vbuf[(size_t)t*V_DIM + tid - 64];
        else if (tid < 192) q_lds[tid - 128] = qbuf[(size_t)t*K_DIM + tid - 128];
        __syncthreads();
        const int st = start[t];
        if (st){
            #pragma unroll
            for (int e = 0; e < 16; ++e) s_loc[e] = 0.f;
        }
        const float vj = v_lds[j];
        float np = 0.f;
        #pragma unroll
        for (int e = 0; e < 16; ++e){
            s_loc[e] += k_lds[i0 + e] * vj;
            np += s_loc[e] * q_lds[i0 + e];
        }
        np += __shfl_down(np, 1, 64);
        np += __shfl_down(np, 2, 64);
        if (g == 0) numer_lds[j] = np;
        float denom = 1.f;
        if (tid < 64){
            z_loc = (st ? 0.f : z_loc) + k_lds[tid];
            z_out[(size_t)t*K_DIM + tid] = z_loc;
            float zs = z_loc;
            float qs = q_lds[tid];
            #pragma unroll
            for (int o = 32; o > 0; o >>= 1){
                zs += __shfl_down(zs, o, 64);
                qs += __shfl_down(qs, o, 64);
            }
            zs = __shfl(zs, 0, 64);
            qs = __shfl(qs, 0, 64);
            denom = fmaxf(zs * qs, 1e-6f);
        }
        #pragma unroll
        for (int e = 0; e < 16; ++e) stage[(i0 + e)*64 + j] = s_loc[e];
        __syncthreads();
        float4* so = (float4*)(s_out + (size_t)t*4096);
        const float4* stv = (const float4*)stage;
        #pragma unroll
        for (int r = 0; r < 4; ++r) so[tid + 256*r] = stv[tid + 256*r];
        if (tid < 64) attout[(size_t)t*V_DIM + tid] = f2bf(numer_lds[tid] / denom);
        __syncthreads();
    }
}

// ---------------- LayerNorm over H=4096, in place ----------------
__global__ __launch_bounds__(256) void ln_kernel(
    float* __restrict__ h, const float* __restrict__ g, const float* __restrict__ b)
{
    __shared__ float sm[4];
    const int t   = blockIdx.x;
    const int tid = threadIdx.x;
    float* row = h + (size_t)t * H_DIM;
    float4 v[4];
    float s = 0.f;
    #pragma unroll
    for (int r = 0; r < 4; ++r){
        v[r] = ((const float4*)row)[tid + 256*r];
        s += v[r].x + v[r].y + v[r].z + v[r].w;
    }
    #pragma unroll
    for (int o = 32; o > 0; o >>= 1) s += __shfl_down(s, o, 64);
    if ((tid & 63) == 0) sm[tid >> 6] = s;
    __syncthreads();
    const float mu = (sm[0] + sm[1] + sm[2] + sm[3]) * (1.f / H_DIM);
    __syncthreads();
    float sq = 0.f;
    #pragma unroll
    for (int r = 0; r < 4; ++r){
        float dx = v[r].x - mu, dy = v[r].y - mu, dz = v[r].z - mu, dw = v[r].w - mu;
        sq += dx*dx + dy*dy + dz*dz + dw*dw;
    }
    #pragma unroll
    for (int o = 32; o > 0; o >>= 1) sq += __shfl_down(sq, o, 64);
    if ((tid & 63) == 0) sm[tid >> 6] = sq;
    __syncthreads();
    const float var = (sm[0] + sm[1] + sm[2] + sm[3]) * (1.f / H_DIM);
    const float inv = rsqrtf(var + 1e-5f);
    #pragma unroll
    for (int r = 0; r < 4; ++r){
        const int i4 = tid + 256*r;
        const float4 gg = ((const float4*)g)[i4];
        const float4 bb = ((const float4*)b)[i4];
        float4 o;
        o.x = (v[r].x - mu) * inv * gg.x + bb.x;
        o.y = (v[r].y - mu) * inv * gg.y + bb.y;
        o.z = (v[r].z - mu) * inv * gg.z + bb.z;
        o.w = (v[r].w - mu) * inv * gg.w + bb.w;
        ((float4*)row)[i4] = o;
    }
}

extern "C" void kernel_launch(void* const* d_in, const int* in_sizes, int n_in,
                              void* d_out, int out_size, void* d_ws, size_t ws_size,
                              hipStream_t stream)
{
    (void)in_sizes; (void)n_in; (void)out_size; (void)ws_size;
    const float* x     = (const float*)d_in[0];
    const float* s0    = (const float*)d_in[1];
    const float* z0    = (const float*)d_in[2];
    const int*   start = (const int*)d_in[3];
    const float* Wk    = (const float*)d_in[5];
    const float* Wq    = (const float*)d_in[6];
    const float* Wv    = (const float*)d_in[7];
    const float* bv    = (const float*)d_in[8];
    const float* Wskip = (const float*)d_in[9];
    const float* bskip = (const float*)d_in[10];
    const float* W1    = (const float*)d_in[11];
    const float* b1    = (const float*)d_in[12];
    const float* W2    = (const float*)d_in[13];
    const float* b2    = (const float*)d_in[14];
    const float* W3    = (const float*)d_in[15];
    const float* b3    = (const float*)d_in[16];
    const float* ln_g  = (const float*)d_in[17];
    const float* ln_b  = (const float*)d_in[18];

    // ---- workspace carve (256B-aligned), total ~148 MB ----
    char* p = (char*)d_ws;
    auto alloc = [&](size_t bytes) -> void* {
        void* r = (void*)p; p += (bytes + 255) & ~(size_t)255; return r;
    };
    float* kbuf  = (float*)alloc((size_t)T_DIM * K_DIM * 4);
    float* qbuf  = (float*)alloc((size_t)T_DIM * K_DIM * 4);
    float* vbuf  = (float*)alloc((size_t)T_DIM * V_DIM * 4);
    float* chS   = (float*)alloc((size_t)CHUNKS * 4096 * 4);
    float* chZ   = (float*)alloc((size_t)CHUNKS * 64 * 4);
    float* caS   = (float*)alloc((size_t)CHUNKS * 4096 * 4);
    float* caZ   = (float*)alloc((size_t)CHUNKS * 64 * 4);
    int*   flags = (int*)  alloc((size_t)CHUNKS * 4);
    unsigned short* xb     = (unsigned short*)alloc((size_t)T_DIM * IN_DIM * 2);
    unsigned short* Wskipb = (unsigned short*)alloc((size_t)H_DIM * IN_DIM * 2);
    unsigned short* W1b    = (unsigned short*)alloc((size_t)H_DIM * V_DIM * 2);
    unsigned short* W2b    = (unsigned short*)alloc((size_t)H_DIM * H_DIM * 2);
    unsigned short* W3b    = (unsigned short*)alloc((size_t)H_DIM * H_DIM * 2);
    unsigned short* attb   = (unsigned short*)alloc((size_t)T_DIM * V_DIM * 2);
    unsigned short* h1b    = (unsigned short*)alloc((size_t)T_DIM * H_DIM * 2);
    unsigned short* h2b    = (unsigned short*)alloc((size_t)T_DIM * H_DIM * 2);

    float* hn  = (float*)d_out;                          // (T,H)
    float* s_o = hn  + (size_t)T_DIM * H_DIM;            // (T,K,V)
    float* z_o = s_o + (size_t)T_DIM * K_DIM * V_DIM;    // (T,1,K)

    // 0) bf16 conversions of GEMM inputs (independent; launch up front)
    cvt_bf16<<<(T_DIM*IN_DIM/4 + 255)/256, 256, 0, stream>>>(x, xb, T_DIM*IN_DIM/4);
    cvt_bf16<<<(H_DIM*IN_DIM/4 + 255)/256, 256, 0, stream>>>(Wskip, Wskipb, H_DIM*IN_DIM/4);
    cvt_bf16<<<(H_DIM*V_DIM/4 + 255)/256, 256, 0, stream>>>(W1, W1b, H_DIM*V_DIM/4);
    cvt_bf16<<<(H_DIM*H_DIM/4 + 255)/256, 256, 0, stream>>>(W2, W2b, H_DIM*H_DIM/4);
    cvt_bf16<<<(H_DIM*H_DIM/4 + 255)/256, 256, 0, stream>>>(W3, W3b, H_DIM*H_DIM/4);

    // 1) projections (fp32): k = phi(x@Wk^T), q = phi(x@Wq^T), v = x@Wv^T + bv
    gemm_xwt<<<dim3(T_DIM/64, K_DIM/64), 256, 0, stream>>>(x, Wk, IN_DIM, nullptr, kbuf, K_DIM, 1);
    gemm_xwt<<<dim3(T_DIM/64, K_DIM/64), 256, 0, stream>>>(x, Wq, IN_DIM, nullptr, qbuf, K_DIM, 1);
    gemm_xwt<<<dim3(T_DIM/64, V_DIM/64), 256, 0, stream>>>(x, Wv, IN_DIM, bv, vbuf, V_DIM, 0);

    // 2) segmented scan (3 passes); pass C emits att in bf16
    scan_passA<<<CHUNKS, 256, 0, stream>>>(kbuf, vbuf, start, chS, chZ, flags);
    scan_passB<<<4096/256, 256, 0, stream>>>(chS, chZ, flags, s0, z0, caS, caZ);
    scan_passC<<<CHUNKS, 256, 0, stream>>>(kbuf, vbuf, qbuf, start, caS, caZ, s_o, z_o, attb);

    // 3) MLP: GEMM1 (K=64) on the 128^2 kernel; big GEMMs on the pipelined 256^2 kernel.
    gemm_mfma_bt<<<dim3(T_DIM/128, H_DIM/128), 256, 0, stream>>>(
        attb, W1b, V_DIM, nullptr, nullptr, 0, b1, nullptr, h1b, H_DIM, 2, 1);
    gemm256<<<dim3(T_DIM/256, H_DIM/256), 512, 0, stream>>>(
        h1b, W2b, H_DIM, b2, h2b, H_DIM, 2, 1, 0);
    // skip path first (fp32 into hn), then main GEMM3 accumulates into it
    gemm256<<<dim3(T_DIM/256, H_DIM/256), 512, 0, stream>>>(
        xb, Wskipb, IN_DIM, bskip, hn, H_DIM, 0, 0, 0);
    gemm256<<<dim3(T_DIM/256, H_DIM/256), 512, 0, stream>>>(
        h2b, W3b, H_DIM, b3, hn, H_DIM, 0, 0, 1);

    // 4) LayerNorm in place on d_out
    ln_kernel<<<T_DIM, 256, 0, stream>>>(hn, ln_g, ln_b);
}

// Round 2
// 950.473 us; speedup vs baseline: 1.0914x; 1.0914x over previous
//
#include <hip/hip_runtime.h>
#include <math.h>

// Problem constants (from reference): T=4096, IN=512, K=64, V=64, H=4096
#define T_DIM 4096
#define IN_DIM 512
#define K_DIM 64
#define V_DIM 64
#define H_DIM 4096
#define CHUNKS 256
#define CLEN 16   // T_DIM / CHUNKS

typedef __attribute__((ext_vector_type(8))) short short8;  // 8 bf16 = 4 VGPRs
typedef __attribute__((ext_vector_type(4))) float f32x4;

// ---------------- activations ----------------
__device__ __forceinline__ float phi_act(float v){
    return v > 0.f ? (v + 1.f) : (expm1f(v) + 1.f);
}
__device__ __forceinline__ float mish_act(float v){
    float sp = fmaxf(v, 0.f) + log1pf(expf(-fabsf(v)));
    return v * tanhf(sp);
}
// fp32 -> bf16 round-to-nearest-even (bit trick)
__device__ __forceinline__ unsigned short f2bf(float f){
    union { float f; unsigned int u; } x; x.f = f;
    unsigned int u = x.u + 0x7fffu + ((x.u >> 16) & 1u);
    return (unsigned short)(u >> 16);
}

// async 16B global->LDS (dest = wave-uniform base + lane*16; layout must be contiguous per lane)
__device__ __forceinline__ void async16(const unsigned short* g, unsigned short* l){
    __builtin_amdgcn_global_load_lds(
        (const __attribute__((address_space(1))) unsigned int*)g,
        (__attribute__((address_space(3))) unsigned int*)l,
        16, 0, 0);
}

// inline-asm ds_read_b128: LDS byte address (low 32 bits of generic LDS pointer).
// Opaque to the compiler's waitcnt insertion -> we control lgkmcnt/vmcnt entirely.
__device__ __forceinline__ short8 dsr128(unsigned addr){
    short8 d;
    asm volatile("ds_read_b128 %0, %1" : "=v"(d) : "v"(addr));
    return d;
}

// ---------------- fp32 -> bf16 conversion, 4 elems/thread ----------------
__global__ __launch_bounds__(256) void cvt_bf16(const float* __restrict__ in,
                                                unsigned short* __restrict__ out, int n4){
    int i = blockIdx.x * 256 + threadIdx.x;
    if (i >= n4) return;
    float4 v = ((const float4*)in)[i];
    ushort4 o;
    o.x = f2bf(v.x); o.y = f2bf(v.y); o.z = f2bf(v.z); o.w = f2bf(v.w);
    ((ushort4*)out)[i] = o;
}

// ---------------- bf16 MFMA GEMM (128x128 tile, m97 structure) ----------------
// Kept for the small-K GEMM1 (K=64): 2 blocks/CU co-residency hides its staging drains.
__global__ __launch_bounds__(256) void gemm_mfma_bt(
    const unsigned short* __restrict__ A0, const unsigned short* __restrict__ B0, int K0,
    const unsigned short* __restrict__ A1, const unsigned short* __restrict__ B1, int K1,
    const float* __restrict__ bias0, const float* __restrict__ bias1,
    void* __restrict__ Y, int N, int act, int out_bf16)
{
    constexpr int BK = 64;
    __shared__ unsigned short As[128 * BK];
    __shared__ unsigned short Bs[128 * BK];
    const int tid  = threadIdx.x;
    const int lane = tid & 63;
    const int wm   = (tid >> 6 & 1) * 64;     // wave m-offset in tile
    const int wn   = (tid >> 7) * 64;         // wave n-offset in tile
    const int bm   = blockIdx.x * 128;
    const int bn   = blockIdx.y * 128;
    const int l15  = lane & 15;
    const int quad = lane >> 4;

    f32x4 acc[4][4] = {};

    for (int seg = 0; seg < 2; ++seg){
        const unsigned short* A = seg ? A1 : A0;
        const unsigned short* B = seg ? B1 : B0;
        const int Kd = seg ? K1 : K0;
        if (Kd <= 0 || A == nullptr) continue;
        for (int k0 = 0; k0 < Kd; k0 += BK){
            __syncthreads();  // previous tile's ds_reads must drain before restage
            #pragma unroll
            for (int it = 0; it < 4; ++it){   // 1024 chunks of 16B per matrix, 4 per thread
                const int c  = it * 256 + tid;        // LDS chunk index (byte off = c*16)
                const int r  = c >> 3;                // row 0..127
                const int kc = (c & 7) ^ (r & 7);     // swizzled global k-chunk
                async16(A + (size_t)(bm + r) * Kd + k0 + kc * 8, &As[c * 8]);
            }
            #pragma unroll
            for (int it = 0; it < 4; ++it){
                const int c  = it * 256 + tid;
                const int r  = c >> 3;
                const int kc = (c & 7) ^ (r & 7);
                async16(B + (size_t)(bn + r) * Kd + k0 + kc * 8, &Bs[c * 8]);
            }
            __syncthreads();  // s_waitcnt vmcnt(0) before s_barrier -> staging complete
            #pragma unroll
            for (int ks = 0; ks < 2; ++ks){
                short8 af[4], bf[4];
                #pragma unroll
                for (int mi = 0; mi < 4; ++mi){
                    const int row = wm + mi * 16 + l15;
                    const int kq  = ks * 4 + quad;            // k-chunk 0..7
                    af[mi] = *(const short8*)&As[(row * 8 + (kq ^ (row & 7))) * 8];
                }
                #pragma unroll
                for (int ni = 0; ni < 4; ++ni){
                    const int row = wn + ni * 16 + l15;
                    const int kq  = ks * 4 + quad;
                    bf[ni] = *(const short8*)&Bs[(row * 8 + (kq ^ (row & 7))) * 8];
                }
                #pragma unroll
                for (int mi = 0; mi < 4; ++mi)
                    #pragma unroll
                    for (int ni = 0; ni < 4; ++ni)
                        acc[mi][ni] = __builtin_amdgcn_mfma_f32_16x16x32_bf16(
                            af[mi], bf[ni], acc[mi][ni], 0, 0, 0);
            }
        }
    }

    // epilogue: C/D mapping col=lane&15, row=quad*4+reg
    #pragma unroll
    for (int ni = 0; ni < 4; ++ni){
        const int col = bn + wn + ni * 16 + l15;
        float bb = 0.f;
        if (bias0) bb += bias0[col];
        if (bias1) bb += bias1[col];
        #pragma unroll
        for (int mi = 0; mi < 4; ++mi){
            #pragma unroll
            for (int r = 0; r < 4; ++r){
                const int row = bm + wm + mi * 16 + quad * 4 + r;
                float v = acc[mi][ni][r] + bb;
                if (act == 2) v = mish_act(v);
                if (out_bf16) ((unsigned short*)Y)[(size_t)row * N + col] = f2bf(v);
                else          ((float*)Y)[(size_t)row * N + col] = v;
            }
        }
    }
}

// ---------------- 256x256 quad-buffered pipelined bf16 MFMA GEMM ----------------
// BM=BN=256, BK=32, NBUF=4 (LDS = 4 x (A 16K + B 16K) = 128 KiB, 1 block/CU).
// 512 threads = 8 waves (2M x 4N); per-wave output 128x64 = acc f32x4[8][4] (128 AGPR).
// Per K-tile: 2 phases x 16 MFMA (mfma_f32_16x16x32_bf16, one K=32 step).
//
// Pipeline: tile t+3 is STAGED (global_load_lds) while computing tile t -> each
// tile's loads have ~3 tiles of compute to land. Steady-state boundary wait is
// vmcnt(8) (tiles t+2,t+3 in flight) folded in before the phase-1 trailing
// s_barrier, which doubles as the cross-wave visibility rendezvous (each wave
// waits its OWN loads; the barrier publishes all). vmcnt never drains to 0
// until the tail. All fragment ds_reads are INLINE ASM so the compiler cannot
// insert a conservative vmcnt(0) on the LDS RAW dependency (round-1 failure);
// rule #18: s_barrier; lgkmcnt(0); sched_barrier(0) precede each MFMA cluster.
//
// Swizzle (both-sides involution): chunk slot s of row r holds global k-chunk
// s ^ swz(r), swz(r) = (r ^ (r>>2)) & 3. Staging dest stays linear (lane*16,
// required by global_load_lds); the source address is pre-swizzled. Reads XOR
// the same pattern. Max 2-way bank aliasing = free.
__global__ __launch_bounds__(512, 2) void gemm256p(
    const unsigned short* __restrict__ A, const unsigned short* __restrict__ B, int Kd,
    const float* __restrict__ bias,
    void* __restrict__ Y, int N, int act, int out_bf16, int accum)
{
    constexpr int BK = 32;
    __shared__ unsigned short As[4][256 * BK];   // 4 x 16 KiB
    __shared__ unsigned short Bs[4][256 * BK];   // 4 x 16 KiB
    const int tid  = threadIdx.x;
    const int lane = tid & 63;
    const int w    = tid >> 6;          // wave 0..7
    const int wr   = w >> 2;            // 0..1  (M half)
    const int wc   = w & 3;             // 0..3  (N quarter)
    const int bm   = blockIdx.x * 256;
    const int bn   = blockIdx.y * 256;
    const int l15  = lane & 15;
    const int quad = lane >> 4;
    const int NT   = Kd / BK;

    f32x4 acc[8][4] = {};

    // --- staging geometry: 1024 chunks of 16B per matrix-tile; thread owns c=tid, c=tid+512.
    // chunk c: row r=c>>2, slot s=c&3, global k-chunk = s ^ swz(r).
    const int rA0  = tid >> 2;
    const int rA1  = (tid + 512) >> 2;
    const int kc0  = (tid & 3) ^ ((rA0 ^ (rA0 >> 2)) & 3);
    const int kc1  = (tid & 3) ^ ((rA1 ^ (rA1 >> 2)) & 3);
    const unsigned short* gA0 = A + (size_t)(bm + rA0) * Kd + kc0 * 8;
    const unsigned short* gA1 = A + (size_t)(bm + rA1) * Kd + kc1 * 8;
    const unsigned short* gB0 = B + (size_t)(bn + rA0) * Kd + kc0 * 8;
    const unsigned short* gB1 = B + (size_t)(bn + rA1) * Kd + kc1 * 8;

    auto stageA = [&](int kt, int bi){
        async16(gA0 + kt * BK, &As[bi][tid * 8]);
        async16(gA1 + kt * BK, &As[bi][(tid + 512) * 8]);
    };
    auto stageB = [&](int kt, int bi){
        async16(gB0 + kt * BK, &Bs[bi][tid * 8]);
        async16(gB1 + kt * BK, &Bs[bi][(tid + 512) * 8]);
    };

    // --- loop-invariant LDS read byte-addresses (buffer 0); per-tile add bi*16384.
    const unsigned asBase = (unsigned)(size_t)&As[0][0];
    const unsigned bsBase = (unsigned)(size_t)&Bs[0][0];
    unsigned offA[8], offB[4];
    #pragma unroll
    for (int mi = 0; mi < 8; ++mi){
        const int row = wr * 128 + mi * 16 + l15;
        const int s   = quad ^ ((row ^ (row >> 2)) & 3);
        offA[mi] = asBase + (unsigned)((row * 4 + s) * 16);
    }
    #pragma unroll
    for (int ni = 0; ni < 4; ++ni){
        const int row = wc * 64 + ni * 16 + l15;
        const int s   = quad ^ ((row ^ (row >> 2)) & 3);
        offB[ni] = bsBase + (unsigned)((row * 4 + s) * 16);
    }

    // --- prologue: stage tiles 0..2, wait tile 0 (8 = tiles 1,2 stay in flight)
    if (NT > 0){ stageA(0, 0); stageB(0, 0); }
    if (NT > 1){ stageA(1, 1); stageB(1, 1); }
    if (NT > 2){ stageA(2, 2); stageB(2, 2); }
    if (NT > 2)      asm volatile("s_waitcnt vmcnt(8)" ::: "memory");
    else if (NT > 1) asm volatile("s_waitcnt vmcnt(4)" ::: "memory");
    else             asm volatile("s_waitcnt vmcnt(0)" ::: "memory");
    __builtin_amdgcn_s_barrier();

    for (int t = 0; t < NT; ++t){
        const int bi      = t & 3;
        const unsigned bo = (unsigned)bi * (unsigned)(256 * BK * 2);
        short8 bfr[4], afr[4];

        // ---------- phase 0: m-frags 0..3 x all n ----------
        #pragma unroll
        for (int ni = 0; ni < 4; ++ni) bfr[ni] = dsr128(offB[ni] + bo);
        #pragma unroll
        for (int mi = 0; mi < 4; ++mi) afr[mi] = dsr128(offA[mi] + bo);
        if (t + 3 < NT) stageA(t + 3, (t + 3) & 3);   // buffer (t-1)&3: reads done at t-1's trailing barrier
        __builtin_amdgcn_s_barrier();
        asm volatile("s_waitcnt lgkmcnt(0)" ::: "memory");
        __builtin_amdgcn_sched_barrier(0);
        __builtin_amdgcn_s_setprio(1);
        #pragma unroll
        for (int mi = 0; mi < 4; ++mi)
            #pragma unroll
            for (int ni = 0; ni < 4; ++ni)
                acc[mi][ni] = __builtin_amdgcn_mfma_f32_16x16x32_bf16(
                    afr[mi], bfr[ni], acc[mi][ni], 0, 0, 0);
        __builtin_amdgcn_s_setprio(0);
        __builtin_amdgcn_s_barrier();

        // ---------- phase 1: m-frags 4..7 x all n ----------
        #pragma unroll
        for (int mi = 0; mi < 4; ++mi) afr[mi] = dsr128(offA[4 + mi] + bo);
        if (t + 3 < NT) stageB(t + 3, (t + 3) & 3);
        __builtin_amdgcn_s_barrier();
        asm volatile("s_waitcnt lgkmcnt(0)" ::: "memory");
        __builtin_amdgcn_sched_barrier(0);
        __builtin_amdgcn_s_setprio(1);
        #pragma unroll
        for (int mi = 0; mi < 4; ++mi)
            #pragma unroll
            for (int ni = 0; ni < 4; ++ni)
                acc[4 + mi][ni] = __builtin_amdgcn_mfma_f32_16x16x32_bf16(
                    afr[mi], bfr[ni], acc[4 + mi][ni], 0, 0, 0);
        __builtin_amdgcn_s_setprio(0);

        // ---------- tile boundary: ensure tile t+1 landed (all waves), keep t+2/t+3 in flight
        if (t + 1 < NT){
            if (t + 4 <= NT)      asm volatile("s_waitcnt vmcnt(8)" ::: "memory");
            else if (t + 3 == NT) asm volatile("s_waitcnt vmcnt(4)" ::: "memory");
            else                  asm volatile("s_waitcnt vmcnt(0)" ::: "memory");
        }
        __builtin_amdgcn_s_barrier();   // publishes every wave's staged chunks of t+1
    }

    // epilogue: C/D mapping col=lane&15, row=quad*4+reg
    #pragma unroll
    for (int ni = 0; ni < 4; ++ni){
        const int col = bn + wc * 64 + ni * 16 + l15;
        const float bb = bias ? bias[col] : 0.f;
        #pragma unroll
        for (int mi = 0; mi < 8; ++mi){
            #pragma unroll
            for (int r = 0; r < 4; ++r){
                const int row = bm + wr * 128 + mi * 16 + quad * 4 + r;
                float v = acc[mi][ni][r] + bb;
                if (act == 2) v = mish_act(v);
                if (out_bf16) ((unsigned short*)Y)[(size_t)row * N + col] = f2bf(v);
                else {
                    float* yp = (float*)Y + (size_t)row * N + col;
                    *yp = accum ? (*yp + v) : v;
                }
            }
        }
    }
}

// ---------------- fp32 GEMM (small projections):  Y = act(x @ W^T [+ bias]) ----------------
__global__ __launch_bounds__(256) void gemm_xwt(
    const float* __restrict__ A0, const float* __restrict__ B0, int K0,
    const float* __restrict__ bias0,
    float* __restrict__ Y, int N, int act)
{
    __shared__ float As[16][68];
    __shared__ float Bs[16][68];
    const int tid  = threadIdx.x;
    const int bm   = blockIdx.x * 64;
    const int bn   = blockIdx.y * 64;
    const int lrow = tid >> 2;
    const int lk4  = (tid & 3) * 4;
    const int tm   = (tid >> 4) * 4;
    const int tn   = (tid & 15) * 4;
    float acc[4][4] = {};

    const float* aptr = A0 + (size_t)(bm + lrow) * K0 + lk4;
    const float* bptr = B0 + (size_t)(bn + lrow) * K0 + lk4;
    for (int k0 = 0; k0 < K0; k0 += 16){
        const float4 av = *(const float4*)(aptr + k0);
        const float4 bv = *(const float4*)(bptr + k0);
        __syncthreads();
        As[lk4+0][lrow]=av.x; As[lk4+1][lrow]=av.y; As[lk4+2][lrow]=av.z; As[lk4+3][lrow]=av.w;
        Bs[lk4+0][lrow]=bv.x; Bs[lk4+1][lrow]=bv.y; Bs[lk4+2][lrow]=bv.z; Bs[lk4+3][lrow]=bv.w;
        __syncthreads();
        #pragma unroll
        for (int kk = 0; kk < 16; ++kk){
            const float4 a = *(const float4*)&As[kk][tm];
            const float4 b = *(const float4*)&Bs[kk][tn];
            acc[0][0] += a.x*b.x; acc[0][1] += a.x*b.y; acc[0][2] += a.x*b.z; acc[0][3] += a.x*b.w;
            acc[1][0] += a.y*b.x; acc[1][1] += a.y*b.y; acc[1][2] += a.y*b.z; acc[1][3] += a.y*b.w;
            acc[2][0] += a.z*b.x; acc[2][1] += a.z*b.y; acc[2][2] += a.z*b.z; acc[2][3] += a.z*b.w;
            acc[3][0] += a.w*b.x; acc[3][1] += a.w*b.y; acc[3][2] += a.w*b.z; acc[3][3] += a.w*b.w;
        }
    }
    float badd[4] = {0.f, 0.f, 0.f, 0.f};
    if (bias0){
        badd[0] = bias0[bn+tn+0]; badd[1] = bias0[bn+tn+1];
        badd[2] = bias0[bn+tn+2]; badd[3] = bias0[bn+tn+3];
    }
    #pragma unroll
    for (int i = 0; i < 4; ++i){
        float r0 = acc[i][0] + badd[0];
        float r1 = acc[i][1] + badd[1];
        float r2 = acc[i][2] + badd[2];
        float r3 = acc[i][3] + badd[3];
        if (act == 1){ r0 = phi_act(r0); r1 = phi_act(r1); r2 = phi_act(r2); r3 = phi_act(r3); }
        *(float4*)&Y[(size_t)(bm + tm + i) * N + bn + tn] = make_float4(r0, r1, r2, r3);
    }
}

// ---------------- segmented scan, pass A ----------------
__global__ __launch_bounds__(256) void scan_passA(
    const float* __restrict__ kbuf, const float* __restrict__ vbuf,
    const int* __restrict__ start,
    float* __restrict__ chunkS, float* __restrict__ chunkZ, int* __restrict__ chunkFlag)
{
    const int c   = blockIdx.x;
    const int tid = threadIdx.x;
    const int j   = tid >> 2;
    const int i0  = (tid & 3) * 16;
    __shared__ float k_lds[64], v_lds[64];
    float s_loc[16];
    #pragma unroll
    for (int e = 0; e < 16; ++e) s_loc[e] = 0.f;
    float z_loc = 0.f;
    int flag = 0;
    const int t0 = c * CLEN;
    for (int tt = 0; tt < CLEN; ++tt){
        const int t = t0 + tt;
        if (tid < 64)       k_lds[tid]      = kbuf[(size_t)t*K_DIM + tid];
        else if (tid < 128) v_lds[tid - 64] = vbuf[(size_t)t*V_DIM + tid - 64];
        __syncthreads();
        const int st = start[t];
        if (st){
            #pragma unroll
            for (int e = 0; e < 16; ++e) s_loc[e] = 0.f;
            z_loc = 0.f;
            flag = 1;
        }
        const float vj = v_lds[j];
        #pragma unroll
        for (int e = 0; e < 16; ++e) s_loc[e] += k_lds[i0 + e] * vj;
        if (tid < 64) z_loc += k_lds[tid];
        __syncthreads();
    }
    #pragma unroll
    for (int e = 0; e < 16; ++e) chunkS[(size_t)c*4096 + (i0 + e)*64 + j] = s_loc[e];
    if (tid < 64) chunkZ[c*64 + tid] = z_loc;
    if (tid == 0) chunkFlag[c] = flag;
}

// ---------------- pass B: exclusive cross-chunk combine ----------------
__global__ __launch_bounds__(256) void scan_passB(
    const float* __restrict__ chunkS, const float* __restrict__ chunkZ, const int* __restrict__ chunkFlag,
    const float* __restrict__ s0, const float* __restrict__ z0,
    float* __restrict__ carryS, float* __restrict__ carryZ)
{
    const int ij = blockIdx.x * 256 + threadIdx.x;
    float e = s0[ij];
    for (int c = 0; c < CHUNKS; ++c){
        carryS[(size_t)c*4096 + ij] = e;
        const int f   = chunkFlag[c];
        const float s = chunkS[(size_t)c*4096 + ij];
        e = f ? s : (e + s);
    }
    if (ij < 64){
        float ez = z0[ij];
        for (int c = 0; c < CHUNKS; ++c){
            carryZ[c*64 + ij] = ez;
            const int f   = chunkFlag[c];
            const float z = chunkZ[c*64 + ij];
            ez = f ? z : (ez + z);
        }
    }
}

// ---------------- pass C: replay with carry; emit s[t], z[t], att out (bf16) ----------------
__global__ __launch_bounds__(256) void scan_passC(
    const float* __restrict__ kbuf, const float* __restrict__ vbuf, const float* __restrict__ qbuf,
    const int* __restrict__ start,
    const float* __restrict__ carryS, const float* __restrict__ carryZ,
    float* __restrict__ s_out, float* __restrict__ z_out, unsigned short* __restrict__ attout)
{
    const int c   = blockIdx.x;
    const int tid = threadIdx.x;
    const int j   = tid >> 2;
    const int g   = tid & 3;
    const int i0  = g * 16;
    __shared__ float k_lds[64], v_lds[64], q_lds[64];
    __shared__ float numer_lds[64];
    __shared__ float stage[4096];
    float s_loc[16];
    #pragma unroll
    for (int e = 0; e < 16; ++e) s_loc[e] = carryS[(size_t)c*4096 + (i0 + e)*64 + j];
    float z_loc = (tid < 64) ? carryZ[c*64 + tid] : 0.f;

    const int t0 = c * CLEN;
    for (int tt = 0; tt < CLEN; ++tt){
        const int t = t0 + tt;
        if (tid < 64)       k_lds[tid]       = kbuf[(size_t)t*K_DIM + tid];
        else if (tid < 128) v_lds[tid - 64]  = vbuf[(size_t)t*V_DIM + tid - 64];
        else if (tid < 192) q_lds[tid - 128] = qbuf[(size_t)t*K_DIM + tid - 128];
        __syncthreads();
        const int st = start[t];
        if (st){
            #pragma unroll
            for (int e = 0; e < 16; ++e) s_loc[e] = 0.f;
        }
        const float vj = v_lds[j];
        float np = 0.f;
        #pragma unroll
        for (int e = 0; e < 16; ++e){
            s_loc[e] += k_lds[i0 + e] * vj;
            np += s_loc[e] * q_lds[i0 + e];
        }
        np += __shfl_down(np, 1, 64);
        np += __shfl_down(np, 2, 64);
        if (g == 0) numer_lds[j] = np;
        float denom = 1.f;
        if (tid < 64){
            z_loc = (st ? 0.f : z_loc) + k_lds[tid];
            z_out[(size_t)t*K_DIM + tid] = z_loc;
            float zs = z_loc;
            float qs = q_lds[tid];
            #pragma unroll
            for (int o = 32; o > 0; o >>= 1){
                zs += __shfl_down(zs, o, 64);
                qs += __shfl_down(qs, o, 64);
            }
            zs = __shfl(zs, 0, 64);
            qs = __shfl(qs, 0, 64);
            denom = fmaxf(zs * qs, 1e-6f);
        }
        #pragma unroll
        for (int e = 0; e < 16; ++e) stage[(i0 + e)*64 + j] = s_loc[e];
        __syncthreads();
        float4* so = (float4*)(s_out + (size_t)t*4096);
        const float4* stv = (const float4*)stage;
        #pragma unroll
        for (int r = 0; r < 4; ++r) so[tid + 256*r] = stv[tid + 256*r];
        if (tid < 64) attout[(size_t)t*V_DIM + tid] = f2bf(numer_lds[tid] / denom);
        __syncthreads();
    }
}

// ---------------- LayerNorm over H=4096, in place ----------------
__global__ __launch_bounds__(256) void ln_kernel(
    float* __restrict__ h, const float* __restrict__ g, const float* __restrict__ b)
{
    __shared__ float sm[4];
    const int t   = blockIdx.x;
    const int tid = threadIdx.x;
    float* row = h + (size_t)t * H_DIM;
    float4 v[4];
    float s = 0.f;
    #pragma unroll
    for (int r = 0; r < 4; ++r){
        v[r] = ((const float4*)row)[tid + 256*r];
        s += v[r].x + v[r].y + v[r].z + v[r].w;
    }
    #pragma unroll
    for (int o = 32; o > 0; o >>= 1) s += __shfl_down(s, o, 64);
    if ((tid & 63) == 0) sm[tid >> 6] = s;
    __syncthreads();
    const float mu = (sm[0] + sm[1] + sm[2] + sm[3]) * (1.f / H_DIM);
    __syncthreads();
    float sq = 0.f;
    #pragma unroll
    for (int r = 0; r < 4; ++r){
        float dx = v[r].x - mu, dy = v[r].y - mu, dz = v[r].z - mu, dw = v[r].w - mu;
        sq += dx*dx + dy*dy + dz*dz + dw*dw;
    }
    #pragma unroll
    for (int o = 32; o > 0; o >>= 1) sq += __shfl_down(sq, o, 64);
    if ((tid & 63) == 0) sm[tid >> 6] = sq;
    __syncthreads();
    const float var = (sm[0] + sm[1] + sm[2] + sm[3]) * (1.f / H_DIM);
    const float inv = rsqrtf(var + 1e-5f);
    #pragma unroll
    for (int r = 0; r < 4; ++r){
        const int i4 = tid + 256*r;
        const float4 gg = ((const float4*)g)[i4];
        const float4 bb = ((const float4*)b)[i4];
        float4 o;
        o.x = (v[r].x - mu) * inv * gg.x + bb.x;
        o.y = (v[r].y - mu) * inv * gg.y + bb.y;
        o.z = (v[r].z - mu) * inv * gg.z + bb.z;
        o.w = (v[r].w - mu) * inv * gg.w + bb.w;
        ((float4*)row)[i4] = o;
    }
}

extern "C" void kernel_launch(void* const* d_in, const int* in_sizes, int n_in,
                              void* d_out, int out_size, void* d_ws, size_t ws_size,
                              hipStream_t stream)
{
    (void)in_sizes; (void)n_in; (void)out_size; (void)ws_size;
    const float* x     = (const float*)d_in[0];
    const float* s0    = (const float*)d_in[1];
    const float* z0    = (const float*)d_in[2];
    const int*   start = (const int*)d_in[3];
    const float* Wk    = (const float*)d_in[5];
    const float* Wq    = (const float*)d_in[6];
    const float* Wv    = (const float*)d_in[7];
    const float* bv    = (const float*)d_in[8];
    const float* Wskip = (const float*)d_in[9];
    const float* bskip = (const float*)d_in[10];
    const float* W1    = (const float*)d_in[11];
    const float* b1    = (const float*)d_in[12];
    const float* W2    = (const float*)d_in[13];
    const float* b2    = (const float*)d_in[14];
    const float* W3    = (const float*)d_in[15];
    const float* b3    = (const float*)d_in[16];
    const float* ln_g  = (const float*)d_in[17];
    const float* ln_b  = (const float*)d_in[18];

    // ---- workspace carve (256B-aligned), total ~148 MB ----
    char* p = (char*)d_ws;
    auto alloc = [&](size_t bytes) -> void* {
        void* r = (void*)p; p += (bytes + 255) & ~(size_t)255; return r;
    };
    float* kbuf  = (float*)alloc((size_t)T_DIM * K_DIM * 4);
    float* qbuf  = (float*)alloc((size_t)T_DIM * K_DIM * 4);
    float* vbuf  = (float*)alloc((size_t)T_DIM * V_DIM * 4);
    float* chS   = (float*)alloc((size_t)CHUNKS * 4096 * 4);
    float* chZ   = (float*)alloc((size_t)CHUNKS * 64 * 4);
    float* caS   = (float*)alloc((size_t)CHUNKS * 4096 * 4);
    float* caZ   = (float*)alloc((size_t)CHUNKS * 64 * 4);
    int*   flags = (int*)  alloc((size_t)CHUNKS * 4);
    unsigned short* xb     = (unsigned short*)alloc((size_t)T_DIM * IN_DIM * 2);
    unsigned short* Wskipb = (unsigned short*)alloc((size_t)H_DIM * IN_DIM * 2);
    unsigned short* W1b    = (unsigned short*)alloc((size_t)H_DIM * V_DIM * 2);
    unsigned short* W2b    = (unsigned short*)alloc((size_t)H_DIM * H_DIM * 2);
    unsigned short* W3b    = (unsigned short*)alloc((size_t)H_DIM * H_DIM * 2);
    unsigned short* attb   = (unsigned short*)alloc((size_t)T_DIM * V_DIM * 2);
    unsigned short* h1b    = (unsigned short*)alloc((size_t)T_DIM * H_DIM * 2);
    unsigned short* h2b    = (unsigned short*)alloc((size_t)T_DIM * H_DIM * 2);

    float* hn  = (float*)d_out;                          // (T,H)
    float* s_o = hn  + (size_t)T_DIM * H_DIM;            // (T,K,V)
    float* z_o = s_o + (size_t)T_DIM * K_DIM * V_DIM;    // (T,1,K)

    // 0) bf16 conversions of GEMM inputs (independent; launch up front)
    cvt_bf16<<<(T_DIM*IN_DIM/4 + 255)/256, 256, 0, stream>>>(x, xb, T_DIM*IN_DIM/4);
    cvt_bf16<<<(H_DIM*IN_DIM/4 + 255)/256, 256, 0, stream>>>(Wskip, Wskipb, H_DIM*IN_DIM/4);
    cvt_bf16<<<(H_DIM*V_DIM/4 + 255)/256, 256, 0, stream>>>(W1, W1b, H_DIM*V_DIM/4);
    cvt_bf16<<<(H_DIM*H_DIM/4 + 255)/256, 256, 0, stream>>>(W2, W2b, H_DIM*H_DIM/4);
    cvt_bf16<<<(H_DIM*H_DIM/4 + 255)/256, 256, 0, stream>>>(W3, W3b, H_DIM*H_DIM/4);

    // 1) projections (fp32): k = phi(x@Wk^T), q = phi(x@Wq^T), v = x@Wv^T + bv
    gemm_xwt<<<dim3(T_DIM/64, K_DIM/64), 256, 0, stream>>>(x, Wk, IN_DIM, nullptr, kbuf, K_DIM, 1);
    gemm_xwt<<<dim3(T_DIM/64, K_DIM/64), 256, 0, stream>>>(x, Wq, IN_DIM, nullptr, qbuf, K_DIM, 1);
    gemm_xwt<<<dim3(T_DIM/64, V_DIM/64), 256, 0, stream>>>(x, Wv, IN_DIM, bv, vbuf, V_DIM, 0);

    // 2) segmented scan (3 passes); pass C emits att in bf16
    scan_passA<<<CHUNKS, 256, 0, stream>>>(kbuf, vbuf, start, chS, chZ, flags);
    scan_passB<<<4096/256, 256, 0, stream>>>(chS, chZ, flags, s0, z0, caS, caZ);
    scan_passC<<<CHUNKS, 256, 0, stream>>>(kbuf, vbuf, qbuf, start, caS, caZ, s_o, z_o, attb);

    // 3) MLP: GEMM1 (K=64) on the 128^2 kernel; big GEMMs on the quad-buffered 256^2 kernel.
    gemm_mfma_bt<<<dim3(T_DIM/128, H_DIM/128), 256, 0, stream>>>(
        attb, W1b, V_DIM, nullptr, nullptr, 0, b1, nullptr, h1b, H_DIM, 2, 1);
    gemm256p<<<dim3(T_DIM/256, H_DIM/256), 512, 0, stream>>>(
        h1b, W2b, H_DIM, b2, h2b, H_DIM, 2, 1, 0);
    // skip path first (fp32 into hn), then main GEMM3 accumulates into it
    gemm256p<<<dim3(T_DIM/256, H_DIM/256), 512, 0, stream>>>(
        xb, Wskipb, IN_DIM, bskip, hn, H_DIM, 0, 0, 0);
    gemm256p<<<dim3(T_DIM/256, H_DIM/256), 512, 0, stream>>>(
        h2b, W3b, H_DIM, b3, hn, H_DIM, 0, 0, 1);

    // 4) LayerNorm in place on d_out
    ln_kernel<<<T_DIM, 256, 0, stream>>>(hn, ln_g, ln_b);
}

// Round 3
// 880.730 us; speedup vs baseline: 1.1779x; 1.0792x over previous
//
#include <hip/hip_runtime.h>
#include <math.h>

// Problem constants (from reference): T=4096, IN=512, K=64, V=64, H=4096
#define T_DIM 4096
#define IN_DIM 512
#define K_DIM 64
#define V_DIM 64
#define H_DIM 4096
#define CHUNKS 256
#define CLEN 16   // T_DIM / CHUNKS

typedef __attribute__((ext_vector_type(8))) short short8;  // 8 bf16 = 4 VGPRs
typedef __attribute__((ext_vector_type(4))) float f32x4;

// ---------------- activations ----------------
__device__ __forceinline__ float phi_act(float v){
    return v > 0.f ? (v + 1.f) : (expm1f(v) + 1.f);
}
__device__ __forceinline__ float mish_act(float v){
    float sp = fmaxf(v, 0.f) + log1pf(expf(-fabsf(v)));
    return v * tanhf(sp);
}
// fp32 -> bf16 round-to-nearest-even (bit trick)
__device__ __forceinline__ unsigned short f2bf(float f){
    union { float f; unsigned int u; } x; x.f = f;
    unsigned int u = x.u + 0x7fffu + ((x.u >> 16) & 1u);
    return (unsigned short)(u >> 16);
}

// async 16B global->LDS (dest = wave-uniform base + lane*16; layout must be contiguous per lane)
__device__ __forceinline__ void async16(const unsigned short* g, unsigned short* l){
    __builtin_amdgcn_global_load_lds(
        (const __attribute__((address_space(1))) unsigned int*)g,
        (__attribute__((address_space(3))) unsigned int*)l,
        16, 0, 0);
}

// inline-asm ds_read_b128 on a raw LDS byte address. Opaque to the compiler's
// waitcnt insertion -> no compiler-inserted vmcnt(0) on the global_load_lds RAW.
__device__ __forceinline__ short8 dsr128(unsigned addr){
    short8 d;
    asm volatile("ds_read_b128 %0, %1" : "=v"(d) : "v"(addr));
    return d;
}

// ---------------- fp32 -> bf16 conversion, 4 elems/thread ----------------
__global__ __launch_bounds__(256) void cvt_bf16(const float* __restrict__ in,
                                                unsigned short* __restrict__ out, int n4){
    int i = blockIdx.x * 256 + threadIdx.x;
    if (i >= n4) return;
    float4 v = ((const float4*)in)[i];
    ushort4 o;
    o.x = f2bf(v.x); o.y = f2bf(v.y); o.z = f2bf(v.z); o.w = f2bf(v.w);
    ((ushort4*)out)[i] = o;
}

// ---------------- bf16 MFMA GEMM (128x128 tile, m97 structure) ----------------
// Kept for the small-K GEMM1 (K=64): 2 blocks/CU co-residency hides its staging drains.
__global__ __launch_bounds__(256) void gemm_mfma_bt(
    const unsigned short* __restrict__ A0, const unsigned short* __restrict__ B0, int K0,
    const unsigned short* __restrict__ A1, const unsigned short* __restrict__ B1, int K1,
    const float* __restrict__ bias0, const float* __restrict__ bias1,
    void* __restrict__ Y, int N, int act, int out_bf16)
{
    constexpr int BK = 64;
    __shared__ unsigned short As[128 * BK];
    __shared__ unsigned short Bs[128 * BK];
    const int tid  = threadIdx.x;
    const int lane = tid & 63;
    const int wm   = (tid >> 6 & 1) * 64;     // wave m-offset in tile
    const int wn   = (tid >> 7) * 64;         // wave n-offset in tile
    const int bm   = blockIdx.x * 128;
    const int bn   = blockIdx.y * 128;
    const int l15  = lane & 15;
    const int quad = lane >> 4;

    f32x4 acc[4][4] = {};

    for (int seg = 0; seg < 2; ++seg){
        const unsigned short* A = seg ? A1 : A0;
        const unsigned short* B = seg ? B1 : B0;
        const int Kd = seg ? K1 : K0;
        if (Kd <= 0 || A == nullptr) continue;
        for (int k0 = 0; k0 < Kd; k0 += BK){
            __syncthreads();  // previous tile's ds_reads must drain before restage
            #pragma unroll
            for (int it = 0; it < 4; ++it){   // 1024 chunks of 16B per matrix, 4 per thread
                const int c  = it * 256 + tid;        // LDS chunk index (byte off = c*16)
                const int r  = c >> 3;                // row 0..127
                const int kc = (c & 7) ^ (r & 7);     // swizzled global k-chunk
                async16(A + (size_t)(bm + r) * Kd + k0 + kc * 8, &As[c * 8]);
            }
            #pragma unroll
            for (int it = 0; it < 4; ++it){
                const int c  = it * 256 + tid;
                const int r  = c >> 3;
                const int kc = (c & 7) ^ (r & 7);
                async16(B + (size_t)(bn + r) * Kd + k0 + kc * 8, &Bs[c * 8]);
            }
            __syncthreads();  // s_waitcnt vmcnt(0) before s_barrier -> staging complete
            #pragma unroll
            for (int ks = 0; ks < 2; ++ks){
                short8 af[4], bf[4];
                #pragma unroll
                for (int mi = 0; mi < 4; ++mi){
                    const int row = wm + mi * 16 + l15;
                    const int kq  = ks * 4 + quad;            // k-chunk 0..7
                    af[mi] = *(const short8*)&As[(row * 8 + (kq ^ (row & 7))) * 8];
                }
                #pragma unroll
                for (int ni = 0; ni < 4; ++ni){
                    const int row = wn + ni * 16 + l15;
                    const int kq  = ks * 4 + quad;
                    bf[ni] = *(const short8*)&Bs[(row * 8 + (kq ^ (row & 7))) * 8];
                }
                #pragma unroll
                for (int mi = 0; mi < 4; ++mi)
                    #pragma unroll
                    for (int ni = 0; ni < 4; ++ni)
                        acc[mi][ni] = __builtin_amdgcn_mfma_f32_16x16x32_bf16(
                            af[mi], bf[ni], acc[mi][ni], 0, 0, 0);
            }
        }
    }

    // epilogue: C/D mapping col=lane&15, row=quad*4+reg
    #pragma unroll
    for (int ni = 0; ni < 4; ++ni){
        const int col = bn + wn + ni * 16 + l15;
        float bb = 0.f;
        if (bias0) bb += bias0[col];
        if (bias1) bb += bias1[col];
        #pragma unroll
        for (int mi = 0; mi < 4; ++mi){
            #pragma unroll
            for (int r = 0; r < 4; ++r){
                const int row = bm + wm + mi * 16 + quad * 4 + r;
                float v = acc[mi][ni][r] + bb;
                if (act == 2) v = mish_act(v);
                if (out_bf16) ((unsigned short*)Y)[(size_t)row * N + col] = f2bf(v);
                else          ((float*)Y)[(size_t)row * N + col] = v;
            }
        }
    }
}

// ---------------- 256x256 4-phase pipelined bf16 MFMA GEMM (m201-template port) ----------------
// BM=BN=256, BK=64, double-buffered LDS (2 x 64 KiB = 128 KiB, 1 block/CU).
// 512 threads = 8 waves (2M x 4N); per-wave output 128x64 = acc f32x4[8][4].
// Per K-tile: 4 phases x 16 MFMA. Reads per phase: 8/4/8/4 ds_read_b128 (< MFMA time
// per phase, so LDS delivery hides under the MFMA cluster across waves).
// Per phase <=3 half-tile stage loads (global_load_lds), front-loaded in phases 0-2 so the
// boundary vmcnt(0) is aged >=2 phases (~1300 cyc >= HBM latency) -> wait, not stall.
// Race-safety: tile t+1 staged into buf (t+1)&1 = buf (t-1)&1, whose reads drained at each
// wave's phase-3 lgkmcnt(0) of tile t-1, published by tile t-1's boundary barrier.
// Swizzle (proven 0-conflict at BK=64): slot s of row r holds global k-chunk s^(r&7);
// LDS dest stays lane-linear (global_load_lds requirement), source pre-swizzled,
// reads XOR the same pattern. Read banks = 4*slot mod 32 -> row-independent, uniform.
// Two K-segments (A0,B0,K0)+(A1,B1,K1) accumulate into the same acc (fuses skip-GEMM).
__global__ __launch_bounds__(512, 2) void gemm256p(
    const unsigned short* __restrict__ A0, const unsigned short* __restrict__ B0, int K0,
    const unsigned short* __restrict__ A1, const unsigned short* __restrict__ B1, int K1,
    const float* __restrict__ bias0, const float* __restrict__ bias1,
    void* __restrict__ Y, int N, int act, int out_bf16)
{
    __shared__ unsigned short As[2][256 * 64];   // 2 x 32 KiB
    __shared__ unsigned short Bs[2][256 * 64];   // 2 x 32 KiB
    const int tid  = threadIdx.x;
    const int lane = tid & 63;
    const int w    = tid >> 6;          // wave 0..7
    const int wr   = w >> 2;            // 0..1  (M half)
    const int wc   = w & 3;             // 0..3  (N quarter)
    const int l15  = lane & 15;
    const int quad = lane >> 4;

    // Bijective XCD-aware swizzle for the 16x16 grid: XCD x owns a 4(M) x 8(N) patch
    // -> per-K-slice working set 12 x 16 KiB = 192 KiB lives in that XCD's L2.
    int bx = blockIdx.x, by = blockIdx.y;
    if (gridDim.x == 16 && gridDim.y == 16){
        const int id  = by * 16 + bx;       // dispatch-linear (blockIdx.x fastest)
        const int xcd = id & 7;             // default round-robin XCD assignment
        const int loc = id >> 3;            // 0..31 within XCD
        bx = (xcd & 3) * 4 + (loc & 3);
        by = (xcd >> 2) * 8 + (loc >> 2);
    }
    const int bm = bx * 256;
    const int bn = by * 256;

    // staging geometry: one half-tile = 64 rows x 64 k = 16 KiB = 512 chunks of 16 B
    // (one async16 per thread). Thread -> (row r0 within half, swizzled k-chunk kc).
    const int r0 = tid >> 3;
    const int kc = (tid & 7) ^ (r0 & 7);

    // loop-invariant LDS read byte-addresses (buffer 0, frag 0); +mi*2048 per frag,
    // +32768 for buffer 1. slot = (ks*4+quad) ^ (row&7), row&7 == l15&7 for all frags.
    const unsigned asB = (unsigned)(size_t)&As[0][0];
    const unsigned bsB = (unsigned)(size_t)&Bs[0][0];
    const unsigned baseA0 = asB + (unsigned)(((wr * 128 + l15) * 8 + ((0 + quad) ^ (l15 & 7))) * 16);
    const unsigned baseA1 = asB + (unsigned)(((wr * 128 + l15) * 8 + ((4 + quad) ^ (l15 & 7))) * 16);
    const unsigned baseB0 = bsB + (unsigned)(((wc * 64  + l15) * 8 + ((0 + quad) ^ (l15 & 7))) * 16);
    const unsigned baseB1 = bsB + (unsigned)(((wc * 64  + l15) * 8 + ((4 + quad) ^ (l15 & 7))) * 16);

    f32x4 acc[8][4] = {};

    for (int seg = 0; seg < 2; ++seg){
        const unsigned short* A = seg ? A1 : A0;
        const unsigned short* B = seg ? B1 : B0;
        const int Kd = seg ? K1 : K0;
        if (Kd <= 0 || A == nullptr) continue;
        const int NT = Kd / 64;

        const size_t toff = (size_t)r0 * Kd + kc * 8;   // per-thread element offset
        const unsigned short* Abase = A + (size_t)bm * Kd + toff;
        const unsigned short* Bbase = B + (size_t)bn * Kd + toff;

        // ---- prologue: stage tiles 0 and 1 (8 loads each), wait tile 0 ----
        #pragma unroll
        for (int g = 0; g < 4; ++g) async16(Abase + (size_t)g * 64 * Kd,      &As[0][(g * 512 + tid) * 8]);
        #pragma unroll
        for (int g = 0; g < 4; ++g) async16(Bbase + (size_t)g * 64 * Kd,      &Bs[0][(g * 512 + tid) * 8]);
        if (NT > 1){
            #pragma unroll
            for (int g = 0; g < 4; ++g) async16(Abase + (size_t)g * 64 * Kd + 64, &As[1][(g * 512 + tid) * 8]);
            #pragma unroll
            for (int g = 0; g < 4; ++g) async16(Bbase + (size_t)g * 64 * Kd + 64, &Bs[1][(g * 512 + tid) * 8]);
            asm volatile("s_waitcnt vmcnt(8)" ::: "memory");   // tile 0 landed; tile 1 in flight
        } else {
            asm volatile("s_waitcnt vmcnt(0)" ::: "memory");
        }
        __builtin_amdgcn_s_barrier();

        for (int t = 0; t < NT; ++t){
            const unsigned bo = (unsigned)(t & 1) * 32768u;
            const int  kn = (t + 1) * 64;               // next tile's k column
            const int  bi = (t + 1) & 1;                // next tile's buffer (dead since t-1)
            const bool st = (t >= 1) && (t + 1 < NT);   // tile 0's successor staged by prologue
            short8 afr[4], bfr[4];

            // ---------- phase 0: ks0, m-frags 0..3 (8 reads; stage A-halves 0,1 + B-half 0)
            #pragma unroll
            for (int ni = 0; ni < 4; ++ni) bfr[ni] = dsr128(baseB0 + bo + ni * 2048);
            #pragma unroll
            for (int mi = 0; mi < 4; ++mi) afr[mi] = dsr128(baseA0 + bo + mi * 2048);
            if (st){
                async16(Abase + (size_t)0 * 64 * Kd + kn, &As[bi][(0 * 512 + tid) * 8]);
                async16(Abase + (size_t)1 * 64 * Kd + kn, &As[bi][(1 * 512 + tid) * 8]);
                async16(Bbase + (size_t)0 * 64 * Kd + kn, &Bs[bi][(0 * 512 + tid) * 8]);
            }
            __builtin_amdgcn_s_barrier();
            asm volatile("s_waitcnt lgkmcnt(0)" ::: "memory");
            __builtin_amdgcn_sched_barrier(0);
            __builtin_amdgcn_s_setprio(1);
            #pragma unroll
            for (int mi = 0; mi < 4; ++mi)
                #pragma unroll
                for (int ni = 0; ni < 4; ++ni)
                    acc[mi][ni] = __builtin_amdgcn_mfma_f32_16x16x32_bf16(
                        afr[mi], bfr[ni], acc[mi][ni], 0, 0, 0);
            __builtin_amdgcn_s_setprio(0);
            __builtin_amdgcn_s_barrier();

            // ---------- phase 1: ks0, m-frags 4..7 (4 reads; stage A-halves 2,3 + B-half 1)
            #pragma unroll
            for (int mi = 0; mi < 4; ++mi) afr[mi] = dsr128(baseA0 + bo + (4 + mi) * 2048);
            if (st){
                async16(Abase + (size_t)2 * 64 * Kd + kn, &As[bi][(2 * 512 + tid) * 8]);
                async16(Abase + (size_t)3 * 64 * Kd + kn, &As[bi][(3 * 512 + tid) * 8]);
                async16(Bbase + (size_t)1 * 64 * Kd + kn, &Bs[bi][(1 * 512 + tid) * 8]);
            }
            __builtin_amdgcn_s_barrier();
            asm volatile("s_waitcnt lgkmcnt(0)" ::: "memory");
            __builtin_amdgcn_sched_barrier(0);
            __builtin_amdgcn_s_setprio(1);
            #pragma unroll
            for (int mi = 0; mi < 4; ++mi)
                #pragma unroll
                for (int ni = 0; ni < 4; ++ni)
                    acc[4 + mi][ni] = __builtin_amdgcn_mfma_f32_16x16x32_bf16(
                        afr[mi], bfr[ni], acc[4 + mi][ni], 0, 0, 0);
            __builtin_amdgcn_s_setprio(0);
            __builtin_amdgcn_s_barrier();

            // ---------- phase 2: ks1, m-frags 0..3 (8 reads; stage B-halves 2,3)
            #pragma unroll
            for (int ni = 0; ni < 4; ++ni) bfr[ni] = dsr128(baseB1 + bo + ni * 2048);
            #pragma unroll
            for (int mi = 0; mi < 4; ++mi) afr[mi] = dsr128(baseA1 + bo + mi * 2048);
            if (st){
                async16(Bbase + (size_t)2 * 64 * Kd + kn, &Bs[bi][(2 * 512 + tid) * 8]);
                async16(Bbase + (size_t)3 * 64 * Kd + kn, &Bs[bi][(3 * 512 + tid) * 8]);
            }
            __builtin_amdgcn_s_barrier();
            asm volatile("s_waitcnt lgkmcnt(0)" ::: "memory");
            __builtin_amdgcn_sched_barrier(0);
            __builtin_amdgcn_s_setprio(1);
            #pragma unroll
            for (int mi = 0; mi < 4; ++mi)
                #pragma unroll
                for (int ni = 0; ni < 4; ++ni)
                    acc[mi][ni] = __builtin_amdgcn_mfma_f32_16x16x32_bf16(
                        afr[mi], bfr[ni], acc[mi][ni], 0, 0, 0);
            __builtin_amdgcn_s_setprio(0);
            __builtin_amdgcn_s_barrier();

            // ---------- phase 3: ks1, m-frags 4..7 (4 reads; no staging)
            #pragma unroll
            for (int mi = 0; mi < 4; ++mi) afr[mi] = dsr128(baseA1 + bo + (4 + mi) * 2048);
            __builtin_amdgcn_s_barrier();
            asm volatile("s_waitcnt lgkmcnt(0)" ::: "memory");
            __builtin_amdgcn_sched_barrier(0);
            __builtin_amdgcn_s_setprio(1);
            #pragma unroll
            for (int mi = 0; mi < 4; ++mi)
                #pragma unroll
                for (int ni = 0; ni < 4; ++ni)
                    acc[4 + mi][ni] = __builtin_amdgcn_mfma_f32_16x16x32_bf16(
                        afr[mi], bfr[ni], acc[4 + mi][ni], 0, 0, 0);
            __builtin_amdgcn_s_setprio(0);

            // ---------- tile boundary: wait tile t+1's loads (aged >=2 phases), publish
            if (t + 1 < NT){
                asm volatile("s_waitcnt vmcnt(0)" ::: "memory");
                __builtin_amdgcn_s_barrier();
            }
        }
        // segment end: all loads drained (last tile stages nothing); sync before restaging
        asm volatile("s_waitcnt vmcnt(0)" ::: "memory");
        __builtin_amdgcn_s_barrier();
    }

    // epilogue: C/D mapping col=lane&15, row=quad*4+reg
    #pragma unroll
    for (int ni = 0; ni < 4; ++ni){
        const int col = bn + wc * 64 + ni * 16 + l15;
        float bb = 0.f;
        if (bias0) bb += bias0[col];
        if (bias1) bb += bias1[col];
        #pragma unroll
        for (int mi = 0; mi < 8; ++mi){
            #pragma unroll
            for (int r = 0; r < 4; ++r){
                const int row = bm + wr * 128 + mi * 16 + quad * 4 + r;
                float v = acc[mi][ni][r] + bb;
                if (act == 2) v = mish_act(v);
                if (out_bf16) ((unsigned short*)Y)[(size_t)row * N + col] = f2bf(v);
                else          ((float*)Y)[(size_t)row * N + col] = v;
            }
        }
    }
}

// ---------------- fp32 GEMM (small projections):  Y = act(x @ W^T [+ bias]) ----------------
__global__ __launch_bounds__(256) void gemm_xwt(
    const float* __restrict__ A0, const float* __restrict__ B0, int K0,
    const float* __restrict__ bias0,
    float* __restrict__ Y, int N, int act)
{
    __shared__ float As[16][68];
    __shared__ float Bs[16][68];
    const int tid  = threadIdx.x;
    const int bm   = blockIdx.x * 64;
    const int bn   = blockIdx.y * 64;
    const int lrow = tid >> 2;
    const int lk4  = (tid & 3) * 4;
    const int tm   = (tid >> 4) * 4;
    const int tn   = (tid & 15) * 4;
    float acc[4][4] = {};

    const float* aptr = A0 + (size_t)(bm + lrow) * K0 + lk4;
    const float* bptr = B0 + (size_t)(bn + lrow) * K0 + lk4;
    for (int k0 = 0; k0 < K0; k0 += 16){
        const float4 av = *(const float4*)(aptr + k0);
        const float4 bv = *(const float4*)(bptr + k0);
        __syncthreads();
        As[lk4+0][lrow]=av.x; As[lk4+1][lrow]=av.y; As[lk4+2][lrow]=av.z; As[lk4+3][lrow]=av.w;
        Bs[lk4+0][lrow]=bv.x; Bs[lk4+1][lrow]=bv.y; Bs[lk4+2][lrow]=bv.z; Bs[lk4+3][lrow]=bv.w;
        __syncthreads();
        #pragma unroll
        for (int kk = 0; kk < 16; ++kk){
            const float4 a = *(const float4*)&As[kk][tm];
            const float4 b = *(const float4*)&Bs[kk][tn];
            acc[0][0] += a.x*b.x; acc[0][1] += a.x*b.y; acc[0][2] += a.x*b.z; acc[0][3] += a.x*b.w;
            acc[1][0] += a.y*b.x; acc[1][1] += a.y*b.y; acc[1][2] += a.y*b.z; acc[1][3] += a.y*b.w;
            acc[2][0] += a.z*b.x; acc[2][1] += a.z*b.y; acc[2][2] += a.z*b.z; acc[2][3] += a.z*b.w;
            acc[3][0] += a.w*b.x; acc[3][1] += a.w*b.y; acc[3][2] += a.w*b.z; acc[3][3] += a.w*b.w;
        }
    }
    float badd[4] = {0.f, 0.f, 0.f, 0.f};
    if (bias0){
        badd[0] = bias0[bn+tn+0]; badd[1] = bias0[bn+tn+1];
        badd[2] = bias0[bn+tn+2]; badd[3] = bias0[bn+tn+3];
    }
    #pragma unroll
    for (int i = 0; i < 4; ++i){
        float r0 = acc[i][0] + badd[0];
        float r1 = acc[i][1] + badd[1];
        float r2 = acc[i][2] + badd[2];
        float r3 = acc[i][3] + badd[3];
        if (act == 1){ r0 = phi_act(r0); r1 = phi_act(r1); r2 = phi_act(r2); r3 = phi_act(r3); }
        *(float4*)&Y[(size_t)(bm + tm + i) * N + bn + tn] = make_float4(r0, r1, r2, r3);
    }
}

// ---------------- segmented scan, pass A ----------------
__global__ __launch_bounds__(256) void scan_passA(
    const float* __restrict__ kbuf, const float* __restrict__ vbuf,
    const int* __restrict__ start,
    float* __restrict__ chunkS, float* __restrict__ chunkZ, int* __restrict__ chunkFlag)
{
    const int c   = blockIdx.x;
    const int tid = threadIdx.x;
    const int j   = tid >> 2;
    const int i0  = (tid & 3) * 16;
    __shared__ float k_lds[64], v_lds[64];
    float s_loc[16];
    #pragma unroll
    for (int e = 0; e < 16; ++e) s_loc[e] = 0.f;
    float z_loc = 0.f;
    int flag = 0;
    const int t0 = c * CLEN;
    for (int tt = 0; tt < CLEN; ++tt){
        const int t = t0 + tt;
        if (tid < 64)       k_lds[tid]      = kbuf[(size_t)t*K_DIM + tid];
        else if (tid < 128) v_lds[tid - 64] = vbuf[(size_t)t*V_DIM + tid - 64];
        __syncthreads();
        const int st = start[t];
        if (st){
            #pragma unroll
            for (int e = 0; e < 16; ++e) s_loc[e] = 0.f;
            z_loc = 0.f;
            flag = 1;
        }
        const float vj = v_lds[j];
        #pragma unroll
        for (int e = 0; e < 16; ++e) s_loc[e] += k_lds[i0 + e] * vj;
        if (tid < 64) z_loc += k_lds[tid];
        __syncthreads();
    }
    #pragma unroll
    for (int e = 0; e < 16; ++e) chunkS[(size_t)c*4096 + (i0 + e)*64 + j] = s_loc[e];
    if (tid < 64) chunkZ[c*64 + tid] = z_loc;
    if (tid == 0) chunkFlag[c] = flag;
}

// ---------------- pass B: exclusive cross-chunk combine ----------------
__global__ __launch_bounds__(256) void scan_passB(
    const float* __restrict__ chunkS, const float* __restrict__ chunkZ, const int* __restrict__ chunkFlag,
    const float* __restrict__ s0, const float* __restrict__ z0,
    float* __restrict__ carryS, float* __restrict__ carryZ)
{
    const int ij = blockIdx.x * 256 + threadIdx.x;
    float e = s0[ij];
    for (int c = 0; c < CHUNKS; ++c){
        carryS[(size_t)c*4096 + ij] = e;
        const int f   = chunkFlag[c];
        const float s = chunkS[(size_t)c*4096 + ij];
        e = f ? s : (e + s);
    }
    if (ij < 64){
        float ez = z0[ij];
        for (int c = 0; c < CHUNKS; ++c){
            carryZ[c*64 + ij] = ez;
            const int f   = chunkFlag[c];
            const float z = chunkZ[c*64 + ij];
            ez = f ? z : (ez + z);
        }
    }
}

// ---------------- pass C: replay with carry; emit s[t], z[t], att out (bf16) ----------------
__global__ __launch_bounds__(256) void scan_passC(
    const float* __restrict__ kbuf, const float* __restrict__ vbuf, const float* __restrict__ qbuf,
    const int* __restrict__ start,
    const float* __restrict__ carryS, const float* __restrict__ carryZ,
    float* __restrict__ s_out, float* __restrict__ z_out, unsigned short* __restrict__ attout)
{
    const int c   = blockIdx.x;
    const int tid = threadIdx.x;
    const int j   = tid >> 2;
    const int g   = tid & 3;
    const int i0  = g * 16;
    __shared__ float k_lds[64], v_lds[64], q_lds[64];
    __shared__ float numer_lds[64];
    __shared__ float stage[4096];
    float s_loc[16];
    #pragma unroll
    for (int e = 0; e < 16; ++e) s_loc[e] = carryS[(size_t)c*4096 + (i0 + e)*64 + j];
    float z_loc = (tid < 64) ? carryZ[c*64 + tid] : 0.f;

    const int t0 = c * CLEN;
    for (int tt = 0; tt < CLEN; ++tt){
        const int t = t0 + tt;
        if (tid < 64)       k_lds[tid]       = kbuf[(size_t)t*K_DIM + tid];
        else if (tid < 128) v_lds[tid - 64]  = vbuf[(size_t)t*V_DIM + tid - 64];
        else if (tid < 192) q_lds[tid - 128] = qbuf[(size_t)t*K_DIM + tid - 128];
        __syncthreads();
        const int st = start[t];
        if (st){
            #pragma unroll
            for (int e = 0; e < 16; ++e) s_loc[e] = 0.f;
        }
        const float vj = v_lds[j];
        float np = 0.f;
        #pragma unroll
        for (int e = 0; e < 16; ++e){
            s_loc[e] += k_lds[i0 + e] * vj;
            np += s_loc[e] * q_lds[i0 + e];
        }
        np += __shfl_down(np, 1, 64);
        np += __shfl_down(np, 2, 64);
        if (g == 0) numer_lds[j] = np;
        float denom = 1.f;
        if (tid < 64){
            z_loc = (st ? 0.f : z_loc) + k_lds[tid];
            z_out[(size_t)t*K_DIM + tid] = z_loc;
            float zs = z_loc;
            float qs = q_lds[tid];
            #pragma unroll
            for (int o = 32; o > 0; o >>= 1){
                zs += __shfl_down(zs, o, 64);
                qs += __shfl_down(qs, o, 64);
            }
            zs = __shfl(zs, 0, 64);
            qs = __shfl(qs, 0, 64);
            denom = fmaxf(zs * qs, 1e-6f);
        }
        #pragma unroll
        for (int e = 0; e < 16; ++e) stage[(i0 + e)*64 + j] = s_loc[e];
        __syncthreads();
        float4* so = (float4*)(s_out + (size_t)t*4096);
        const float4* stv = (const float4*)stage;
        #pragma unroll
        for (int r = 0; r < 4; ++r) so[tid + 256*r] = stv[tid + 256*r];
        if (tid < 64) attout[(size_t)t*V_DIM + tid] = f2bf(numer_lds[tid] / denom);
        __syncthreads();
    }
}

// ---------------- LayerNorm over H=4096, in place ----------------
__global__ __launch_bounds__(256) void ln_kernel(
    float* __restrict__ h, const float* __restrict__ g, const float* __restrict__ b)
{
    __shared__ float sm[4];
    const int t   = blockIdx.x;
    const int tid = threadIdx.x;
    float* row = h + (size_t)t * H_DIM;
    float4 v[4];
    float s = 0.f;
    #pragma unroll
    for (int r = 0; r < 4; ++r){
        v[r] = ((const float4*)row)[tid + 256*r];
        s += v[r].x + v[r].y + v[r].z + v[r].w;
    }
    #pragma unroll
    for (int o = 32; o > 0; o >>= 1) s += __shfl_down(s, o, 64);
    if ((tid & 63) == 0) sm[tid >> 6] = s;
    __syncthreads();
    const float mu = (sm[0] + sm[1] + sm[2] + sm[3]) * (1.f / H_DIM);
    __syncthreads();
    float sq = 0.f;
    #pragma unroll
    for (int r = 0; r < 4; ++r){
        float dx = v[r].x - mu, dy = v[r].y - mu, dz = v[r].z - mu, dw = v[r].w - mu;
        sq += dx*dx + dy*dy + dz*dz + dw*dw;
    }
    #pragma unroll
    for (int o = 32; o > 0; o >>= 1) sq += __shfl_down(sq, o, 64);
    if ((tid & 63) == 0) sm[tid >> 6] = sq;
    __syncthreads();
    const float var = (sm[0] + sm[1] + sm[2] + sm[3]) * (1.f / H_DIM);
    const float inv = rsqrtf(var + 1e-5f);
    #pragma unroll
    for (int r = 0; r < 4; ++r){
        const int i4 = tid + 256*r;
        const float4 gg = ((const float4*)g)[i4];
        const float4 bb = ((const float4*)b)[i4];
        float4 o;
        o.x = (v[r].x - mu) * inv * gg.x + bb.x;
        o.y = (v[r].y - mu) * inv * gg.y + bb.y;
        o.z = (v[r].z - mu) * inv * gg.z + bb.z;
        o.w = (v[r].w - mu) * inv * gg.w + bb.w;
        ((float4*)row)[i4] = o;
    }
}

extern "C" void kernel_launch(void* const* d_in, const int* in_sizes, int n_in,
                              void* d_out, int out_size, void* d_ws, size_t ws_size,
                              hipStream_t stream)
{
    (void)in_sizes; (void)n_in; (void)out_size; (void)ws_size;
    const float* x     = (const float*)d_in[0];
    const float* s0    = (const float*)d_in[1];
    const float* z0    = (const float*)d_in[2];
    const int*   start = (const int*)d_in[3];
    const float* Wk    = (const float*)d_in[5];
    const float* Wq    = (const float*)d_in[6];
    const float* Wv    = (const float*)d_in[7];
    const float* bv    = (const float*)d_in[8];
    const float* Wskip = (const float*)d_in[9];
    const float* bskip = (const float*)d_in[10];
    const float* W1    = (const float*)d_in[11];
    const float* b1    = (const float*)d_in[12];
    const float* W2    = (const float*)d_in[13];
    const float* b2    = (const float*)d_in[14];
    const float* W3    = (const float*)d_in[15];
    const float* b3    = (const float*)d_in[16];
    const float* ln_g  = (const float*)d_in[17];
    const float* ln_b  = (const float*)d_in[18];

    // ---- workspace carve (256B-aligned), total ~148 MB ----
    char* p = (char*)d_ws;
    auto alloc = [&](size_t bytes) -> void* {
        void* r = (void*)p; p += (bytes + 255) & ~(size_t)255; return r;
    };
    float* kbuf  = (float*)alloc((size_t)T_DIM * K_DIM * 4);
    float* qbuf  = (float*)alloc((size_t)T_DIM * K_DIM * 4);
    float* vbuf  = (float*)alloc((size_t)T_DIM * V_DIM * 4);
    float* chS   = (float*)alloc((size_t)CHUNKS * 4096 * 4);
    float* chZ   = (float*)alloc((size_t)CHUNKS * 64 * 4);
    float* caS   = (float*)alloc((size_t)CHUNKS * 4096 * 4);
    float* caZ   = (float*)alloc((size_t)CHUNKS * 64 * 4);
    int*   flags = (int*)  alloc((size_t)CHUNKS * 4);
    unsigned short* xb     = (unsigned short*)alloc((size_t)T_DIM * IN_DIM * 2);
    unsigned short* Wskipb = (unsigned short*)alloc((size_t)H_DIM * IN_DIM * 2);
    unsigned short* W1b    = (unsigned short*)alloc((size_t)H_DIM * V_DIM * 2);
    unsigned short* W2b    = (unsigned short*)alloc((size_t)H_DIM * H_DIM * 2);
    unsigned short* W3b    = (unsigned short*)alloc((size_t)H_DIM * H_DIM * 2);
    unsigned short* attb   = (unsigned short*)alloc((size_t)T_DIM * V_DIM * 2);
    unsigned short* h1b    = (unsigned short*)alloc((size_t)T_DIM * H_DIM * 2);
    unsigned short* h2b    = (unsigned short*)alloc((size_t)T_DIM * H_DIM * 2);

    float* hn  = (float*)d_out;                          // (T,H)
    float* s_o = hn  + (size_t)T_DIM * H_DIM;            // (T,K,V)
    float* z_o = s_o + (size_t)T_DIM * K_DIM * V_DIM;    // (T,1,K)

    // 0) bf16 conversions of GEMM inputs (independent; launch up front)
    cvt_bf16<<<(T_DIM*IN_DIM/4 + 255)/256, 256, 0, stream>>>(x, xb, T_DIM*IN_DIM/4);
    cvt_bf16<<<(H_DIM*IN_DIM/4 + 255)/256, 256, 0, stream>>>(Wskip, Wskipb, H_DIM*IN_DIM/4);
    cvt_bf16<<<(H_DIM*V_DIM/4 + 255)/256, 256, 0, stream>>>(W1, W1b, H_DIM*V_DIM/4);
    cvt_bf16<<<(H_DIM*H_DIM/4 + 255)/256, 256, 0, stream>>>(W2, W2b, H_DIM*H_DIM/4);
    cvt_bf16<<<(H_DIM*H_DIM/4 + 255)/256, 256, 0, stream>>>(W3, W3b, H_DIM*H_DIM/4);

    // 1) projections (fp32): k = phi(x@Wk^T), q = phi(x@Wq^T), v = x@Wv^T + bv
    gemm_xwt<<<dim3(T_DIM/64, K_DIM/64), 256, 0, stream>>>(x, Wk, IN_DIM, nullptr, kbuf, K_DIM, 1);
    gemm_xwt<<<dim3(T_DIM/64, K_DIM/64), 256, 0, stream>>>(x, Wq, IN_DIM, nullptr, qbuf, K_DIM, 1);
    gemm_xwt<<<dim3(T_DIM/64, V_DIM/64), 256, 0, stream>>>(x, Wv, IN_DIM, bv, vbuf, V_DIM, 0);

    // 2) segmented scan (3 passes); pass C emits att in bf16
    scan_passA<<<CHUNKS, 256, 0, stream>>>(kbuf, vbuf, start, chS, chZ, flags);
    scan_passB<<<4096/256, 256, 0, stream>>>(chS, chZ, flags, s0, z0, caS, caZ);
    scan_passC<<<CHUNKS, 256, 0, stream>>>(kbuf, vbuf, qbuf, start, caS, caZ, s_o, z_o, attb);

    // 3) MLP: GEMM1 (K=64) on the 128^2 kernel; big GEMMs on the 4-phase pipelined 256^2.
    gemm_mfma_bt<<<dim3(T_DIM/128, H_DIM/128), 256, 0, stream>>>(
        attb, W1b, V_DIM, nullptr, nullptr, 0, b1, nullptr, h1b, H_DIM, 2, 1);
    gemm256p<<<dim3(T_DIM/256, H_DIM/256), 512, 0, stream>>>(
        h1b, W2b, H_DIM, nullptr, nullptr, 0, b2, nullptr, h2b, H_DIM, 2, 1);
    // GEMM3 fused with skip: hn = h2@W3^T + x@Wskip^T + b3 + bskip (fp32 out)
    gemm256p<<<dim3(T_DIM/256, H_DIM/256), 512, 0, stream>>>(
        h2b, W3b, H_DIM, xb, Wskipb, IN_DIM, b3, bskip, hn, H_DIM, 0, 0);

    // 4) LayerNorm in place on d_out
    ln_kernel<<<T_DIM, 256, 0, stream>>>(hn, ln_g, ln_b);
}

// Round 4
// 853.743 us; speedup vs baseline: 1.2151x; 1.0316x over previous
//
#include <hip/hip_runtime.h>
#include <math.h>

// Problem constants (from reference): T=4096, IN=512, K=64, V=64, H=4096
#define T_DIM 4096
#define IN_DIM 512
#define K_DIM 64
#define V_DIM 64
#define H_DIM 4096
#define CHUNKS 256
#define CLEN 16   // T_DIM / CHUNKS

typedef __attribute__((ext_vector_type(8))) short short8;  // 8 bf16 = 4 VGPRs
typedef __attribute__((ext_vector_type(4))) float f32x4;

// ---------------- activations ----------------
__device__ __forceinline__ float phi_act(float v){
    return v > 0.f ? (v + 1.f) : (expm1f(v) + 1.f);
}
__device__ __forceinline__ float mish_act(float v){
    float sp = fmaxf(v, 0.f) + log1pf(expf(-fabsf(v)));
    return v * tanhf(sp);
}
// fp32 -> bf16 round-to-nearest-even (bit trick)
__device__ __forceinline__ unsigned short f2bf(float f){
    union { float f; unsigned int u; } x; x.f = f;
    unsigned int u = x.u + 0x7fffu + ((x.u >> 16) & 1u);
    return (unsigned short)(u >> 16);
}

// async 16B global->LDS (dest = wave-uniform base + lane*16; layout must be contiguous per lane)
__device__ __forceinline__ void async16(const unsigned short* g, unsigned short* l){
    __builtin_amdgcn_global_load_lds(
        (const __attribute__((address_space(1))) unsigned int*)g,
        (__attribute__((address_space(3))) unsigned int*)l,
        16, 0, 0);
}

// inline-asm ds_read_b128 with compile-time immediate offset. Opaque to the
// compiler's waitcnt insertion -> we control lgkmcnt/vmcnt entirely; offset:imm
// keeps address VALU at zero inside the K-loop.
__device__ __forceinline__ short8 dsr128o(unsigned addr, int off){
    short8 d;
    asm volatile("ds_read_b128 %0, %1 offset:%2" : "=v"(d) : "v"(addr), "i"(off));
    return d;
}

#define LGKM(n)  asm volatile("s_waitcnt lgkmcnt(" #n ")" ::: "memory")
#define VMCNT(n) asm volatile("s_waitcnt vmcnt(" #n ")" ::: "memory")

// ---------------- fp32 -> bf16 conversion, 4 elems/thread ----------------
__global__ __launch_bounds__(256) void cvt_bf16(const float* __restrict__ in,
                                                unsigned short* __restrict__ out, int n4){
    int i = blockIdx.x * 256 + threadIdx.x;
    if (i >= n4) return;
    float4 v = ((const float4*)in)[i];
    ushort4 o;
    o.x = f2bf(v.x); o.y = f2bf(v.y); o.z = f2bf(v.z); o.w = f2bf(v.w);
    ((ushort4*)out)[i] = o;
}

// ---------------- bf16 MFMA GEMM (128x128 tile, m97 structure) ----------------
// Kept for the small-K GEMM1 (K=64): 2 blocks/CU co-residency hides its staging drains.
__global__ __launch_bounds__(256) void gemm_mfma_bt(
    const unsigned short* __restrict__ A0, const unsigned short* __restrict__ B0, int K0,
    const unsigned short* __restrict__ A1, const unsigned short* __restrict__ B1, int K1,
    const float* __restrict__ bias0, const float* __restrict__ bias1,
    void* __restrict__ Y, int N, int act, int out_bf16)
{
    constexpr int BK = 64;
    __shared__ unsigned short As[128 * BK];
    __shared__ unsigned short Bs[128 * BK];
    const int tid  = threadIdx.x;
    const int lane = tid & 63;
    const int wm   = (tid >> 6 & 1) * 64;     // wave m-offset in tile
    const int wn   = (tid >> 7) * 64;         // wave n-offset in tile
    const int bm   = blockIdx.x * 128;
    const int bn   = blockIdx.y * 128;
    const int l15  = lane & 15;
    const int quad = lane >> 4;

    f32x4 acc[4][4] = {};

    for (int seg = 0; seg < 2; ++seg){
        const unsigned short* A = seg ? A1 : A0;
        const unsigned short* B = seg ? B1 : B0;
        const int Kd = seg ? K1 : K0;
        if (Kd <= 0 || A == nullptr) continue;
        for (int k0 = 0; k0 < Kd; k0 += BK){
            __syncthreads();  // previous tile's ds_reads must drain before restage
            #pragma unroll
            for (int it = 0; it < 4; ++it){   // 1024 chunks of 16B per matrix, 4 per thread
                const int c  = it * 256 + tid;        // LDS chunk index (byte off = c*16)
                const int r  = c >> 3;                // row 0..127
                const int kc = (c & 7) ^ (r & 7);     // swizzled global k-chunk
                async16(A + (size_t)(bm + r) * Kd + k0 + kc * 8, &As[c * 8]);
            }
            #pragma unroll
            for (int it = 0; it < 4; ++it){
                const int c  = it * 256 + tid;
                const int r  = c >> 3;
                const int kc = (c & 7) ^ (r & 7);
                async16(B + (size_t)(bn + r) * Kd + k0 + kc * 8, &Bs[c * 8]);
            }
            __syncthreads();  // s_waitcnt vmcnt(0) before s_barrier -> staging complete
            #pragma unroll
            for (int ks = 0; ks < 2; ++ks){
                short8 af[4], bf[4];
                #pragma unroll
                for (int mi = 0; mi < 4; ++mi){
                    const int row = wm + mi * 16 + l15;
                    const int kq  = ks * 4 + quad;            // k-chunk 0..7
                    af[mi] = *(const short8*)&As[(row * 8 + (kq ^ (row & 7))) * 8];
                }
                #pragma unroll
                for (int ni = 0; ni < 4; ++ni){
                    const int row = wn + ni * 16 + l15;
                    const int kq  = ks * 4 + quad;
                    bf[ni] = *(const short8*)&Bs[(row * 8 + (kq ^ (row & 7))) * 8];
                }
                #pragma unroll
                for (int mi = 0; mi < 4; ++mi)
                    #pragma unroll
                    for (int ni = 0; ni < 4; ++ni)
                        acc[mi][ni] = __builtin_amdgcn_mfma_f32_16x16x32_bf16(
                            af[mi], bf[ni], acc[mi][ni], 0, 0, 0);
            }
        }
    }

    // epilogue: C/D mapping col=lane&15, row=quad*4+reg
    #pragma unroll
    for (int ni = 0; ni < 4; ++ni){
        const int col = bn + wn + ni * 16 + l15;
        float bb = 0.f;
        if (bias0) bb += bias0[col];
        if (bias1) bb += bias1[col];
        #pragma unroll
        for (int mi = 0; mi < 4; ++mi){
            #pragma unroll
            for (int r = 0; r < 4; ++r){
                const int row = bm + wm + mi * 16 + quad * 4 + r;
                float v = acc[mi][ni][r] + bb;
                if (act == 2) v = mish_act(v);
                if (out_bf16) ((unsigned short*)Y)[(size_t)row * N + col] = f2bf(v);
                else          ((float*)Y)[(size_t)row * N + col] = v;
            }
        }
    }
}

// ---------------- 256x256 wave-pipelined bf16 MFMA GEMM ----------------
// BM=BN=256, BK=64, double-buffered LDS (128 KiB, 1 block/CU). 512 threads = 8 waves
// (2M x 4N); per-wave output 128x64 = acc f32x4[8][4] (AGPR).
//
// ONE barrier per K-tile. Within a tile there is no inter-wave LDS hazard (reads hit
// buf t&1, staging writes buf t^1), so phase-lockstep barriers are unnecessary.
// Per-wave schedule with counted lgkmcnt (DS completes in-order per wave):
//   stage all 8 global_load_lds of tile t+1   (max aging: a full tile before use)
//   issue 12 ds_read_b128 (B0,A0ks0m03,A1ks0m47) -> lgkm(8)  -> 16 MFMA (acc[0:4] x B0)
//   issue  8 reads (B1, A-ks1m03)              -> lgkm(8)  -> 16 MFMA (acc[4:8] x B0)
//   issue  4 reads (A-ks1m47)                  -> lgkm(4)  -> 16 MFMA (acc[0:4] x B1)
//                                                 lgkm(0)  -> 16 MFMA (acc[4:8] x B1)
//   vmcnt(0)  (own tile-t+1 loads, aged ~2500 cyc)  ;  s_barrier (publishes to all)
// Each read-group issues right after the previous MFMA cluster -> executes under the
// matrix pipe; across the 2 waves/SIMD, skew + setprio keep the MFMA pipe fed.
// rule #18: sched_barrier(0) after every counted lgkmcnt.
// ds_read offsets are imm (offset:N) off 4 base VGPRs -> zero address VALU in loop.
// Swizzle (proven 0-conflict): slot s of row r holds k-chunk s^(r&7); linear LDS dest,
// pre-swizzled source, reads XOR the same pattern.
// Two K-segments (A0,B0,K0)+(A1,B1,K1) accumulate into the same acc (fuses skip-GEMM).
__global__ __launch_bounds__(512, 2) void gemm256p(
    const unsigned short* __restrict__ A0, const unsigned short* __restrict__ B0, int K0,
    const unsigned short* __restrict__ A1, const unsigned short* __restrict__ B1, int K1,
    const float* __restrict__ bias0, const float* __restrict__ bias1,
    void* __restrict__ Y, int N, int act, int out_bf16)
{
    __shared__ unsigned short As[2][16384];   // 2 x 32 KiB
    __shared__ unsigned short Bs[2][16384];   // 2 x 32 KiB
    const int tid  = threadIdx.x;
    const int lane = tid & 63;
    const int w    = tid >> 6;          // wave 0..7
    const int wr   = w >> 2;            // 0..1  (M half)
    const int wc   = w & 3;             // 0..3  (N quarter)
    const int l15  = lane & 15;
    const int quad = lane >> 4;

    // Bijective XCD-aware swizzle for the 16x16 grid: XCD x owns a 4(M) x 8(N) patch.
    int bx = blockIdx.x, by = blockIdx.y;
    if (gridDim.x == 16 && gridDim.y == 16){
        const int id  = by * 16 + bx;       // dispatch-linear (blockIdx.x fastest)
        const int xcd = id & 7;             // default round-robin XCD assignment
        const int loc = id >> 3;            // 0..31 within XCD
        bx = (xcd & 3) * 4 + (loc & 3);
        by = (xcd >> 2) * 8 + (loc >> 2);
    }
    const int bm = bx * 256;
    const int bn = by * 256;

    // staging geometry: thread owns chunk g*512+tid of each 2048-chunk tile (16 B each);
    // row = g*64 + (tid>>3), swizzled k-chunk kc = (tid&7) ^ (row&7).
    const int r0 = tid >> 3;
    const int kc = (tid & 7) ^ (r0 & 7);

    // loop-invariant LDS read bases (buffer 0); frag mi at +mi*2048, buffer 1 at +32768.
    const unsigned asB = (unsigned)(size_t)&As[0][0];
    const unsigned bsB = (unsigned)(size_t)&Bs[0][0];
    const unsigned bA0 = asB + (unsigned)(((wr * 128 + l15) * 8 + ((0 + quad) ^ (l15 & 7))) * 16);
    const unsigned bA1 = asB + (unsigned)(((wr * 128 + l15) * 8 + ((4 + quad) ^ (l15 & 7))) * 16);
    const unsigned bB0 = bsB + (unsigned)(((wc * 64  + l15) * 8 + ((0 + quad) ^ (l15 & 7))) * 16);
    const unsigned bB1 = bsB + (unsigned)(((wc * 64  + l15) * 8 + ((4 + quad) ^ (l15 & 7))) * 16);

    f32x4 acc[8][4] = {};

    for (int seg = 0; seg < 2; ++seg){
        const unsigned short* A = seg ? A1 : A0;
        const unsigned short* B = seg ? B1 : B0;
        const int Kd = seg ? K1 : K0;
        if (Kd <= 0 || A == nullptr) continue;
        const int NT = Kd / 64;
        const size_t gstride = (size_t)64 * Kd;
        const unsigned short* pA = A + (size_t)bm * Kd + (size_t)r0 * Kd + kc * 8;
        const unsigned short* pB = B + (size_t)bn * Kd + (size_t)r0 * Kd + kc * 8;

        // ---- prologue: stage tile 0 into buf0, drain, publish ----
        #pragma unroll
        for (int g = 0; g < 4; ++g) async16(pA + g * gstride, &As[0][(g * 512 + tid) * 8]);
        #pragma unroll
        for (int g = 0; g < 4; ++g) async16(pB + g * gstride, &Bs[0][(g * 512 + tid) * 8]);
        VMCNT(0);
        __builtin_amdgcn_s_barrier();

        for (int t = 0; t < NT; ++t){
            const unsigned bo = (unsigned)(t & 1) * 32768u;
            const unsigned aA0 = bA0 + bo, aA1 = bA1 + bo, aB0 = bB0 + bo, aB1 = bB1 + bo;
            short8 fa0[4], fa1[4], fb0[4], fb1[4];

            // reads for cluster 0/1 (12 DS outstanding)
            #pragma unroll
            for (int ni = 0; ni < 4; ++ni) fb0[ni] = dsr128o(aB0, ni * 2048);
            #pragma unroll
            for (int mi = 0; mi < 4; ++mi) fa0[mi] = dsr128o(aA0, mi * 2048);
            // stage tile t+1 into the other buffer (earliest legal point)
            if (t + 1 < NT){
                const int bi = (t + 1) & 1;
                const int kn = (t + 1) * 64;
                #pragma unroll
                for (int g = 0; g < 4; ++g) async16(pA + g * gstride + kn, &As[bi][(g * 512 + tid) * 8]);
                #pragma unroll
                for (int g = 0; g < 4; ++g) async16(pB + g * gstride + kn, &Bs[bi][(g * 512 + tid) * 8]);
            }
            #pragma unroll
            for (int mi = 0; mi < 4; ++mi) fa1[mi] = dsr128o(aA0, (4 + mi) * 2048);

            LGKM(8);                                   // fb0 + fa0 landed
            __builtin_amdgcn_sched_barrier(0);
            __builtin_amdgcn_s_setprio(1);
            #pragma unroll
            for (int mi = 0; mi < 4; ++mi)
                #pragma unroll
                for (int ni = 0; ni < 4; ++ni)
                    acc[mi][ni] = __builtin_amdgcn_mfma_f32_16x16x32_bf16(
                        fa0[mi], fb0[ni], acc[mi][ni], 0, 0, 0);
            __builtin_amdgcn_s_setprio(0);

            // reads for cluster 2 (execute under cluster-0/1 MFMA)
            #pragma unroll
            for (int ni = 0; ni < 4; ++ni) fb1[ni] = dsr128o(aB1, ni * 2048);
            #pragma unroll
            for (int mi = 0; mi < 4; ++mi) fa0[mi] = dsr128o(aA1, mi * 2048);

            LGKM(8);                                   // fa1 landed
            __builtin_amdgcn_sched_barrier(0);
            __builtin_amdgcn_s_setprio(1);
            #pragma unroll
            for (int mi = 0; mi < 4; ++mi)
                #pragma unroll
                for (int ni = 0; ni < 4; ++ni)
                    acc[4 + mi][ni] = __builtin_amdgcn_mfma_f32_16x16x32_bf16(
                        fa1[mi], fb0[ni], acc[4 + mi][ni], 0, 0, 0);
            __builtin_amdgcn_s_setprio(0);

            // reads for cluster 3
            #pragma unroll
            for (int mi = 0; mi < 4; ++mi) fa1[mi] = dsr128o(aA1, (4 + mi) * 2048);

            LGKM(4);                                   // fb1 + fa0(ks1) landed
            __builtin_amdgcn_sched_barrier(0);
            __builtin_amdgcn_s_setprio(1);
            #pragma unroll
            for (int mi = 0; mi < 4; ++mi)
                #pragma unroll
                for (int ni = 0; ni < 4; ++ni)
                    acc[mi][ni] = __builtin_amdgcn_mfma_f32_16x16x32_bf16(
                        fa0[mi], fb1[ni], acc[mi][ni], 0, 0, 0);
            __builtin_amdgcn_s_setprio(0);

            LGKM(0);                                   // fa1(ks1) landed
            __builtin_amdgcn_sched_barrier(0);
            __builtin_amdgcn_s_setprio(1);
            #pragma unroll
            for (int mi = 0; mi < 4; ++mi)
                #pragma unroll
                for (int ni = 0; ni < 4; ++ni)
                    acc[4 + mi][ni] = __builtin_amdgcn_mfma_f32_16x16x32_bf16(
                        fa1[mi], fb1[ni], acc[4 + mi][ni], 0, 0, 0);
            __builtin_amdgcn_s_setprio(0);

            // tile boundary: own tile-t+1 loads drained (aged a full tile), then publish.
            VMCNT(0);
            __builtin_amdgcn_s_barrier();
        }
    }

    // epilogue: C/D mapping col=lane&15, row=quad*4+reg
    #pragma unroll
    for (int ni = 0; ni < 4; ++ni){
        const int col = bn + wc * 64 + ni * 16 + l15;
        float bb = 0.f;
        if (bias0) bb += bias0[col];
        if (bias1) bb += bias1[col];
        #pragma unroll
        for (int mi = 0; mi < 8; ++mi){
            #pragma unroll
            for (int r = 0; r < 4; ++r){
                const int row = bm + wr * 128 + mi * 16 + quad * 4 + r;
                float v = acc[mi][ni][r] + bb;
                if (act == 2) v = mish_act(v);
                if (out_bf16) ((unsigned short*)Y)[(size_t)row * N + col] = f2bf(v);
                else          ((float*)Y)[(size_t)row * N + col] = v;
            }
        }
    }
}

// ---------------- fp32 GEMM (small projections):  Y = act(x @ W^T [+ bias]) ----------------
__global__ __launch_bounds__(256) void gemm_xwt(
    const float* __restrict__ A0, const float* __restrict__ B0, int K0,
    const float* __restrict__ bias0,
    float* __restrict__ Y, int N, int act)
{
    __shared__ float As[16][68];
    __shared__ float Bs[16][68];
    const int tid  = threadIdx.x;
    const int bm   = blockIdx.x * 64;
    const int bn   = blockIdx.y * 64;
    const int lrow = tid >> 2;
    const int lk4  = (tid & 3) * 4;
    const int tm   = (tid >> 4) * 4;
    const int tn   = (tid & 15) * 4;
    float acc[4][4] = {};

    const float* aptr = A0 + (size_t)(bm + lrow) * K0 + lk4;
    const float* bptr = B0 + (size_t)(bn + lrow) * K0 + lk4;
    for (int k0 = 0; k0 < K0; k0 += 16){
        const float4 av = *(const float4*)(aptr + k0);
        const float4 bv = *(const float4*)(bptr + k0);
        __syncthreads();
        As[lk4+0][lrow]=av.x; As[lk4+1][lrow]=av.y; As[lk4+2][lrow]=av.z; As[lk4+3][lrow]=av.w;
        Bs[lk4+0][lrow]=bv.x; Bs[lk4+1][lrow]=bv.y; Bs[lk4+2][lrow]=bv.z; Bs[lk4+3][lrow]=bv.w;
        __syncthreads();
        #pragma unroll
        for (int kk = 0; kk < 16; ++kk){
            const float4 a = *(const float4*)&As[kk][tm];
            const float4 b = *(const float4*)&Bs[kk][tn];
            acc[0][0] += a.x*b.x; acc[0][1] += a.x*b.y; acc[0][2] += a.x*b.z; acc[0][3] += a.x*b.w;
            acc[1][0] += a.y*b.x; acc[1][1] += a.y*b.y; acc[1][2] += a.y*b.z; acc[1][3] += a.y*b.w;
            acc[2][0] += a.z*b.x; acc[2][1] += a.z*b.y; acc[2][2] += a.z*b.z; acc[2][3] += a.z*b.w;
            acc[3][0] += a.w*b.x; acc[3][1] += a.w*b.y; acc[3][2] += a.w*b.z; acc[3][3] += a.w*b.w;
        }
    }
    float badd[4] = {0.f, 0.f, 0.f, 0.f};
    if (bias0){
        badd[0] = bias0[bn+tn+0]; badd[1] = bias0[bn+tn+1];
        badd[2] = bias0[bn+tn+2]; badd[3] = bias0[bn+tn+3];
    }
    #pragma unroll
    for (int i = 0; i < 4; ++i){
        float r0 = acc[i][0] + badd[0];
        float r1 = acc[i][1] + badd[1];
        float r2 = acc[i][2] + badd[2];
        float r3 = acc[i][3] + badd[3];
        if (act == 1){ r0 = phi_act(r0); r1 = phi_act(r1); r2 = phi_act(r2); r3 = phi_act(r3); }
        *(float4*)&Y[(size_t)(bm + tm + i) * N + bn + tn] = make_float4(r0, r1, r2, r3);
    }
}

// ---------------- segmented scan, pass A ----------------
__global__ __launch_bounds__(256) void scan_passA(
    const float* __restrict__ kbuf, const float* __restrict__ vbuf,
    const int* __restrict__ start,
    float* __restrict__ chunkS, float* __restrict__ chunkZ, int* __restrict__ chunkFlag)
{
    const int c   = blockIdx.x;
    const int tid = threadIdx.x;
    const int j   = tid >> 2;
    const int i0  = (tid & 3) * 16;
    __shared__ float k_lds[64], v_lds[64];
    float s_loc[16];
    #pragma unroll
    for (int e = 0; e < 16; ++e) s_loc[e] = 0.f;
    float z_loc = 0.f;
    int flag = 0;
    const int t0 = c * CLEN;
    for (int tt = 0; tt < CLEN; ++tt){
        const int t = t0 + tt;
        if (tid < 64)       k_lds[tid]      = kbuf[(size_t)t*K_DIM + tid];
        else if (tid < 128) v_lds[tid - 64] = vbuf[(size_t)t*V_DIM + tid - 64];
        __syncthreads();
        const int st = start[t];
        if (st){
            #pragma unroll
            for (int e = 0; e < 16; ++e) s_loc[e] = 0.f;
            z_loc = 0.f;
            flag = 1;
        }
        const float vj = v_lds[j];
        #pragma unroll
        for (int e = 0; e < 16; ++e) s_loc[e] += k_lds[i0 + e] * vj;
        if (tid < 64) z_loc += k_lds[tid];
        __syncthreads();
    }
    #pragma unroll
    for (int e = 0; e < 16; ++e) chunkS[(size_t)c*4096 + (i0 + e)*64 + j] = s_loc[e];
    if (tid < 64) chunkZ[c*64 + tid] = z_loc;
    if (tid == 0) chunkFlag[c] = flag;
}

// ---------------- pass B: exclusive cross-chunk combine ----------------
__global__ __launch_bounds__(256) void scan_passB(
    const float* __restrict__ chunkS, const float* __restrict__ chunkZ, const int* __restrict__ chunkFlag,
    const float* __restrict__ s0, const float* __restrict__ z0,
    float* __restrict__ carryS, float* __restrict__ carryZ)
{
    const int ij = blockIdx.x * 256 + threadIdx.x;
    float e = s0[ij];
    for (int c = 0; c < CHUNKS; ++c){
        carryS[(size_t)c*4096 + ij] = e;
        const int f   = chunkFlag[c];
        const float s = chunkS[(size_t)c*4096 + ij];
        e = f ? s : (e + s);
    }
    if (ij < 64){
        float ez = z0[ij];
        for (int c = 0; c < CHUNKS; ++c){
            carryZ[c*64 + ij] = ez;
            const int f   = chunkFlag[c];
            const float z = chunkZ[c*64 + ij];
            ez = f ? z : (ez + z);
        }
    }
}

// ---------------- pass C: replay with carry; emit s[t], z[t], att out (bf16) ----------------
__global__ __launch_bounds__(256) void scan_passC(
    const float* __restrict__ kbuf, const float* __restrict__ vbuf, const float* __restrict__ qbuf,
    const int* __restrict__ start,
    const float* __restrict__ carryS, const float* __restrict__ carryZ,
    float* __restrict__ s_out, float* __restrict__ z_out, unsigned short* __restrict__ attout)
{
    const int c   = blockIdx.x;
    const int tid = threadIdx.x;
    const int j   = tid >> 2;
    const int g   = tid & 3;
    const int i0  = g * 16;
    __shared__ float k_lds[64], v_lds[64], q_lds[64];
    __shared__ float numer_lds[64];
    __shared__ float stage[4096];
    float s_loc[16];
    #pragma unroll
    for (int e = 0; e < 16; ++e) s_loc[e] = carryS[(size_t)c*4096 + (i0 + e)*64 + j];
    float z_loc = (tid < 64) ? carryZ[c*64 + tid] : 0.f;

    const int t0 = c * CLEN;
    for (int tt = 0; tt < CLEN; ++tt){
        const int t = t0 + tt;
        if (tid < 64)       k_lds[tid]       = kbuf[(size_t)t*K_DIM + tid];
        else if (tid < 128) v_lds[tid - 64]  = vbuf[(size_t)t*V_DIM + tid - 64];
        else if (tid < 192) q_lds[tid - 128] = qbuf[(size_t)t*K_DIM + tid - 128];
        __syncthreads();
        const int st = start[t];
        if (st){
            #pragma unroll
            for (int e = 0; e < 16; ++e) s_loc[e] = 0.f;
        }
        const float vj = v_lds[j];
        float np = 0.f;
        #pragma unroll
        for (int e = 0; e < 16; ++e){
            s_loc[e] += k_lds[i0 + e] * vj;
            np += s_loc[e] * q_lds[i0 + e];
        }
        np += __shfl_down(np, 1, 64);
        np += __shfl_down(np, 2, 64);
        if (g == 0) numer_lds[j] = np;
        float denom = 1.f;
        if (tid < 64){
            z_loc = (st ? 0.f : z_loc) + k_lds[tid];
            z_out[(size_t)t*K_DIM + tid] = z_loc;
            float zs = z_loc;
            float qs = q_lds[tid];
            #pragma unroll
            for (int o = 32; o > 0; o >>= 1){
                zs += __shfl_down(zs, o, 64);
                qs += __shfl_down(qs, o, 64);
            }
            zs = __shfl(zs, 0, 64);
            qs = __shfl(qs, 0, 64);
            denom = fmaxf(zs * qs, 1e-6f);
        }
        #pragma unroll
        for (int e = 0; e < 16; ++e) stage[(i0 + e)*64 + j] = s_loc[e];
        __syncthreads();
        float4* so = (float4*)(s_out + (size_t)t*4096);
        const float4* stv = (const float4*)stage;
        #pragma unroll
        for (int r = 0; r < 4; ++r) so[tid + 256*r] = stv[tid + 256*r];
        if (tid < 64) attout[(size_t)t*V_DIM + tid] = f2bf(numer_lds[tid] / denom);
        __syncthreads();
    }
}

// ---------------- LayerNorm over H=4096, in place ----------------
__global__ __launch_bounds__(256) void ln_kernel(
    float* __restrict__ h, const float* __restrict__ g, const float* __restrict__ b)
{
    __shared__ float sm[4];
    const int t   = blockIdx.x;
    const int tid = threadIdx.x;
    float* row = h + (size_t)t * H_DIM;
    float4 v[4];
    float s = 0.f;
    #pragma unroll
    for (int r = 0; r < 4; ++r){
        v[r] = ((const float4*)row)[tid + 256*r];
        s += v[r].x + v[r].y + v[r].z + v[r].w;
    }
    #pragma unroll
    for (int o = 32; o > 0; o >>= 1) s += __shfl_down(s, o, 64);
    if ((tid & 63) == 0) sm[tid >> 6] = s;
    __syncthreads();
    const float mu = (sm[0] + sm[1] + sm[2] + sm[3]) * (1.f / H_DIM);
    __syncthreads();
    float sq = 0.f;
    #pragma unroll
    for (int r = 0; r < 4; ++r){
        float dx = v[r].x - mu, dy = v[r].y - mu, dz = v[r].z - mu, dw = v[r].w - mu;
        sq += dx*dx + dy*dy + dz*dz + dw*dw;
    }
    #pragma unroll
    for (int o = 32; o > 0; o >>= 1) sq += __shfl_down(sq, o, 64);
    if ((tid & 63) == 0) sm[tid >> 6] = sq;
    __syncthreads();
    const float var = (sm[0] + sm[1] + sm[2] + sm[3]) * (1.f / H_DIM);
    const float inv = rsqrtf(var + 1e-5f);
    #pragma unroll
    for (int r = 0; r < 4; ++r){
        const int i4 = tid + 256*r;
        const float4 gg = ((const float4*)g)[i4];
        const float4 bb = ((const float4*)b)[i4];
        float4 o;
        o.x = (v[r].x - mu) * inv * gg.x + bb.x;
        o.y = (v[r].y - mu) * inv * gg.y + bb.y;
        o.z = (v[r].z - mu) * inv * gg.z + bb.z;
        o.w = (v[r].w - mu) * inv * gg.w + bb.w;
        ((float4*)row)[i4] = o;
    }
}

extern "C" void kernel_launch(void* const* d_in, const int* in_sizes, int n_in,
                              void* d_out, int out_size, void* d_ws, size_t ws_size,
                              hipStream_t stream)
{
    (void)in_sizes; (void)n_in; (void)out_size; (void)ws_size;
    const float* x     = (const float*)d_in[0];
    const float* s0    = (const float*)d_in[1];
    const float* z0    = (const float*)d_in[2];
    const int*   start = (const int*)d_in[3];
    const float* Wk    = (const float*)d_in[5];
    const float* Wq    = (const float*)d_in[6];
    const float* Wv    = (const float*)d_in[7];
    const float* bv    = (const float*)d_in[8];
    const float* Wskip = (const float*)d_in[9];
    const float* bskip = (const float*)d_in[10];
    const float* W1    = (const float*)d_in[11];
    const float* b1    = (const float*)d_in[12];
    const float* W2    = (const float*)d_in[13];
    const float* b2    = (const float*)d_in[14];
    const float* W3    = (const float*)d_in[15];
    const float* b3    = (const float*)d_in[16];
    const float* ln_g  = (const float*)d_in[17];
    const float* ln_b  = (const float*)d_in[18];

    // ---- workspace carve (256B-aligned), total ~148 MB ----
    char* p = (char*)d_ws;
    auto alloc = [&](size_t bytes) -> void* {
        void* r = (void*)p; p += (bytes + 255) & ~(size_t)255; return r;
    };
    float* kbuf  = (float*)alloc((size_t)T_DIM * K_DIM * 4);
    float* qbuf  = (float*)alloc((size_t)T_DIM * K_DIM * 4);
    float* vbuf  = (float*)alloc((size_t)T_DIM * V_DIM * 4);
    float* chS   = (float*)alloc((size_t)CHUNKS * 4096 * 4);
    float* chZ   = (float*)alloc((size_t)CHUNKS * 64 * 4);
    float* caS   = (float*)alloc((size_t)CHUNKS * 4096 * 4);
    float* caZ   = (float*)alloc((size_t)CHUNKS * 64 * 4);
    int*   flags = (int*)  alloc((size_t)CHUNKS * 4);
    unsigned short* xb     = (unsigned short*)alloc((size_t)T_DIM * IN_DIM * 2);
    unsigned short* Wskipb = (unsigned short*)alloc((size_t)H_DIM * IN_DIM * 2);
    unsigned short* W1b    = (unsigned short*)alloc((size_t)H_DIM * V_DIM * 2);
    unsigned short* W2b    = (unsigned short*)alloc((size_t)H_DIM * H_DIM * 2);
    unsigned short* W3b    = (unsigned short*)alloc((size_t)H_DIM * H_DIM * 2);
    unsigned short* attb   = (unsigned short*)alloc((size_t)T_DIM * V_DIM * 2);
    unsigned short* h1b    = (unsigned short*)alloc((size_t)T_DIM * H_DIM * 2);
    unsigned short* h2b    = (unsigned short*)alloc((size_t)T_DIM * H_DIM * 2);

    float* hn  = (float*)d_out;                          // (T,H)
    float* s_o = hn  + (size_t)T_DIM * H_DIM;            // (T,K,V)
    float* z_o = s_o + (size_t)T_DIM * K_DIM * V_DIM;    // (T,1,K)

    // 0) bf16 conversions of GEMM inputs (independent; launch up front)
    cvt_bf16<<<(T_DIM*IN_DIM/4 + 255)/256, 256, 0, stream>>>(x, xb, T_DIM*IN_DIM/4);
    cvt_bf16<<<(H_DIM*IN_DIM/4 + 255)/256, 256, 0, stream>>>(Wskip, Wskipb, H_DIM*IN_DIM/4);
    cvt_bf16<<<(H_DIM*V_DIM/4 + 255)/256, 256, 0, stream>>>(W1, W1b, H_DIM*V_DIM/4);
    cvt_bf16<<<(H_DIM*H_DIM/4 + 255)/256, 256, 0, stream>>>(W2, W2b, H_DIM*H_DIM/4);
    cvt_bf16<<<(H_DIM*H_DIM/4 + 255)/256, 256, 0, stream>>>(W3, W3b, H_DIM*H_DIM/4);

    // 1) projections (fp32): k = phi(x@Wk^T), q = phi(x@Wq^T), v = x@Wv^T + bv
    gemm_xwt<<<dim3(T_DIM/64, K_DIM/64), 256, 0, stream>>>(x, Wk, IN_DIM, nullptr, kbuf, K_DIM, 1);
    gemm_xwt<<<dim3(T_DIM/64, K_DIM/64), 256, 0, stream>>>(x, Wq, IN_DIM, nullptr, qbuf, K_DIM, 1);
    gemm_xwt<<<dim3(T_DIM/64, V_DIM/64), 256, 0, stream>>>(x, Wv, IN_DIM, bv, vbuf, V_DIM, 0);

    // 2) segmented scan (3 passes); pass C emits att in bf16
    scan_passA<<<CHUNKS, 256, 0, stream>>>(kbuf, vbuf, start, chS, chZ, flags);
    scan_passB<<<4096/256, 256, 0, stream>>>(chS, chZ, flags, s0, z0, caS, caZ);
    scan_passC<<<CHUNKS, 256, 0, stream>>>(kbuf, vbuf, qbuf, start, caS, caZ, s_o, z_o, attb);

    // 3) MLP: GEMM1 (K=64) on the 128^2 kernel; big GEMMs on the wave-pipelined 256^2.
    gemm_mfma_bt<<<dim3(T_DIM/128, H_DIM/128), 256, 0, stream>>>(
        attb, W1b, V_DIM, nullptr, nullptr, 0, b1, nullptr, h1b, H_DIM, 2, 1);
    gemm256p<<<dim3(T_DIM/256, H_DIM/256), 512, 0, stream>>>(
        h1b, W2b, H_DIM, nullptr, nullptr, 0, b2, nullptr, h2b, H_DIM, 2, 1);
    // GEMM3 fused with skip: hn = h2@W3^T + x@Wskip^T + b3 + bskip (fp32 out)
    gemm256p<<<dim3(T_DIM/256, H_DIM/256), 512, 0, stream>>>(
        h2b, W3b, H_DIM, xb, Wskipb, IN_DIM, b3, bskip, hn, H_DIM, 0, 0);

    // 4) LayerNorm in place on d_out
    ln_kernel<<<T_DIM, 256, 0, stream>>>(hn, ln_g, ln_b);
}

// Round 5
// 807.990 us; speedup vs baseline: 1.2839x; 1.0566x over previous
//
#include <hip/hip_runtime.h>
#include <math.h>

// Problem constants (from reference): T=4096, IN=512, K=64, V=64, H=4096
#define T_DIM 4096
#define IN_DIM 512
#define K_DIM 64
#define V_DIM 64
#define H_DIM 4096
#define CHUNKS 256
#define CLEN 16   // T_DIM / CHUNKS

typedef __attribute__((ext_vector_type(8))) short short8;  // 8 bf16 = 4 VGPRs
typedef __attribute__((ext_vector_type(4))) float f32x4;

// ---------------- activations ----------------
__device__ __forceinline__ float phi_act(float v){
    return v > 0.f ? (v + 1.f) : (expm1f(v) + 1.f);
}
__device__ __forceinline__ float mish_act(float v){
    float sp = fmaxf(v, 0.f) + log1pf(expf(-fabsf(v)));
    return v * tanhf(sp);
}
// fp32 -> bf16 round-to-nearest-even (bit trick)
__device__ __forceinline__ unsigned short f2bf(float f){
    union { float f; unsigned int u; } x; x.f = f;
    unsigned int u = x.u + 0x7fffu + ((x.u >> 16) & 1u);
    return (unsigned short)(u >> 16);
}

// async 16B global->LDS (dest = wave-uniform base + lane*16; layout must be contiguous per lane)
__device__ __forceinline__ void async16(const unsigned short* g, unsigned short* l){
    __builtin_amdgcn_global_load_lds(
        (const __attribute__((address_space(1))) unsigned int*)g,
        (__attribute__((address_space(3))) unsigned int*)l,
        16, 0, 0);
}

// inline-asm ds_read_b128 with compile-time immediate offset. Opaque to the
// compiler's waitcnt insertion -> we control lgkmcnt/vmcnt entirely; offset:imm
// keeps address VALU at zero inside the K-loop.
__device__ __forceinline__ short8 dsr128o(unsigned addr, int off){
    short8 d;
    asm volatile("ds_read_b128 %0, %1 offset:%2" : "=v"(d) : "v"(addr), "i"(off));
    return d;
}

#define LGKM(n)  asm volatile("s_waitcnt lgkmcnt(" #n ")" ::: "memory")
#define VMCNT(n) asm volatile("s_waitcnt vmcnt(" #n ")" ::: "memory")

// ---------------- fp32 -> bf16 conversion, 4 elems/thread ----------------
__global__ __launch_bounds__(256) void cvt_bf16(const float* __restrict__ in,
                                                unsigned short* __restrict__ out, int n4){
    int i = blockIdx.x * 256 + threadIdx.x;
    if (i >= n4) return;
    float4 v = ((const float4*)in)[i];
    ushort4 o;
    o.x = f2bf(v.x); o.y = f2bf(v.y); o.z = f2bf(v.z); o.w = f2bf(v.w);
    ((ushort4*)out)[i] = o;
}

// ---------------- bf16 MFMA GEMM (128x128 tile, m97 structure) ----------------
// Kept for the small-K GEMM1 (K=64): 2 blocks/CU co-residency hides its staging drains.
__global__ __launch_bounds__(256) void gemm_mfma_bt(
    const unsigned short* __restrict__ A0, const unsigned short* __restrict__ B0, int K0,
    const unsigned short* __restrict__ A1, const unsigned short* __restrict__ B1, int K1,
    const float* __restrict__ bias0, const float* __restrict__ bias1,
    void* __restrict__ Y, int N, int act, int out_bf16)
{
    constexpr int BK = 64;
    __shared__ unsigned short As[128 * BK];
    __shared__ unsigned short Bs[128 * BK];
    const int tid  = threadIdx.x;
    const int lane = tid & 63;
    const int wm   = (tid >> 6 & 1) * 64;     // wave m-offset in tile
    const int wn   = (tid >> 7) * 64;         // wave n-offset in tile
    const int bm   = blockIdx.x * 128;
    const int bn   = blockIdx.y * 128;
    const int l15  = lane & 15;
    const int quad = lane >> 4;

    f32x4 acc[4][4] = {};

    for (int seg = 0; seg < 2; ++seg){
        const unsigned short* A = seg ? A1 : A0;
        const unsigned short* B = seg ? B1 : B0;
        const int Kd = seg ? K1 : K0;
        if (Kd <= 0 || A == nullptr) continue;
        for (int k0 = 0; k0 < Kd; k0 += BK){
            __syncthreads();  // previous tile's ds_reads must drain before restage
            #pragma unroll
            for (int it = 0; it < 4; ++it){   // 1024 chunks of 16B per matrix, 4 per thread
                const int c  = it * 256 + tid;        // LDS chunk index (byte off = c*16)
                const int r  = c >> 3;                // row 0..127
                const int kc = (c & 7) ^ (r & 7);     // swizzled global k-chunk
                async16(A + (size_t)(bm + r) * Kd + k0 + kc * 8, &As[c * 8]);
            }
            #pragma unroll
            for (int it = 0; it < 4; ++it){
                const int c  = it * 256 + tid;
                const int r  = c >> 3;
                const int kc = (c & 7) ^ (r & 7);
                async16(B + (size_t)(bn + r) * Kd + k0 + kc * 8, &Bs[c * 8]);
            }
            __syncthreads();  // s_waitcnt vmcnt(0) before s_barrier -> staging complete
            #pragma unroll
            for (int ks = 0; ks < 2; ++ks){
                short8 af[4], bf[4];
                #pragma unroll
                for (int mi = 0; mi < 4; ++mi){
                    const int row = wm + mi * 16 + l15;
                    const int kq  = ks * 4 + quad;            // k-chunk 0..7
                    af[mi] = *(const short8*)&As[(row * 8 + (kq ^ (row & 7))) * 8];
                }
                #pragma unroll
                for (int ni = 0; ni < 4; ++ni){
                    const int row = wn + ni * 16 + l15;
                    const int kq  = ks * 4 + quad;
                    bf[ni] = *(const short8*)&Bs[(row * 8 + (kq ^ (row & 7))) * 8];
                }
                #pragma unroll
                for (int mi = 0; mi < 4; ++mi)
                    #pragma unroll
                    for (int ni = 0; ni < 4; ++ni)
                        acc[mi][ni] = __builtin_amdgcn_mfma_f32_16x16x32_bf16(
                            af[mi], bf[ni], acc[mi][ni], 0, 0, 0);
            }
        }
    }

    // epilogue: C/D mapping col=lane&15, row=quad*4+reg
    #pragma unroll
    for (int ni = 0; ni < 4; ++ni){
        const int col = bn + wn + ni * 16 + l15;
        float bb = 0.f;
        if (bias0) bb += bias0[col];
        if (bias1) bb += bias1[col];
        #pragma unroll
        for (int mi = 0; mi < 4; ++mi){
            #pragma unroll
            for (int r = 0; r < 4; ++r){
                const int row = bm + wm + mi * 16 + quad * 4 + r;
                float v = acc[mi][ni][r] + bb;
                if (act == 2) v = mish_act(v);
                if (out_bf16) ((unsigned short*)Y)[(size_t)row * N + col] = f2bf(v);
                else          ((float*)Y)[(size_t)row * N + col] = v;
            }
        }
    }
}

// ---------------- 256x256 deep-pipelined bf16 MFMA GEMM (BK=32, quad-buffer) ----------------
// BM=BN=256, BK=32, NBUF=4 (LDS = 4 x (A 16K + B 16K)/2 ... = 4 x 32 KiB = 128 KiB).
// 512 threads = 8 waves (2M x 4N); per-wave output 128x64 = acc f32x4[8][4].
//
// THE fix vs the previous round: never drain vmcnt to 0 in the main loop. Tile t+3 is
// staged while computing tile t (prefetch depth 3); the tile boundary waits vmcnt(8) --
// tile t+1 complete, tiles t+2/t+3 (8 loads) STAY IN FLIGHT, so the L2/L3/HBM pipe never
// restarts. Per-wave counted lgkmcnt clusters (DS completes in order per wave):
//   issue 4 fb + 4 fa reads; stage tile t+3 (4 async16); issue 4 fa2 reads
//   LGKM(4) -> 16 MFMA (acc[0:4])   ;  LGKM(0) -> 16 MFMA (acc[4:8])
//   boundary: VMCNT(8) ; s_barrier  (one barrier per tile)
// Race-safety: stage target buf (t+3)&3 = buf (t-1)&3; all waves' reads of tile t-1
// completed before t-1's boundary barrier (own LGKM(0) precedes it).
// Swizzle (BK=32): LDS slot s of row r holds global k-chunk s ^ ((r>>1)&3); read slot =
// quad ^ ((row>>1)&3). Within each 16-lane quad this gives 2 lanes per 4-bank group --
// identical structure to the measured-0-conflict BK=64 layout. Linear LDS dest
// (global_load_lds requirement), pre-swizzled global source, reads XOR the same pattern.
// Two K-segments (A0,B0,K0)+(A1,B1,K1) accumulate into the same acc (fuses skip-GEMM).
__global__ __launch_bounds__(512, 2) void gemm256p(
    const unsigned short* __restrict__ A0, const unsigned short* __restrict__ B0, int K0,
    const unsigned short* __restrict__ A1, const unsigned short* __restrict__ B1, int K1,
    const float* __restrict__ bias0, const float* __restrict__ bias1,
    void* __restrict__ Y, int N, int act, int out_bf16)
{
    __shared__ unsigned short As[4][8192];   // 4 bufs x 16 KiB (256 rows x 32 k bf16)
    __shared__ unsigned short Bs[4][8192];
    const int tid  = threadIdx.x;
    const int lane = tid & 63;
    const int w    = tid >> 6;          // wave 0..7
    const int wr   = w >> 2;            // 0..1  (M half)
    const int wc   = w & 3;             // 0..3  (N quarter)
    const int l15  = lane & 15;
    const int quad = lane >> 4;

    // Bijective XCD-aware swizzle for the 16x16 grid: XCD x owns a 4(M) x 8(N) patch.
    int bx = blockIdx.x, by = blockIdx.y;
    if (gridDim.x == 16 && gridDim.y == 16){
        const int id  = by * 16 + bx;       // dispatch-linear (blockIdx.x fastest)
        const int xcd = id & 7;             // default round-robin XCD assignment
        const int loc = id >> 3;            // 0..31 within XCD
        bx = (xcd & 3) * 4 + (loc & 3);
        by = (xcd >> 2) * 8 + (loc >> 2);
    }
    const int bm = bx * 256;
    const int bn = by * 256;

    // staging geometry: per matrix-tile 1024 chunks of 16B; thread owns chunks tid and
    // tid+512. chunk c: row r=c>>2 (0..255), slot=c&3, k-chunk = slot ^ ((r>>1)&3).
    // (tid+512: row r+128, same slot, same swizzle value -> same k-chunk offset.)
    const int rA  = tid >> 2;                       // 0..127
    const int kcs = (tid & 3) ^ ((rA >> 1) & 3);

    // loop-invariant LDS read bases (buffer 0); frag i at +i*1024, buffer stride 16384.
    // slot = quad ^ ((row>>1)&3); (row>>1)&3 == (l15>>1)&3 for every 16-aligned frag row.
    const unsigned asB  = (unsigned)(size_t)&As[0][0];
    const unsigned bsB  = (unsigned)(size_t)&Bs[0][0];
    const int      slot = quad ^ ((l15 >> 1) & 3);
    const unsigned baseA = asB + (unsigned)((((wr * 128 + l15) * 4) + slot) * 16);
    const unsigned baseB = bsB + (unsigned)((((wc * 64  + l15) * 4) + slot) * 16);

    f32x4 acc[8][4] = {};

    for (int seg = 0; seg < 2; ++seg){
        const unsigned short* A = seg ? A1 : A0;
        const unsigned short* B = seg ? B1 : B0;
        const int Kd = seg ? K1 : K0;
        if (Kd <= 0 || A == nullptr) continue;
        const int NT = Kd / 32;

        const size_t ro = (size_t)rA * Kd + (size_t)kcs * 8;
        const unsigned short* sA0 = A + (size_t)bm * Kd + ro;
        const unsigned short* sA1 = sA0 + (size_t)128 * Kd;
        const unsigned short* sB0 = B + (size_t)bn * Kd + ro;
        const unsigned short* sB1 = sB0 + (size_t)128 * Kd;

        // ---- prologue: stage tiles 0..2 into bufs 0..2; wait tile 0 only ----
        const int nst = NT < 3 ? NT : 3;
        for (int kt = 0; kt < nst; ++kt){
            async16(sA0 + kt * 32, &As[kt][tid * 8]);
            async16(sA1 + kt * 32, &As[kt][(tid + 512) * 8]);
            async16(sB0 + kt * 32, &Bs[kt][tid * 8]);
            async16(sB1 + kt * 32, &Bs[kt][(tid + 512) * 8]);
        }
        sA0 += nst * 32; sA1 += nst * 32; sB0 += nst * 32; sB1 += nst * 32;
        if (NT > 2)      VMCNT(8);
        else if (NT > 1) VMCNT(4);
        else             VMCNT(0);
        __builtin_amdgcn_s_barrier();

        for (int t = 0; t < NT; ++t){
            const unsigned bo = (unsigned)(t & 3) * 16384u;
            const unsigned aA = baseA + bo, aB = baseB + bo;
            short8 fb[4], fa[4], fa2[4];

            // reads for cluster 0 (8 DS) ...
            #pragma unroll
            for (int ni = 0; ni < 4; ++ni) fb[ni] = dsr128o(aB, ni * 1024);
            #pragma unroll
            for (int mi = 0; mi < 4; ++mi) fa[mi] = dsr128o(aA, mi * 1024);
            // ... stage tile t+3 into buf (t-1)&3 (dead since tile t-1's boundary) ...
            if (t + 3 < NT){
                unsigned short* dA = &As[(t + 3) & 3][0];
                unsigned short* dB = &Bs[(t + 3) & 3][0];
                async16(sA0, dA + tid * 8);
                async16(sA1, dA + (tid + 512) * 8);
                async16(sB0, dB + tid * 8);
                async16(sB1, dB + (tid + 512) * 8);
                sA0 += 32; sA1 += 32; sB0 += 32; sB1 += 32;
            }
            // ... reads for cluster 1 (4 DS; execute under cluster-0 MFMA)
            #pragma unroll
            for (int mi = 0; mi < 4; ++mi) fa2[mi] = dsr128o(aA, (4 + mi) * 1024);

            LGKM(4);                                   // fb + fa landed
            __builtin_amdgcn_sched_barrier(0);
            __builtin_amdgcn_s_setprio(1);
            #pragma unroll
            for (int mi = 0; mi < 4; ++mi)
                #pragma unroll
                for (int ni = 0; ni < 4; ++ni)
                    acc[mi][ni] = __builtin_amdgcn_mfma_f32_16x16x32_bf16(
                        fa[mi], fb[ni], acc[mi][ni], 0, 0, 0);
            __builtin_amdgcn_s_setprio(0);

            LGKM(0);                                   // fa2 landed
            __builtin_amdgcn_sched_barrier(0);
            __builtin_amdgcn_s_setprio(1);
            #pragma unroll
            for (int mi = 0; mi < 4; ++mi)
                #pragma unroll
                for (int ni = 0; ni < 4; ++ni)
                    acc[4 + mi][ni] = __builtin_amdgcn_mfma_f32_16x16x32_bf16(
                        fa2[mi], fb[ni], acc[4 + mi][ni], 0, 0, 0);
            __builtin_amdgcn_s_setprio(0);

            // tile boundary: tile t+1 complete, tiles t+2/t+3 stay in flight.
            if (t + 1 < NT){
                if (t + 3 < NT)      VMCNT(8);
                else if (t + 2 < NT) VMCNT(4);
                else                 VMCNT(0);
                __builtin_amdgcn_s_barrier();
            }
        }
        // segment end: per-wave reads done (LGKM(0)); vmcnt drained by the tail boundary
        // waits. The next segment's prologue barrier is the cross-wave rendezvous.
    }

    // epilogue: C/D mapping col=lane&15, row=quad*4+reg
    #pragma unroll
    for (int ni = 0; ni < 4; ++ni){
        const int col = bn + wc * 64 + ni * 16 + l15;
        float bb = 0.f;
        if (bias0) bb += bias0[col];
        if (bias1) bb += bias1[col];
        #pragma unroll
        for (int mi = 0; mi < 8; ++mi){
            #pragma unroll
            for (int r = 0; r < 4; ++r){
                const int row = bm + wr * 128 + mi * 16 + quad * 4 + r;
                float v = acc[mi][ni][r] + bb;
                if (act == 2) v = mish_act(v);
                if (out_bf16) ((unsigned short*)Y)[(size_t)row * N + col] = f2bf(v);
                else          ((float*)Y)[(size_t)row * N + col] = v;
            }
        }
    }
}

// ---------------- fused k/q/v projections (fp32): one dispatch, grid (T/64, 3) ----------------
// blockIdx.y selects {k: phi(x@Wk^T), q: phi(x@Wq^T), v: x@Wv^T + bv}. N=64, K=512.
__global__ __launch_bounds__(256) void gemm_xwt3(
    const float* __restrict__ x,
    const float* __restrict__ Wk, const float* __restrict__ Wq, const float* __restrict__ Wv,
    const float* __restrict__ bv,
    float* __restrict__ kbuf, float* __restrict__ qbuf, float* __restrict__ vbuf)
{
    const int which = blockIdx.y;
    const float* B0 = which == 0 ? Wk : which == 1 ? Wq : Wv;
    float* Y        = which == 0 ? kbuf : which == 1 ? qbuf : vbuf;
    const int act   = which < 2;

    __shared__ float As[16][68];
    __shared__ float Bs[16][68];
    const int tid  = threadIdx.x;
    const int bm   = blockIdx.x * 64;
    const int lrow = tid >> 2;
    const int lk4  = (tid & 3) * 4;
    const int tm   = (tid >> 4) * 4;
    const int tn   = (tid & 15) * 4;
    float acc[4][4] = {};

    const float* aptr = x  + (size_t)(bm + lrow) * IN_DIM + lk4;
    const float* bptr = B0 + (size_t)lrow * IN_DIM + lk4;
    for (int k0 = 0; k0 < IN_DIM; k0 += 16){
        const float4 av = *(const float4*)(aptr + k0);
        const float4 bv4 = *(const float4*)(bptr + k0);
        __syncthreads();
        As[lk4+0][lrow]=av.x;  As[lk4+1][lrow]=av.y;  As[lk4+2][lrow]=av.z;  As[lk4+3][lrow]=av.w;
        Bs[lk4+0][lrow]=bv4.x; Bs[lk4+1][lrow]=bv4.y; Bs[lk4+2][lrow]=bv4.z; Bs[lk4+3][lrow]=bv4.w;
        __syncthreads();
        #pragma unroll
        for (int kk = 0; kk < 16; ++kk){
            const float4 a = *(const float4*)&As[kk][tm];
            const float4 b = *(const float4*)&Bs[kk][tn];
            acc[0][0] += a.x*b.x; acc[0][1] += a.x*b.y; acc[0][2] += a.x*b.z; acc[0][3] += a.x*b.w;
            acc[1][0] += a.y*b.x; acc[1][1] += a.y*b.y; acc[1][2] += a.y*b.z; acc[1][3] += a.y*b.w;
            acc[2][0] += a.z*b.x; acc[2][1] += a.z*b.y; acc[2][2] += a.z*b.z; acc[2][3] += a.z*b.w;
            acc[3][0] += a.w*b.x; acc[3][1] += a.w*b.y; acc[3][2] += a.w*b.z; acc[3][3] += a.w*b.w;
        }
    }
    float badd[4] = {0.f, 0.f, 0.f, 0.f};
    if (which == 2){
        badd[0] = bv[tn+0]; badd[1] = bv[tn+1]; badd[2] = bv[tn+2]; badd[3] = bv[tn+3];
    }
    #pragma unroll
    for (int i = 0; i < 4; ++i){
        float r0 = acc[i][0] + badd[0];
        float r1 = acc[i][1] + badd[1];
        float r2 = acc[i][2] + badd[2];
        float r3 = acc[i][3] + badd[3];
        if (act){ r0 = phi_act(r0); r1 = phi_act(r1); r2 = phi_act(r2); r3 = phi_act(r3); }
        *(float4*)&Y[(size_t)(bm + tm + i) * 64 + tn] = make_float4(r0, r1, r2, r3);
    }
}

// ---------------- segmented scan, pass A ----------------
__global__ __launch_bounds__(256) void scan_passA(
    const float* __restrict__ kbuf, const float* __restrict__ vbuf,
    const int* __restrict__ start,
    float* __restrict__ chunkS, float* __restrict__ chunkZ, int* __restrict__ chunkFlag)
{
    const int c   = blockIdx.x;
    const int tid = threadIdx.x;
    const int j   = tid >> 2;
    const int i0  = (tid & 3) * 16;
    __shared__ float k_lds[64], v_lds[64];
    float s_loc[16];
    #pragma unroll
    for (int e = 0; e < 16; ++e) s_loc[e] = 0.f;
    float z_loc = 0.f;
    int flag = 0;
    const int t0 = c * CLEN;
    for (int tt = 0; tt < CLEN; ++tt){
        const int t = t0 + tt;
        if (tid < 64)       k_lds[tid]      = kbuf[(size_t)t*K_DIM + tid];
        else if (tid < 128) v_lds[tid - 64] = vbuf[(size_t)t*V_DIM + tid - 64];
        __syncthreads();
        const int st = start[t];
        if (st){
            #pragma unroll
            for (int e = 0; e < 16; ++e) s_loc[e] = 0.f;
            z_loc = 0.f;
            flag = 1;
        }
        const float vj = v_lds[j];
        #pragma unroll
        for (int e = 0; e < 16; ++e) s_loc[e] += k_lds[i0 + e] * vj;
        if (tid < 64) z_loc += k_lds[tid];
        __syncthreads();
    }
    #pragma unroll
    for (int e = 0; e < 16; ++e) chunkS[(size_t)c*4096 + (i0 + e)*64 + j] = s_loc[e];
    if (tid < 64) chunkZ[c*64 + tid] = z_loc;
    if (tid == 0) chunkFlag[c] = flag;
}

// ---------------- pass B: exclusive cross-chunk combine ----------------
__global__ __launch_bounds__(256) void scan_passB(
    const float* __restrict__ chunkS, const float* __restrict__ chunkZ, const int* __restrict__ chunkFlag,
    const float* __restrict__ s0, const float* __restrict__ z0,
    float* __restrict__ carryS, float* __restrict__ carryZ)
{
    const int ij = blockIdx.x * 256 + threadIdx.x;
    float e = s0[ij];
    for (int c = 0; c < CHUNKS; ++c){
        carryS[(size_t)c*4096 + ij] = e;
        const int f   = chunkFlag[c];
        const float s = chunkS[(size_t)c*4096 + ij];
        e = f ? s : (e + s);
    }
    if (ij < 64){
        float ez = z0[ij];
        for (int c = 0; c < CHUNKS; ++c){
            carryZ[c*64 + ij] = ez;
            const int f   = chunkFlag[c];
            const float z = chunkZ[c*64 + ij];
            ez = f ? z : (ez + z);
        }
    }
}

// ---------------- pass C: replay with carry; emit s[t], z[t], att out (bf16) ----------------
__global__ __launch_bounds__(256) void scan_passC(
    const float* __restrict__ kbuf, const float* __restrict__ vbuf, const float* __restrict__ qbuf,
    const int* __restrict__ start,
    const float* __restrict__ carryS, const float* __restrict__ carryZ,
    float* __restrict__ s_out, float* __restrict__ z_out, unsigned short* __restrict__ attout)
{
    const int c   = blockIdx.x;
    const int tid = threadIdx.x;
    const int j   = tid >> 2;
    const int g   = tid & 3;
    const int i0  = g * 16;
    __shared__ float k_lds[64], v_lds[64], q_lds[64];
    __shared__ float numer_lds[64];
    __shared__ float stage[4096];
    float s_loc[16];
    #pragma unroll
    for (int e = 0; e < 16; ++e) s_loc[e] = carryS[(size_t)c*4096 + (i0 + e)*64 + j];
    float z_loc = (tid < 64) ? carryZ[c*64 + tid] : 0.f;

    const int t0 = c * CLEN;
    for (int tt = 0; tt < CLEN; ++tt){
        const int t = t0 + tt;
        if (tid < 64)       k_lds[tid]       = kbuf[(size_t)t*K_DIM + tid];
        else if (tid < 128) v_lds[tid - 64]  = vbuf[(size_t)t*V_DIM + tid - 64];
        else if (tid < 192) q_lds[tid - 128] = qbuf[(size_t)t*K_DIM + tid - 128];
        __syncthreads();
        const int st = start[t];
        if (st){
            #pragma unroll
            for (int e = 0; e < 16; ++e) s_loc[e] = 0.f;
        }
        const float vj = v_lds[j];
        float np = 0.f;
        #pragma unroll
        for (int e = 0; e < 16; ++e){
            s_loc[e] += k_lds[i0 + e] * vj;
            np += s_loc[e] * q_lds[i0 + e];
        }
        np += __shfl_down(np, 1, 64);
        np += __shfl_down(np, 2, 64);
        if (g == 0) numer_lds[j] = np;
        float denom = 1.f;
        if (tid < 64){
            z_loc = (st ? 0.f : z_loc) + k_lds[tid];
            z_out[(size_t)t*K_DIM + tid] = z_loc;
            float zs = z_loc;
            float qs = q_lds[tid];
            #pragma unroll
            for (int o = 32; o > 0; o >>= 1){
                zs += __shfl_down(zs, o, 64);
                qs += __shfl_down(qs, o, 64);
            }
            zs = __shfl(zs, 0, 64);
            qs = __shfl(qs, 0, 64);
            denom = fmaxf(zs * qs, 1e-6f);
        }
        #pragma unroll
        for (int e = 0; e < 16; ++e) stage[(i0 + e)*64 + j] = s_loc[e];
        __syncthreads();
        float4* so = (float4*)(s_out + (size_t)t*4096);
        const float4* stv = (const float4*)stage;
        #pragma unroll
        for (int r = 0; r < 4; ++r) so[tid + 256*r] = stv[tid + 256*r];
        if (tid < 64) attout[(size_t)t*V_DIM + tid] = f2bf(numer_lds[tid] / denom);
        __syncthreads();
    }
}

// ---------------- LayerNorm over H=4096, in place ----------------
__global__ __launch_bounds__(256) void ln_kernel(
    float* __restrict__ h, const float* __restrict__ g, const float* __restrict__ b)
{
    __shared__ float sm[4];
    const int t   = blockIdx.x;
    const int tid = threadIdx.x;
    float* row = h + (size_t)t * H_DIM;
    float4 v[4];
    float s = 0.f;
    #pragma unroll
    for (int r = 0; r < 4; ++r){
        v[r] = ((const float4*)row)[tid + 256*r];
        s += v[r].x + v[r].y + v[r].z + v[r].w;
    }
    #pragma unroll
    for (int o = 32; o > 0; o >>= 1) s += __shfl_down(s, o, 64);
    if ((tid & 63) == 0) sm[tid >> 6] = s;
    __syncthreads();
    const float mu = (sm[0] + sm[1] + sm[2] + sm[3]) * (1.f / H_DIM);
    __syncthreads();
    float sq = 0.f;
    #pragma unroll
    for (int r = 0; r < 4; ++r){
        float dx = v[r].x - mu, dy = v[r].y - mu, dz = v[r].z - mu, dw = v[r].w - mu;
        sq += dx*dx + dy*dy + dz*dz + dw*dw;
    }
    #pragma unroll
    for (int o = 32; o > 0; o >>= 1) sq += __shfl_down(sq, o, 64);
    if ((tid & 63) == 0) sm[tid >> 6] = sq;
    __syncthreads();
    const float var = (sm[0] + sm[1] + sm[2] + sm[3]) * (1.f / H_DIM);
    const float inv = rsqrtf(var + 1e-5f);
    #pragma unroll
    for (int r = 0; r < 4; ++r){
        const int i4 = tid + 256*r;
        const float4 gg = ((const float4*)g)[i4];
        const float4 bb = ((const float4*)b)[i4];
        float4 o;
        o.x = (v[r].x - mu) * inv * gg.x + bb.x;
        o.y = (v[r].y - mu) * inv * gg.y + bb.y;
        o.z = (v[r].z - mu) * inv * gg.z + bb.z;
        o.w = (v[r].w - mu) * inv * gg.w + bb.w;
        ((float4*)row)[i4] = o;
    }
}

extern "C" void kernel_launch(void* const* d_in, const int* in_sizes, int n_in,
                              void* d_out, int out_size, void* d_ws, size_t ws_size,
                              hipStream_t stream)
{
    (void)in_sizes; (void)n_in; (void)out_size; (void)ws_size;
    const float* x     = (const float*)d_in[0];
    const float* s0    = (const float*)d_in[1];
    const float* z0    = (const float*)d_in[2];
    const int*   start = (const int*)d_in[3];
    const float* Wk    = (const float*)d_in[5];
    const float* Wq    = (const float*)d_in[6];
    const float* Wv    = (const float*)d_in[7];
    const float* bv    = (const float*)d_in[8];
    const float* Wskip = (const float*)d_in[9];
    const float* bskip = (const float*)d_in[10];
    const float* W1    = (const float*)d_in[11];
    const float* b1    = (const float*)d_in[12];
    const float* W2    = (const float*)d_in[13];
    const float* b2    = (const float*)d_in[14];
    const float* W3    = (const float*)d_in[15];
    const float* b3    = (const float*)d_in[16];
    const float* ln_g  = (const float*)d_in[17];
    const float* ln_b  = (const float*)d_in[18];

    // ---- workspace carve (256B-aligned), total ~148 MB ----
    char* p = (char*)d_ws;
    auto alloc = [&](size_t bytes) -> void* {
        void* r = (void*)p; p += (bytes + 255) & ~(size_t)255; return r;
    };
    float* kbuf  = (float*)alloc((size_t)T_DIM * K_DIM * 4);
    float* qbuf  = (float*)alloc((size_t)T_DIM * K_DIM * 4);
    float* vbuf  = (float*)alloc((size_t)T_DIM * V_DIM * 4);
    float* chS   = (float*)alloc((size_t)CHUNKS * 4096 * 4);
    float* chZ   = (float*)alloc((size_t)CHUNKS * 64 * 4);
    float* caS   = (float*)alloc((size_t)CHUNKS * 4096 * 4);
    float* caZ   = (float*)alloc((size_t)CHUNKS * 64 * 4);
    int*   flags = (int*)  alloc((size_t)CHUNKS * 4);
    unsigned short* xb     = (unsigned short*)alloc((size_t)T_DIM * IN_DIM * 2);
    unsigned short* Wskipb = (unsigned short*)alloc((size_t)H_DIM * IN_DIM * 2);
    unsigned short* W1b    = (unsigned short*)alloc((size_t)H_DIM * V_DIM * 2);
    unsigned short* W2b    = (unsigned short*)alloc((size_t)H_DIM * H_DIM * 2);
    unsigned short* W3b    = (unsigned short*)alloc((size_t)H_DIM * H_DIM * 2);
    unsigned short* attb   = (unsigned short*)alloc((size_t)T_DIM * V_DIM * 2);
    unsigned short* h1b    = (unsigned short*)alloc((size_t)T_DIM * H_DIM * 2);
    unsigned short* h2b    = (unsigned short*)alloc((size_t)T_DIM * H_DIM * 2);

    float* hn  = (float*)d_out;                          // (T,H)
    float* s_o = hn  + (size_t)T_DIM * H_DIM;            // (T,K,V)
    float* z_o = s_o + (size_t)T_DIM * K_DIM * V_DIM;    // (T,1,K)

    // 0) bf16 conversions of GEMM inputs (independent; launch up front)
    cvt_bf16<<<(T_DIM*IN_DIM/4 + 255)/256, 256, 0, stream>>>(x, xb, T_DIM*IN_DIM/4);
    cvt_bf16<<<(H_DIM*IN_DIM/4 + 255)/256, 256, 0, stream>>>(Wskip, Wskipb, H_DIM*IN_DIM/4);
    cvt_bf16<<<(H_DIM*V_DIM/4 + 255)/256, 256, 0, stream>>>(W1, W1b, H_DIM*V_DIM/4);
    cvt_bf16<<<(H_DIM*H_DIM/4 + 255)/256, 256, 0, stream>>>(W2, W2b, H_DIM*H_DIM/4);
    cvt_bf16<<<(H_DIM*H_DIM/4 + 255)/256, 256, 0, stream>>>(W3, W3b, H_DIM*H_DIM/4);

    // 1) fused projections (fp32): k = phi(x@Wk^T), q = phi(x@Wq^T), v = x@Wv^T + bv
    gemm_xwt3<<<dim3(T_DIM/64, 3), 256, 0, stream>>>(x, Wk, Wq, Wv, bv, kbuf, qbuf, vbuf);

    // 2) segmented scan (3 passes); pass C emits att in bf16
    scan_passA<<<CHUNKS, 256, 0, stream>>>(kbuf, vbuf, start, chS, chZ, flags);
    scan_passB<<<4096/256, 256, 0, stream>>>(chS, chZ, flags, s0, z0, caS, caZ);
    scan_passC<<<CHUNKS, 256, 0, stream>>>(kbuf, vbuf, qbuf, start, caS, caZ, s_o, z_o, attb);

    // 3) MLP: GEMM1 (K=64) on the 128^2 kernel; big GEMMs on the deep-pipelined 256^2.
    gemm_mfma_bt<<<dim3(T_DIM/128, H_DIM/128), 256, 0, stream>>>(
        attb, W1b, V_DIM, nullptr, nullptr, 0, b1, nullptr, h1b, H_DIM, 2, 1);
    gemm256p<<<dim3(T_DIM/256, H_DIM/256), 512, 0, stream>>>(
        h1b, W2b, H_DIM, nullptr, nullptr, 0, b2, nullptr, h2b, H_DIM, 2, 1);
    // GEMM3 fused with skip: hn = h2@W3^T + x@Wskip^T + b3 + bskip (fp32 out)
    gemm256p<<<dim3(T_DIM/256, H_DIM/256), 512, 0, stream>>>(
        h2b, W3b, H_DIM, xb, Wskipb, IN_DIM, b3, bskip, hn, H_DIM, 0, 0);

    // 4) LayerNorm in place on d_out
    ln_kernel<<<T_DIM, 256, 0, stream>>>(hn, ln_g, ln_b);
}

// Round 6
// 806.827 us; speedup vs baseline: 1.2857x; 1.0014x over previous
//
#include <hip/hip_runtime.h>
#include <math.h>

// Problem constants (from reference): T=4096, IN=512, K=64, V=64, H=4096
#define T_DIM 4096
#define IN_DIM 512
#define K_DIM 64
#define V_DIM 64
#define H_DIM 4096
#define CHUNKS 256
#define CLEN 16   // T_DIM / CHUNKS

typedef __attribute__((ext_vector_type(8))) short short8;  // 8 bf16 = 4 VGPRs
typedef __attribute__((ext_vector_type(4))) float f32x4;

// ---------------- activations ----------------
__device__ __forceinline__ float phi_act(float v){
    return v > 0.f ? (v + 1.f) : (expm1f(v) + 1.f);
}
__device__ __forceinline__ float mish_act(float v){
    float sp = fmaxf(v, 0.f) + log1pf(expf(-fabsf(v)));
    return v * tanhf(sp);
}
// fp32 -> bf16 round-to-nearest-even (bit trick)
__device__ __forceinline__ unsigned short f2bf(float f){
    union { float f; unsigned int u; } x; x.f = f;
    unsigned int u = x.u + 0x7fffu + ((x.u >> 16) & 1u);
    return (unsigned short)(u >> 16);
}

// async 16B global->LDS (dest = wave-uniform base + lane*16; layout must be contiguous per lane)
__device__ __forceinline__ void async16(const unsigned short* g, unsigned short* l){
    __builtin_amdgcn_global_load_lds(
        (const __attribute__((address_space(1))) unsigned int*)g,
        (__attribute__((address_space(3))) unsigned int*)l,
        16, 0, 0);
}

// inline-asm ds_read_b128 with compile-time immediate offset. Opaque to the
// compiler's waitcnt insertion -> we control lgkmcnt/vmcnt entirely; offset:imm
// keeps address VALU at zero inside the K-loop.
__device__ __forceinline__ short8 dsr128o(unsigned addr, int off){
    short8 d;
    asm volatile("ds_read_b128 %0, %1 offset:%2" : "=v"(d) : "v"(addr), "i"(off));
    return d;
}

#define LGKM(n)  asm volatile("s_waitcnt lgkmcnt(" #n ")" ::: "memory")
#define VMCNT(n) asm volatile("s_waitcnt vmcnt(" #n ")" ::: "memory")

// ---------------- fp32 -> bf16 conversion, 4 elems/thread ----------------
__global__ __launch_bounds__(256) void cvt_bf16(const float* __restrict__ in,
                                                unsigned short* __restrict__ out, int n4){
    int i = blockIdx.x * 256 + threadIdx.x;
    if (i >= n4) return;
    float4 v = ((const float4*)in)[i];
    ushort4 o;
    o.x = f2bf(v.x); o.y = f2bf(v.y); o.z = f2bf(v.z); o.w = f2bf(v.w);
    ((ushort4*)out)[i] = o;
}

// ---------------- bf16 MFMA GEMM (128x128 tile, m97 structure) ----------------
// Kept for the small-K GEMM1 (K=64): 2 blocks/CU co-residency hides its staging drains.
__global__ __launch_bounds__(256) void gemm_mfma_bt(
    const unsigned short* __restrict__ A0, const unsigned short* __restrict__ B0, int K0,
    const unsigned short* __restrict__ A1, const unsigned short* __restrict__ B1, int K1,
    const float* __restrict__ bias0, const float* __restrict__ bias1,
    void* __restrict__ Y, int N, int act, int out_bf16)
{
    constexpr int BK = 64;
    __shared__ unsigned short As[128 * BK];
    __shared__ unsigned short Bs[128 * BK];
    const int tid  = threadIdx.x;
    const int lane = tid & 63;
    const int wm   = (tid >> 6 & 1) * 64;     // wave m-offset in tile
    const int wn   = (tid >> 7) * 64;         // wave n-offset in tile
    const int bm   = blockIdx.x * 128;
    const int bn   = blockIdx.y * 128;
    const int l15  = lane & 15;
    const int quad = lane >> 4;

    f32x4 acc[4][4] = {};

    for (int seg = 0; seg < 2; ++seg){
        const unsigned short* A = seg ? A1 : A0;
        const unsigned short* B = seg ? B1 : B0;
        const int Kd = seg ? K1 : K0;
        if (Kd <= 0 || A == nullptr) continue;
        for (int k0 = 0; k0 < Kd; k0 += BK){
            __syncthreads();  // previous tile's ds_reads must drain before restage
            #pragma unroll
            for (int it = 0; it < 4; ++it){   // 1024 chunks of 16B per matrix, 4 per thread
                const int c  = it * 256 + tid;        // LDS chunk index (byte off = c*16)
                const int r  = c >> 3;                // row 0..127
                const int kc = (c & 7) ^ (r & 7);     // swizzled global k-chunk
                async16(A + (size_t)(bm + r) * Kd + k0 + kc * 8, &As[c * 8]);
            }
            #pragma unroll
            for (int it = 0; it < 4; ++it){
                const int c  = it * 256 + tid;
                const int r  = c >> 3;
                const int kc = (c & 7) ^ (r & 7);
                async16(B + (size_t)(bn + r) * Kd + k0 + kc * 8, &Bs[c * 8]);
            }
            __syncthreads();  // s_waitcnt vmcnt(0) before s_barrier -> staging complete
            #pragma unroll
            for (int ks = 0; ks < 2; ++ks){
                short8 af[4], bf[4];
                #pragma unroll
                for (int mi = 0; mi < 4; ++mi){
                    const int row = wm + mi * 16 + l15;
                    const int kq  = ks * 4 + quad;            // k-chunk 0..7
                    af[mi] = *(const short8*)&As[(row * 8 + (kq ^ (row & 7))) * 8];
                }
                #pragma unroll
                for (int ni = 0; ni < 4; ++ni){
                    const int row = wn + ni * 16 + l15;
                    const int kq  = ks * 4 + quad;
                    bf[ni] = *(const short8*)&Bs[(row * 8 + (kq ^ (row & 7))) * 8];
                }
                #pragma unroll
                for (int mi = 0; mi < 4; ++mi)
                    #pragma unroll
                    for (int ni = 0; ni < 4; ++ni)
                        acc[mi][ni] = __builtin_amdgcn_mfma_f32_16x16x32_bf16(
                            af[mi], bf[ni], acc[mi][ni], 0, 0, 0);
            }
        }
    }

    // epilogue: C/D mapping col=lane&15, row=quad*4+reg
    #pragma unroll
    for (int ni = 0; ni < 4; ++ni){
        const int col = bn + wn + ni * 16 + l15;
        float bb = 0.f;
        if (bias0) bb += bias0[col];
        if (bias1) bb += bias1[col];
        #pragma unroll
        for (int mi = 0; mi < 4; ++mi){
            #pragma unroll
            for (int r = 0; r < 4; ++r){
                const int row = bm + wm + mi * 16 + quad * 4 + r;
                float v = acc[mi][ni][r] + bb;
                if (act == 2) v = mish_act(v);
                if (out_bf16) ((unsigned short*)Y)[(size_t)row * N + col] = f2bf(v);
                else          ((float*)Y)[(size_t)row * N + col] = v;
            }
        }
    }
}

// ---------------- 256x256 8-phase bf16 MFMA GEMM (faithful m201-template port) ----------------
// BM=BN=256, BK=64. 512 threads = 8 waves (2M x 4N); per-wave output 128x64 = f32x4[8][4].
// LDS = 2 dbuf x {Aks0, Aks1, Bks0, Bks1} regions of 16 KiB (256 rows x 32 k) = 128 KiB.
//
// Per K-tile: 4 phases, each
//   { 4-or-8 ds_read_b128 ; stage EXACTLY ONE half-tile (2 async16/thread) ;
//     s_barrier ; lgkmcnt(0) ; sched_barrier(0) ; setprio(1) ; 16 MFMA ; setprio(0) ; s_barrier }
// Phase p reads:  p0: A m0-3 ks0 + B ks0 (8) | p1: A m4-7 ks0 (4)
//                 p2: A m0-3 ks1 + B ks1 (8) | p3: A m4-7 ks1 (4)
// Phase p stages: p0: (t+1, Aks1)  p1: (t+1, Bks1)   -> other buffer, regions dead since t-1
//                 p2: (t+2, Aks0)  p3: (t+2, Bks0)   -> CURRENT buffer's ks0 regions, which are
//                     provably dead after p1's trailing barrier (ks0 only read in p0/p1).
// Tile boundary (once per K-tile, after p3's MFMA): s_waitcnt vmcnt(4) -> tile t+1 fully
// landed, tile t+2's 2 half-tiles (4 loads) STAY IN FLIGHT. Never drains to 0 in steady
// state (the m218 invariant: counted-vs-drain0 = +38..73%). Prologue stages 6 half-tiles
// then vmcnt(4). DS ops complete in order per wave -> lgkmcnt counts exact; vmcnt waits
// the (outstanding-N) oldest loads, so vmcnt(4) completes everything but the newest 4.
// Swizzle: per 16KB region, slot s of row r holds k-chunk s ^ ((r>>1)&3); read slot =
// quad ^ ((l15>>1)&3). Measured 0 bank conflicts (round-5 PMC). Linear LDS dest
// (global_load_lds requirement), pre-swizzled global source, reads XOR the same pattern.
// Two K-segments (A0,B0,K0)+(A1,B1,K1) accumulate into the same acc (fuses skip-GEMM).
__global__ __launch_bounds__(512, 2) void gemm256p(
    const unsigned short* __restrict__ A0, const unsigned short* __restrict__ B0, int K0,
    const unsigned short* __restrict__ A1, const unsigned short* __restrict__ B1, int K1,
    const float* __restrict__ bias0, const float* __restrict__ bias1,
    void* __restrict__ Y, int N, int act, int out_bf16)
{
    __shared__ unsigned short As[4][8192];   // region (buf*2+ks): 256 rows x 32 k, 16 KiB
    __shared__ unsigned short Bs[4][8192];
    const int tid  = threadIdx.x;
    const int lane = tid & 63;
    const int w    = tid >> 6;          // wave 0..7
    const int wr   = w >> 2;            // 0..1  (M half)
    const int wc   = w & 3;             // 0..3  (N quarter)
    const int l15  = lane & 15;
    const int quad = lane >> 4;

    // Bijective XCD-aware swizzle for the 16x16 grid: XCD x owns a 4(M) x 8(N) patch.
    int bx = blockIdx.x, by = blockIdx.y;
    if (gridDim.x == 16 && gridDim.y == 16){
        const int id  = by * 16 + bx;       // dispatch-linear (blockIdx.x fastest)
        const int xcd = id & 7;             // default round-robin XCD assignment
        const int loc = id >> 3;            // 0..31 within XCD
        bx = (xcd & 3) * 4 + (loc & 3);
        by = (xcd >> 2) * 8 + (loc >> 2);
    }
    const int bm = bx * 256;
    const int bn = by * 256;

    // staging geometry: one half-tile (matrix x ks) = 1024 chunks of 16B; thread owns
    // chunks tid (row rA) and tid+512 (row rA+128). slot=c&3, k-chunk = slot^((row>>1)&3)
    // (row+128 keeps the same swizzle value).
    const int rA  = tid >> 2;                       // 0..127
    const int kcs = (tid & 3) ^ ((rA >> 1) & 3);

    // loop-invariant LDS read bases; frag i at +i*1024, region r at +r*16384.
    const unsigned asB  = (unsigned)(size_t)&As[0][0];
    const unsigned bsB  = (unsigned)(size_t)&Bs[0][0];
    const int      slot = quad ^ ((l15 >> 1) & 3);
    const unsigned baseA = asB + (unsigned)((((wr * 128 + l15) * 4) + slot) * 16);
    const unsigned baseB = bsB + (unsigned)((((wc * 64  + l15) * 4) + slot) * 16);

    f32x4 acc[8][4] = {};

    for (int seg = 0; seg < 2; ++seg){
        const unsigned short* A = seg ? A1 : A0;
        const unsigned short* B = seg ? B1 : B0;
        const int Kd = seg ? K1 : K0;
        if (Kd <= 0 || A == nullptr) continue;
        const int NT = Kd / 64;

        const size_t ro = (size_t)rA * Kd + (size_t)kcs * 8;
        const unsigned short* pA0 = A + (size_t)bm * Kd + ro;
        const unsigned short* pA1 = pA0 + (size_t)128 * Kd;
        const unsigned short* pB0 = B + (size_t)bn * Kd + ro;
        const unsigned short* pB1 = pB0 + (size_t)128 * Kd;

        // stage one half-tile: (tile kt, matrix A/B, ks half) -> region [(kt&1)*2+ks]
        auto stgA = [&](int kt, int ks){
            const int col = kt * 64 + ks * 32;
            unsigned short* d = &As[(kt & 1) * 2 + ks][0];
            async16(pA0 + col, d + tid * 8);
            async16(pA1 + col, d + (tid + 512) * 8);
        };
        auto stgB = [&](int kt, int ks){
            const int col = kt * 64 + ks * 32;
            unsigned short* d = &Bs[(kt & 1) * 2 + ks][0];
            async16(pB0 + col, d + tid * 8);
            async16(pB1 + col, d + (tid + 512) * 8);
        };

        // ---- prologue: 6 half-tiles (t0 complete + t1's ks0 pair), vmcnt(4) ----
        stgA(0, 0); stgB(0, 0); stgA(0, 1); stgB(0, 1);
        if (NT > 1){
            stgA(1, 0); stgB(1, 0);
            VMCNT(4);                      // t0's 8 loads landed; t1's 4 in flight
        } else {
            VMCNT(0);
        }
        __builtin_amdgcn_s_barrier();

        for (int t = 0; t < NT; ++t){
            const unsigned r0 = baseA + (unsigned)((t & 1) * 2 + 0) * 16384u - baseA; // 0 helper
            const unsigned offA0 = (unsigned)((t & 1) * 2 + 0) * 16384u;
            const unsigned offA1 = (unsigned)((t & 1) * 2 + 1) * 16384u;
            (void)r0;
            short8 fa[4], fb[4];

            // ---------- phase 0: ks0, m0..3 + B ks0 (8 reads) ; stage (t+1, Aks1)
            #pragma unroll
            for (int ni = 0; ni < 4; ++ni) fb[ni] = dsr128o(baseB + offA0, ni * 1024);
            #pragma unroll
            for (int mi = 0; mi < 4; ++mi) fa[mi] = dsr128o(baseA + offA0, mi * 1024);
            if (t + 1 < NT) stgA(t + 1, 1);
            __builtin_amdgcn_s_barrier();
            LGKM(0);
            __builtin_amdgcn_sched_barrier(0);
            __builtin_amdgcn_s_setprio(1);
            #pragma unroll
            for (int mi = 0; mi < 4; ++mi)
                #pragma unroll
                for (int ni = 0; ni < 4; ++ni)
                    acc[mi][ni] = __builtin_amdgcn_mfma_f32_16x16x32_bf16(
                        fa[mi], fb[ni], acc[mi][ni], 0, 0, 0);
            __builtin_amdgcn_s_setprio(0);
            __builtin_amdgcn_s_barrier();

            // ---------- phase 1: ks0, m4..7 (4 reads) ; stage (t+1, Bks1)
            #pragma unroll
            for (int mi = 0; mi < 4; ++mi) fa[mi] = dsr128o(baseA + offA0, (4 + mi) * 1024);
            if (t + 1 < NT) stgB(t + 1, 1);
            __builtin_amdgcn_s_barrier();
            LGKM(0);
            __builtin_amdgcn_sched_barrier(0);
            __builtin_amdgcn_s_setprio(1);
            #pragma unroll
            for (int mi = 0; mi < 4; ++mi)
                #pragma unroll
                for (int ni = 0; ni < 4; ++ni)
                    acc[4 + mi][ni] = __builtin_amdgcn_mfma_f32_16x16x32_bf16(
                        fa[mi], fb[ni], acc[4 + mi][ni], 0, 0, 0);
            __builtin_amdgcn_s_setprio(0);
            __builtin_amdgcn_s_barrier();

            // ---------- phase 2: ks1, m0..3 + B ks1 (8 reads) ; stage (t+2, Aks0)
            // (current buffer's ks0 regions are dead after phase 1's barrier)
            #pragma unroll
            for (int ni = 0; ni < 4; ++ni) fb[ni] = dsr128o(baseB + offA1, ni * 1024);
            #pragma unroll
            for (int mi = 0; mi < 4; ++mi) fa[mi] = dsr128o(baseA + offA1, mi * 1024);
            if (t + 2 < NT) stgA(t + 2, 0);
            __builtin_amdgcn_s_barrier();
            LGKM(0);
            __builtin_amdgcn_sched_barrier(0);
            __builtin_amdgcn_s_setprio(1);
            #pragma unroll
            for (int mi = 0; mi < 4; ++mi)
                #pragma unroll
                for (int ni = 0; ni < 4; ++ni)
                    acc[mi][ni] = __builtin_amdgcn_mfma_f32_16x16x32_bf16(
                        fa[mi], fb[ni], acc[mi][ni], 0, 0, 0);
            __builtin_amdgcn_s_setprio(0);
            __builtin_amdgcn_s_barrier();

            // ---------- phase 3: ks1, m4..7 (4 reads) ; stage (t+2, Bks0)
            #pragma unroll
            for (int mi = 0; mi < 4; ++mi) fa[mi] = dsr128o(baseA + offA1, (4 + mi) * 1024);
            if (t + 2 < NT) stgB(t + 2, 0);
            __builtin_amdgcn_s_barrier();
            LGKM(0);
            __builtin_amdgcn_sched_barrier(0);
            __builtin_amdgcn_s_setprio(1);
            #pragma unroll
            for (int mi = 0; mi < 4; ++mi)
                #pragma unroll
                for (int ni = 0; ni < 4; ++ni)
                    acc[4 + mi][ni] = __builtin_amdgcn_mfma_f32_16x16x32_bf16(
                        fa[mi], fb[ni], acc[4 + mi][ni], 0, 0, 0);
            __builtin_amdgcn_s_setprio(0);

            // ---------- tile boundary (once per K-tile): t+1 landed, t+2 in flight
            if (t + 1 < NT){
                if (t + 2 < NT) VMCNT(4);
                else            VMCNT(0);
                __builtin_amdgcn_s_barrier();
            }
        }
        // segment end: drain before the next segment's prologue restages the buffers
        VMCNT(0);
        __builtin_amdgcn_s_barrier();
    }

    // epilogue: C/D mapping col=lane&15, row=quad*4+reg
    #pragma unroll
    for (int ni = 0; ni < 4; ++ni){
        const int col = bn + wc * 64 + ni * 16 + l15;
        float bb = 0.f;
        if (bias0) bb += bias0[col];
        if (bias1) bb += bias1[col];
        #pragma unroll
        for (int mi = 0; mi < 8; ++mi){
            #pragma unroll
            for (int r = 0; r < 4; ++r){
                const int row = bm + wr * 128 + mi * 16 + quad * 4 + r;
                float v = acc[mi][ni][r] + bb;
                if (act == 2) v = mish_act(v);
                if (out_bf16) ((unsigned short*)Y)[(size_t)row * N + col] = f2bf(v);
                else          ((float*)Y)[(size_t)row * N + col] = v;
            }
        }
    }
}

// ---------------- fused k/q/v projections (fp32): one dispatch, grid (T/64, 3) ----------------
// blockIdx.y selects {k: phi(x@Wk^T), q: phi(x@Wq^T), v: x@Wv^T + bv}. N=64, K=512.
__global__ __launch_bounds__(256) void gemm_xwt3(
    const float* __restrict__ x,
    const float* __restrict__ Wk, const float* __restrict__ Wq, const float* __restrict__ Wv,
    const float* __restrict__ bv,
    float* __restrict__ kbuf, float* __restrict__ qbuf, float* __restrict__ vbuf)
{
    const int which = blockIdx.y;
    const float* B0 = which == 0 ? Wk : which == 1 ? Wq : Wv;
    float* Y        = which == 0 ? kbuf : which == 1 ? qbuf : vbuf;
    const int act   = which < 2;

    __shared__ float As[16][68];
    __shared__ float Bs[16][68];
    const int tid  = threadIdx.x;
    const int bm   = blockIdx.x * 64;
    const int lrow = tid >> 2;
    const int lk4  = (tid & 3) * 4;
    const int tm   = (tid >> 4) * 4;
    const int tn   = (tid & 15) * 4;
    float acc[4][4] = {};

    const float* aptr = x  + (size_t)(bm + lrow) * IN_DIM + lk4;
    const float* bptr = B0 + (size_t)lrow * IN_DIM + lk4;
    for (int k0 = 0; k0 < IN_DIM; k0 += 16){
        const float4 av = *(const float4*)(aptr + k0);
        const float4 bv4 = *(const float4*)(bptr + k0);
        __syncthreads();
        As[lk4+0][lrow]=av.x;  As[lk4+1][lrow]=av.y;  As[lk4+2][lrow]=av.z;  As[lk4+3][lrow]=av.w;
        Bs[lk4+0][lrow]=bv4.x; Bs[lk4+1][lrow]=bv4.y; Bs[lk4+2][lrow]=bv4.z; Bs[lk4+3][lrow]=bv4.w;
        __syncthreads();
        #pragma unroll
        for (int kk = 0; kk < 16; ++kk){
            const float4 a = *(const float4*)&As[kk][tm];
            const float4 b = *(const float4*)&Bs[kk][tn];
            acc[0][0] += a.x*b.x; acc[0][1] += a.x*b.y; acc[0][2] += a.x*b.z; acc[0][3] += a.x*b.w;
            acc[1][0] += a.y*b.x; acc[1][1] += a.y*b.y; acc[1][2] += a.y*b.z; acc[1][3] += a.y*b.w;
            acc[2][0] += a.z*b.x; acc[2][1] += a.z*b.y; acc[2][2] += a.z*b.z; acc[2][3] += a.z*b.w;
            acc[3][0] += a.w*b.x; acc[3][1] += a.w*b.y; acc[3][2] += a.w*b.z; acc[3][3] += a.w*b.w;
        }
    }
    float badd[4] = {0.f, 0.f, 0.f, 0.f};
    if (which == 2){
        badd[0] = bv[tn+0]; badd[1] = bv[tn+1]; badd[2] = bv[tn+2]; badd[3] = bv[tn+3];
    }
    #pragma unroll
    for (int i = 0; i < 4; ++i){
        float r0 = acc[i][0] + badd[0];
        float r1 = acc[i][1] + badd[1];
        float r2 = acc[i][2] + badd[2];
        float r3 = acc[i][3] + badd[3];
        if (act){ r0 = phi_act(r0); r1 = phi_act(r1); r2 = phi_act(r2); r3 = phi_act(r3); }
        *(float4*)&Y[(size_t)(bm + tm + i) * 64 + tn] = make_float4(r0, r1, r2, r3);
    }
}

// ---------------- segmented scan, pass A ----------------
__global__ __launch_bounds__(256) void scan_passA(
    const float* __restrict__ kbuf, const float* __restrict__ vbuf,
    const int* __restrict__ start,
    float* __restrict__ chunkS, float* __restrict__ chunkZ, int* __restrict__ chunkFlag)
{
    const int c   = blockIdx.x;
    const int tid = threadIdx.x;
    const int j   = tid >> 2;
    const int i0  = (tid & 3) * 16;
    __shared__ float k_lds[64], v_lds[64];
    float s_loc[16];
    #pragma unroll
    for (int e = 0; e < 16; ++e) s_loc[e] = 0.f;
    float z_loc = 0.f;
    int flag = 0;
    const int t0 = c * CLEN;
    for (int tt = 0; tt < CLEN; ++tt){
        const int t = t0 + tt;
        if (tid < 64)       k_lds[tid]      = kbuf[(size_t)t*K_DIM + tid];
        else if (tid < 128) v_lds[tid - 64] = vbuf[(size_t)t*V_DIM + tid - 64];
        __syncthreads();
        const int st = start[t];
        if (st){
            #pragma unroll
            for (int e = 0; e < 16; ++e) s_loc[e] = 0.f;
            z_loc = 0.f;
            flag = 1;
        }
        const float vj = v_lds[j];
        #pragma unroll
        for (int e = 0; e < 16; ++e) s_loc[e] += k_lds[i0 + e] * vj;
        if (tid < 64) z_loc += k_lds[tid];
        __syncthreads();
    }
    #pragma unroll
    for (int e = 0; e < 16; ++e) chunkS[(size_t)c*4096 + (i0 + e)*64 + j] = s_loc[e];
    if (tid < 64) chunkZ[c*64 + tid] = z_loc;
    if (tid == 0) chunkFlag[c] = flag;
}

// ---------------- pass B: exclusive cross-chunk combine ----------------
__global__ __launch_bounds__(256) void scan_passB(
    const float* __restrict__ chunkS, const float* __restrict__ chunkZ, const int* __restrict__ chunkFlag,
    const float* __restrict__ s0, const float* __restrict__ z0,
    float* __restrict__ carryS, float* __restrict__ carryZ)
{
    const int ij = blockIdx.x * 256 + threadIdx.x;
    float e = s0[ij];
    for (int c = 0; c < CHUNKS; ++c){
        carryS[(size_t)c*4096 + ij] = e;
        const int f   = chunkFlag[c];
        const float s = chunkS[(size_t)c*4096 + ij];
        e = f ? s : (e + s);
    }
    if (ij < 64){
        float ez = z0[ij];
        for (int c = 0; c < CHUNKS; ++c){
            carryZ[c*64 + ij] = ez;
            const int f   = chunkFlag[c];
            const float z = chunkZ[c*64 + ij];
            ez = f ? z : (ez + z);
        }
    }
}

// ---------------- pass C: replay with carry; emit s[t], z[t], att out (bf16) ----------------
__global__ __launch_bounds__(256) void scan_passC(
    const float* __restrict__ kbuf, const float* __restrict__ vbuf, const float* __restrict__ qbuf,
    const int* __restrict__ start,
    const float* __restrict__ carryS, const float* __restrict__ carryZ,
    float* __restrict__ s_out, float* __restrict__ z_out, unsigned short* __restrict__ attout)
{
    const int c   = blockIdx.x;
    const int tid = threadIdx.x;
    const int j   = tid >> 2;
    const int g   = tid & 3;
    const int i0  = g * 16;
    __shared__ float k_lds[64], v_lds[64], q_lds[64];
    __shared__ float numer_lds[64];
    __shared__ float stage[4096];
    float s_loc[16];
    #pragma unroll
    for (int e = 0; e < 16; ++e) s_loc[e] = carryS[(size_t)c*4096 + (i0 + e)*64 + j];
    float z_loc = (tid < 64) ? carryZ[c*64 + tid] : 0.f;

    const int t0 = c * CLEN;
    for (int tt = 0; tt < CLEN; ++tt){
        const int t = t0 + tt;
        if (tid < 64)       k_lds[tid]       = kbuf[(size_t)t*K_DIM + tid];
        else if (tid < 128) v_lds[tid - 64]  = vbuf[(size_t)t*V_DIM + tid - 64];
        else if (tid < 192) q_lds[tid - 128] = qbuf[(size_t)t*K_DIM + tid - 128];
        __syncthreads();
        const int st = start[t];
        if (st){
            #pragma unroll
            for (int e = 0; e < 16; ++e) s_loc[e] = 0.f;
        }
        const float vj = v_lds[j];
        float np = 0.f;
        #pragma unroll
        for (int e = 0; e < 16; ++e){
            s_loc[e] += k_lds[i0 + e] * vj;
            np += s_loc[e] * q_lds[i0 + e];
        }
        np += __shfl_down(np, 1, 64);
        np += __shfl_down(np, 2, 64);
        if (g == 0) numer_lds[j] = np;
        float denom = 1.f;
        if (tid < 64){
            z_loc = (st ? 0.f : z_loc) + k_lds[tid];
            z_out[(size_t)t*K_DIM + tid] = z_loc;
            float zs = z_loc;
            float qs = q_lds[tid];
            #pragma unroll
            for (int o = 32; o > 0; o >>= 1){
                zs += __shfl_down(zs, o, 64);
                qs += __shfl_down(qs, o, 64);
            }
            zs = __shfl(zs, 0, 64);
            qs = __shfl(qs, 0, 64);
            denom = fmaxf(zs * qs, 1e-6f);
        }
        #pragma unroll
        for (int e = 0; e < 16; ++e) stage[(i0 + e)*64 + j] = s_loc[e];
        __syncthreads();
        float4* so = (float4*)(s_out + (size_t)t*4096);
        const float4* stv = (const float4*)stage;
        #pragma unroll
        for (int r = 0; r < 4; ++r) so[tid + 256*r] = stv[tid + 256*r];
        if (tid < 64) attout[(size_t)t*V_DIM + tid] = f2bf(numer_lds[tid] / denom);
        __syncthreads();
    }
}

// ---------------- LayerNorm over H=4096, in place ----------------
__global__ __launch_bounds__(256) void ln_kernel(
    float* __restrict__ h, const float* __restrict__ g, const float* __restrict__ b)
{
    __shared__ float sm[4];
    const int t   = blockIdx.x;
    const int tid = threadIdx.x;
    float* row = h + (size_t)t * H_DIM;
    float4 v[4];
    float s = 0.f;
    #pragma unroll
    for (int r = 0; r < 4; ++r){
        v[r] = ((const float4*)row)[tid + 256*r];
        s += v[r].x + v[r].y + v[r].z + v[r].w;
    }
    #pragma unroll
    for (int o = 32; o > 0; o >>= 1) s += __shfl_down(s, o, 64);
    if ((tid & 63) == 0) sm[tid >> 6] = s;
    __syncthreads();
    const float mu = (sm[0] + sm[1] + sm[2] + sm[3]) * (1.f / H_DIM);
    __syncthreads();
    float sq = 0.f;
    #pragma unroll
    for (int r = 0; r < 4; ++r){
        float dx = v[r].x - mu, dy = v[r].y - mu, dz = v[r].z - mu, dw = v[r].w - mu;
        sq += dx*dx + dy*dy + dz*dz + dw*dw;
    }
    #pragma unroll
    for (int o = 32; o > 0; o >>= 1) sq += __shfl_down(sq, o, 64);
    if ((tid & 63) == 0) sm[tid >> 6] = sq;
    __syncthreads();
    const float var = (sm[0] + sm[1] + sm[2] + sm[3]) * (1.f / H_DIM);
    const float inv = rsqrtf(var + 1e-5f);
    #pragma unroll
    for (int r = 0; r < 4; ++r){
        const int i4 = tid + 256*r;
        const float4 gg = ((const float4*)g)[i4];
        const float4 bb = ((const float4*)b)[i4];
        float4 o;
        o.x = (v[r].x - mu) * inv * gg.x + bb.x;
        o.y = (v[r].y - mu) * inv * gg.y + bb.y;
        o.z = (v[r].z - mu) * inv * gg.z + bb.z;
        o.w = (v[r].w - mu) * inv * gg.w + bb.w;
        ((float4*)row)[i4] = o;
    }
}

extern "C" void kernel_launch(void* const* d_in, const int* in_sizes, int n_in,
                              void* d_out, int out_size, void* d_ws, size_t ws_size,
                              hipStream_t stream)
{
    (void)in_sizes; (void)n_in; (void)out_size; (void)ws_size;
    const float* x     = (const float*)d_in[0];
    const float* s0    = (const float*)d_in[1];
    const float* z0    = (const float*)d_in[2];
    const int*   start = (const int*)d_in[3];
    const float* Wk    = (const float*)d_in[5];
    const float* Wq    = (const float*)d_in[6];
    const float* Wv    = (const float*)d_in[7];
    const float* bv    = (const float*)d_in[8];
    const float* Wskip = (const float*)d_in[9];
    const float* bskip = (const float*)d_in[10];
    const float* W1    = (const float*)d_in[11];
    const float* b1    = (const float*)d_in[12];
    const float* W2    = (const float*)d_in[13];
    const float* b2    = (const float*)d_in[14];
    const float* W3    = (const float*)d_in[15];
    const float* b3    = (const float*)d_in[16];
    const float* ln_g  = (const float*)d_in[17];
    const float* ln_b  = (const float*)d_in[18];

    // ---- workspace carve (256B-aligned), total ~148 MB ----
    char* p = (char*)d_ws;
    auto alloc = [&](size_t bytes) -> void* {
        void* r = (void*)p; p += (bytes + 255) & ~(size_t)255; return r;
    };
    float* kbuf  = (float*)alloc((size_t)T_DIM * K_DIM * 4);
    float* qbuf  = (float*)alloc((size_t)T_DIM * K_DIM * 4);
    float* vbuf  = (float*)alloc((size_t)T_DIM * V_DIM * 4);
    float* chS   = (float*)alloc((size_t)CHUNKS * 4096 * 4);
    float* chZ   = (float*)alloc((size_t)CHUNKS * 64 * 4);
    float* caS   = (float*)alloc((size_t)CHUNKS * 4096 * 4);
    float* caZ   = (float*)alloc((size_t)CHUNKS * 64 * 4);
    int*   flags = (int*)  alloc((size_t)CHUNKS * 4);
    unsigned short* xb     = (unsigned short*)alloc((size_t)T_DIM * IN_DIM * 2);
    unsigned short* Wskipb = (unsigned short*)alloc((size_t)H_DIM * IN_DIM * 2);
    unsigned short* W1b    = (unsigned short*)alloc((size_t)H_DIM * V_DIM * 2);
    unsigned short* W2b    = (unsigned short*)alloc((size_t)H_DIM * H_DIM * 2);
    unsigned short* W3b    = (unsigned short*)alloc((size_t)H_DIM * H_DIM * 2);
    unsigned short* attb   = (unsigned short*)alloc((size_t)T_DIM * V_DIM * 2);
    unsigned short* h1b    = (unsigned short*)alloc((size_t)T_DIM * H_DIM * 2);
    unsigned short* h2b    = (unsigned short*)alloc((size_t)T_DIM * H_DIM * 2);

    float* hn  = (float*)d_out;                          // (T,H)
    float* s_o = hn  + (size_t)T_DIM * H_DIM;            // (T,K,V)
    float* z_o = s_o + (size_t)T_DIM * K_DIM * V_DIM;    // (T,1,K)

    // 0) bf16 conversions of GEMM inputs (independent; launch up front)
    cvt_bf16<<<(T_DIM*IN_DIM/4 + 255)/256, 256, 0, stream>>>(x, xb, T_DIM*IN_DIM/4);
    cvt_bf16<<<(H_DIM*IN_DIM/4 + 255)/256, 256, 0, stream>>>(Wskip, Wskipb, H_DIM*IN_DIM/4);
    cvt_bf16<<<(H_DIM*V_DIM/4 + 255)/256, 256, 0, stream>>>(W1, W1b, H_DIM*V_DIM/4);
    cvt_bf16<<<(H_DIM*H_DIM/4 + 255)/256, 256, 0, stream>>>(W2, W2b, H_DIM*H_DIM/4);
    cvt_bf16<<<(H_DIM*H_DIM/4 + 255)/256, 256, 0, stream>>>(W3, W3b, H_DIM*H_DIM/4);

    // 1) fused projections (fp32): k = phi(x@Wk^T), q = phi(x@Wq^T), v = x@Wv^T + bv
    gemm_xwt3<<<dim3(T_DIM/64, 3), 256, 0, stream>>>(x, Wk, Wq, Wv, bv, kbuf, qbuf, vbuf);

    // 2) segmented scan (3 passes); pass C emits att in bf16
    scan_passA<<<CHUNKS, 256, 0, stream>>>(kbuf, vbuf, start, chS, chZ, flags);
    scan_passB<<<4096/256, 256, 0, stream>>>(chS, chZ, flags, s0, z0, caS, caZ);
    scan_passC<<<CHUNKS, 256, 0, stream>>>(kbuf, vbuf, qbuf, start, caS, caZ, s_o, z_o, attb);

    // 3) MLP: GEMM1 (K=64) on the 128^2 kernel; big GEMMs on the 8-phase 256^2.
    gemm_mfma_bt<<<dim3(T_DIM/128, H_DIM/128), 256, 0, stream>>>(
        attb, W1b, V_DIM, nullptr, nullptr, 0, b1, nullptr, h1b, H_DIM, 2, 1);
    gemm256p<<<dim3(T_DIM/256, H_DIM/256), 512, 0, stream>>>(
        h1b, W2b, H_DIM, nullptr, nullptr, 0, b2, nullptr, h2b, H_DIM, 2, 1);
    // GEMM3 fused with skip: hn = h2@W3^T + x@Wskip^T + b3 + bskip (fp32 out)
    gemm256p<<<dim3(T_DIM/256, H_DIM/256), 512, 0, stream>>>(
        h2b, W3b, H_DIM, xb, Wskipb, IN_DIM, b3, bskip, hn, H_DIM, 0, 0);

    // 4) LayerNorm in place on d_out
    ln_kernel<<<T_DIM, 256, 0, stream>>>(hn, ln_g, ln_b);
}

// Round 7
// 803.682 us; speedup vs baseline: 1.2908x; 1.0039x over previous
//
#include <hip/hip_runtime.h>
#include <math.h>

// Problem constants (from reference): T=4096, IN=512, K=64, V=64, H=4096
#define T_DIM 4096
#define IN_DIM 512
#define K_DIM 64
#define V_DIM 64
#define H_DIM 4096
#define CHUNKS 256
#define CLEN 16   // T_DIM / CHUNKS

typedef __attribute__((ext_vector_type(8))) short short8;           // 8 bf16 = 4 VGPRs
typedef __attribute__((ext_vector_type(8))) unsigned short ushort8; // 16 B store unit
typedef __attribute__((ext_vector_type(4))) float f32x4;

// ---------------- activations ----------------
__device__ __forceinline__ float phi_act(float v){
    return v > 0.f ? (v + 1.f) : (expm1f(v) + 1.f);
}
__device__ __forceinline__ float mish_act(float v){
    float sp = fmaxf(v, 0.f) + log1pf(expf(-fabsf(v)));
    return v * tanhf(sp);
}
// fp32 -> bf16 round-to-nearest-even (bit trick)
__device__ __forceinline__ unsigned short f2bf(float f){
    union { float f; unsigned int u; } x; x.f = f;
    unsigned int u = x.u + 0x7fffu + ((x.u >> 16) & 1u);
    return (unsigned short)(u >> 16);
}

// async 16B global->LDS (dest = wave-uniform base + lane*16; layout must be contiguous per lane)
__device__ __forceinline__ void async16(const unsigned short* g, unsigned short* l){
    __builtin_amdgcn_global_load_lds(
        (const __attribute__((address_space(1))) unsigned int*)g,
        (__attribute__((address_space(3))) unsigned int*)l,
        16, 0, 0);
}

// inline-asm ds_read_b128 with compile-time immediate offset. Opaque to the
// compiler's waitcnt insertion -> we control lgkmcnt/vmcnt entirely; offset:imm
// keeps address VALU at zero inside the K-loop.
__device__ __forceinline__ short8 dsr128o(unsigned addr, int off){
    short8 d;
    asm volatile("ds_read_b128 %0, %1 offset:%2" : "=v"(d) : "v"(addr), "i"(off));
    return d;
}

#define LGKM(n)  asm volatile("s_waitcnt lgkmcnt(" #n ")" ::: "memory")
#define VMCNT(n) asm volatile("s_waitcnt vmcnt(" #n ")" ::: "memory")

// ---------------- prep kernel: 3 fp32 projections + 5 bf16 conversions, ONE dispatch -----
// blocks 0..191: projection (which = bid>>6): {k=phi(x@Wk^T), q=phi(x@Wq^T), v=x@Wv^T+bv}
// blocks 192.. : grid-stride bf16 conversion over {x, Wskip, W1, W2, W3} (9502720 float4s)
#define CVT_X4   524288          // T*IN/4
#define CVT_WS   524288          // H*IN/4
#define CVT_W1   65536           // H*V/4
#define CVT_W2   4194304         // H*H/4
#define CVT_TOT  9502720
__global__ __launch_bounds__(256) void prep_kernel(
    const float* __restrict__ x,
    const float* __restrict__ Wk, const float* __restrict__ Wq, const float* __restrict__ Wv,
    const float* __restrict__ bv,
    float* __restrict__ kbuf, float* __restrict__ qbuf, float* __restrict__ vbuf,
    const float* __restrict__ Wskip, const float* __restrict__ W1,
    const float* __restrict__ W2, const float* __restrict__ W3,
    unsigned short* __restrict__ xb, unsigned short* __restrict__ Wskipb,
    unsigned short* __restrict__ W1b, unsigned short* __restrict__ W2b,
    unsigned short* __restrict__ W3b)
{
    __shared__ float As[16][68];
    __shared__ float Bs[16][68];
    const int bid = blockIdx.x;
    const int tid = threadIdx.x;

    if (bid < 192){
        // ---- projection path (uniform per block; __syncthreads is block-uniform) ----
        const int which = bid >> 6;
        const float* B0 = which == 0 ? Wk : which == 1 ? Wq : Wv;
        float* Y        = which == 0 ? kbuf : which == 1 ? qbuf : vbuf;
        const int actp  = which < 2;
        const int bm    = (bid & 63) * 64;
        const int lrow  = tid >> 2;
        const int lk4   = (tid & 3) * 4;
        const int tm    = (tid >> 4) * 4;
        const int tn    = (tid & 15) * 4;
        float acc[4][4] = {};
        const float* aptr = x  + (size_t)(bm + lrow) * IN_DIM + lk4;
        const float* bptr = B0 + (size_t)lrow * IN_DIM + lk4;
        for (int k0 = 0; k0 < IN_DIM; k0 += 16){
            const float4 av  = *(const float4*)(aptr + k0);
            const float4 bv4 = *(const float4*)(bptr + k0);
            __syncthreads();
            As[lk4+0][lrow]=av.x;  As[lk4+1][lrow]=av.y;  As[lk4+2][lrow]=av.z;  As[lk4+3][lrow]=av.w;
            Bs[lk4+0][lrow]=bv4.x; Bs[lk4+1][lrow]=bv4.y; Bs[lk4+2][lrow]=bv4.z; Bs[lk4+3][lrow]=bv4.w;
            __syncthreads();
            #pragma unroll
            for (int kk = 0; kk < 16; ++kk){
                const float4 a = *(const float4*)&As[kk][tm];
                const float4 b = *(const float4*)&Bs[kk][tn];
                acc[0][0] += a.x*b.x; acc[0][1] += a.x*b.y; acc[0][2] += a.x*b.z; acc[0][3] += a.x*b.w;
                acc[1][0] += a.y*b.x; acc[1][1] += a.y*b.y; acc[1][2] += a.y*b.z; acc[1][3] += a.y*b.w;
                acc[2][0] += a.z*b.x; acc[2][1] += a.z*b.y; acc[2][2] += a.z*b.z; acc[2][3] += a.z*b.w;
                acc[3][0] += a.w*b.x; acc[3][1] += a.w*b.y; acc[3][2] += a.w*b.z; acc[3][3] += a.w*b.w;
            }
        }
        float badd[4] = {0.f, 0.f, 0.f, 0.f};
        if (which == 2){
            badd[0] = bv[tn+0]; badd[1] = bv[tn+1]; badd[2] = bv[tn+2]; badd[3] = bv[tn+3];
        }
        #pragma unroll
        for (int i = 0; i < 4; ++i){
            float r0 = acc[i][0] + badd[0];
            float r1 = acc[i][1] + badd[1];
            float r2 = acc[i][2] + badd[2];
            float r3 = acc[i][3] + badd[3];
            if (actp){ r0 = phi_act(r0); r1 = phi_act(r1); r2 = phi_act(r2); r3 = phi_act(r3); }
            *(float4*)&Y[(size_t)(bm + tm + i) * 64 + tn] = make_float4(r0, r1, r2, r3);
        }
        return;
    }

    // ---- conversion path: grid-stride over 5 segments ----
    const int nb = gridDim.x - 192;
    for (int i = (bid - 192) * 256 + tid; i < CVT_TOT; i += nb * 256){
        const float* src; unsigned short* dst; int off;
        if      (i < CVT_X4)                          { src = x;     dst = xb;     off = i; }
        else if (i < CVT_X4 + CVT_WS)                 { src = Wskip; dst = Wskipb; off = i - CVT_X4; }
        else if (i < CVT_X4 + CVT_WS + CVT_W1)        { src = W1;    dst = W1b;    off = i - CVT_X4 - CVT_WS; }
        else if (i < CVT_X4 + CVT_WS + CVT_W1 + CVT_W2){ src = W2;   dst = W2b;    off = i - CVT_X4 - CVT_WS - CVT_W1; }
        else                                          { src = W3;    dst = W3b;    off = i - CVT_X4 - CVT_WS - CVT_W1 - CVT_W2; }
        float4 v = ((const float4*)src)[off];
        ushort4 o;
        o.x = f2bf(v.x); o.y = f2bf(v.y); o.z = f2bf(v.z); o.w = f2bf(v.w);
        ((ushort4*)dst)[off] = o;
    }
}

// ---------------- 256x256 wave-pipelined bf16 MFMA GEMM (round-4 structure, best measured) ----
// BM=BN=256, BK=64, double-buffered LDS (128 KiB, 1 block/CU). 512 threads = 8 waves
// (2M x 4N); per-wave output 128x64 = acc f32x4[8][4] (AGPR).
// ONE barrier per K-tile; per-wave counted lgkmcnt clusters (DS completes in-order/wave):
//   issue 8 reads (B-ks0, A-ks0 m0-3); stage all 8 loads of tile t+1; issue 4 reads (A-ks0 m4-7)
//   LGKM(4)  -> 16 MFMA  | issue 8 reads (B-ks1, A-ks1 m0-3)
//   LGKM(8)  -> 16 MFMA  | issue 4 reads (A-ks1 m4-7)
//   LGKM(4)  -> 16 MFMA  |  LGKM(0) -> 16 MFMA
//   VMCNT(0) ; s_barrier   (boundary: own tile-t+1 loads aged a full tile)
// Swizzle (measured 0-conflict): slot s of row r holds k-chunk s^(r&7); linear LDS dest,
// pre-swizzled global source, reads XOR the same pattern.
// Two K-segments (A0,B0,K0)+(A1,B1,K1) accumulate into the same acc (fuses skip-GEMM).
// Epilogue: stage C through LDS (per-wave padded 16x68-float region, reusing As) and emit
// coalesced 16-B stores -- kills the measured 2.2x write amplification of scattered stores.
__global__ __launch_bounds__(512, 2) void gemm256p(
    const unsigned short* __restrict__ A0, const unsigned short* __restrict__ B0, int K0,
    const unsigned short* __restrict__ A1, const unsigned short* __restrict__ B1, int K1,
    const float* __restrict__ bias0, const float* __restrict__ bias1,
    void* __restrict__ Y, int N, int act, int out_bf16)
{
    __shared__ unsigned short As[2][16384];   // 2 x 32 KiB
    __shared__ unsigned short Bs[2][16384];   // 2 x 32 KiB
    const int tid  = threadIdx.x;
    const int lane = tid & 63;
    const int w    = tid >> 6;          // wave 0..7
    const int wr   = w >> 2;            // 0..1  (M half)
    const int wc   = w & 3;             // 0..3  (N quarter)
    const int l15  = lane & 15;
    const int quad = lane >> 4;

    // Bijective XCD-aware swizzle for the 16x16 grid: XCD x owns a 4(M) x 8(N) patch.
    int bx = blockIdx.x, by = blockIdx.y;
    if (gridDim.x == 16 && gridDim.y == 16){
        const int id  = by * 16 + bx;       // dispatch-linear (blockIdx.x fastest)
        const int xcd = id & 7;             // default round-robin XCD assignment
        const int loc = id >> 3;            // 0..31 within XCD
        bx = (xcd & 3) * 4 + (loc & 3);
        by = (xcd >> 2) * 8 + (loc >> 2);
    }
    const int bm = bx * 256;
    const int bn = by * 256;

    // staging geometry: thread owns chunk g*512+tid of each 2048-chunk tile (16 B each);
    // row = g*64 + (tid>>3), swizzled k-chunk kc = (tid&7) ^ (row&7).
    const int r0 = tid >> 3;
    const int kc = (tid & 7) ^ (r0 & 7);

    // loop-invariant LDS read bases (buffer 0); frag mi at +mi*2048, buffer 1 at +32768.
    const unsigned asB = (unsigned)(size_t)&As[0][0];
    const unsigned bsB = (unsigned)(size_t)&Bs[0][0];
    const unsigned bA0 = asB + (unsigned)(((wr * 128 + l15) * 8 + ((0 + quad) ^ (l15 & 7))) * 16);
    const unsigned bA1 = asB + (unsigned)(((wr * 128 + l15) * 8 + ((4 + quad) ^ (l15 & 7))) * 16);
    const unsigned bB0 = bsB + (unsigned)(((wc * 64  + l15) * 8 + ((0 + quad) ^ (l15 & 7))) * 16);
    const unsigned bB1 = bsB + (unsigned)(((wc * 64  + l15) * 8 + ((4 + quad) ^ (l15 & 7))) * 16);

    f32x4 acc[8][4] = {};

    for (int seg = 0; seg < 2; ++seg){
        const unsigned short* A = seg ? A1 : A0;
        const unsigned short* B = seg ? B1 : B0;
        const int Kd = seg ? K1 : K0;
        if (Kd <= 0 || A == nullptr) continue;
        const int NT = Kd / 64;
        const size_t gstride = (size_t)64 * Kd;
        const unsigned short* pA = A + (size_t)bm * Kd + (size_t)r0 * Kd + kc * 8;
        const unsigned short* pB = B + (size_t)bn * Kd + (size_t)r0 * Kd + kc * 8;

        // ---- prologue: stage tile 0 into buf0, drain, publish ----
        #pragma unroll
        for (int g = 0; g < 4; ++g) async16(pA + g * gstride, &As[0][(g * 512 + tid) * 8]);
        #pragma unroll
        for (int g = 0; g < 4; ++g) async16(pB + g * gstride, &Bs[0][(g * 512 + tid) * 8]);
        VMCNT(0);
        __builtin_amdgcn_s_barrier();

        for (int t = 0; t < NT; ++t){
            const unsigned bo = (unsigned)(t & 1) * 32768u;
            const unsigned aA0 = bA0 + bo, aA1 = bA1 + bo, aB0 = bB0 + bo, aB1 = bB1 + bo;
            short8 fa0[4], fa1[4], fb0[4], fb1[4];

            // reads for cluster 0 (8 DS), then stage tile t+1, then cluster-1 reads (4 DS)
            #pragma unroll
            for (int ni = 0; ni < 4; ++ni) fb0[ni] = dsr128o(aB0, ni * 2048);
            #pragma unroll
            for (int mi = 0; mi < 4; ++mi) fa0[mi] = dsr128o(aA0, mi * 2048);
            if (t + 1 < NT){
                const int bi = (t + 1) & 1;
                const int kn = (t + 1) * 64;
                #pragma unroll
                for (int g = 0; g < 4; ++g) async16(pA + g * gstride + kn, &As[bi][(g * 512 + tid) * 8]);
                #pragma unroll
                for (int g = 0; g < 4; ++g) async16(pB + g * gstride + kn, &Bs[bi][(g * 512 + tid) * 8]);
            }
            #pragma unroll
            for (int mi = 0; mi < 4; ++mi) fa1[mi] = dsr128o(aA0, (4 + mi) * 2048);

            LGKM(4);                                   // fb0 + fa0 landed (fa1 may be in flight)
            __builtin_amdgcn_sched_barrier(0);
            __builtin_amdgcn_s_setprio(1);
            #pragma unroll
            for (int mi = 0; mi < 4; ++mi)
                #pragma unroll
                for (int ni = 0; ni < 4; ++ni)
                    acc[mi][ni] = __builtin_amdgcn_mfma_f32_16x16x32_bf16(
                        fa0[mi], fb0[ni], acc[mi][ni], 0, 0, 0);
            __builtin_amdgcn_s_setprio(0);

            // reads for cluster 2 (execute under cluster-0/1 MFMA)
            #pragma unroll
            for (int ni = 0; ni < 4; ++ni) fb1[ni] = dsr128o(aB1, ni * 2048);
            #pragma unroll
            for (int mi = 0; mi < 4; ++mi) fa0[mi] = dsr128o(aA1, mi * 2048);

            LGKM(8);                                   // fa1 landed
            __builtin_amdgcn_sched_barrier(0);
            __builtin_amdgcn_s_setprio(1);
            #pragma unroll
            for (int mi = 0; mi < 4; ++mi)
                #pragma unroll
                for (int ni = 0; ni < 4; ++ni)
                    acc[4 + mi][ni] = __builtin_amdgcn_mfma_f32_16x16x32_bf16(
                        fa1[mi], fb0[ni], acc[4 + mi][ni], 0, 0, 0);
            __builtin_amdgcn_s_setprio(0);

            // reads for cluster 3
            #pragma unroll
            for (int mi = 0; mi < 4; ++mi) fa1[mi] = dsr128o(aA1, (4 + mi) * 2048);

            LGKM(4);                                   // fb1 + fa0(ks1) landed
            __builtin_amdgcn_sched_barrier(0);
            __builtin_amdgcn_s_setprio(1);
            #pragma unroll
            for (int mi = 0; mi < 4; ++mi)
                #pragma unroll
                for (int ni = 0; ni < 4; ++ni)
                    acc[mi][ni] = __builtin_amdgcn_mfma_f32_16x16x32_bf16(
                        fa0[mi], fb1[ni], acc[mi][ni], 0, 0, 0);
            __builtin_amdgcn_s_setprio(0);

            LGKM(0);                                   // fa1(ks1) landed
            __builtin_amdgcn_sched_barrier(0);
            __builtin_amdgcn_s_setprio(1);
            #pragma unroll
            for (int mi = 0; mi < 4; ++mi)
                #pragma unroll
                for (int ni = 0; ni < 4; ++ni)
                    acc[4 + mi][ni] = __builtin_amdgcn_mfma_f32_16x16x32_bf16(
                        fa1[mi], fb1[ni], acc[4 + mi][ni], 0, 0, 0);
            __builtin_amdgcn_s_setprio(0);

            // tile boundary: own tile-t+1 loads drained (aged a full tile), then publish.
            if (t + 1 < NT){
                VMCNT(0);
                __builtin_amdgcn_s_barrier();
            }
        }
    }

    // ---- coalesced epilogue: stage C through LDS (reuse As), emit 16-B stores ----
    __syncthreads();                       // all waves done with As/Bs (vmcnt drained per-wave)
    float* myc = (float*)&As[0][0] + w * (16 * 68);    // per-wave 16 rows x 68 floats (padded)
    float bcol[4];
    #pragma unroll
    for (int ni = 0; ni < 4; ++ni){
        const int col = bn + wc * 64 + ni * 16 + l15;
        bcol[ni] = (bias0 ? bias0[col] : 0.f) + (bias1 ? bias1[col] : 0.f);
    }
    for (int mi = 0; mi < 8; ++mi){
        #pragma unroll
        for (int ni = 0; ni < 4; ++ni)
            #pragma unroll
            for (int r = 0; r < 4; ++r){
                float v = acc[mi][ni][r] + bcol[ni];
                if (act == 2) v = mish_act(v);
                myc[(quad * 4 + r) * 68 + ni * 16 + l15] = v;   // same-wave LDS, compiler-ordered
            }
        const int gr0 = bm + wr * 128 + mi * 16;
        if (out_bf16){
            #pragma unroll
            for (int s = 0; s < 2; ++s){
                const int rr = s * 8 + (lane >> 3);
                const int c0 = (lane & 7) * 8;
                const float4 u0 = *(const float4*)&myc[rr * 68 + c0];
                const float4 u1 = *(const float4*)&myc[rr * 68 + c0 + 4];
                ushort8 o;
                o[0]=f2bf(u0.x); o[1]=f2bf(u0.y); o[2]=f2bf(u0.z); o[3]=f2bf(u0.w);
                o[4]=f2bf(u1.x); o[5]=f2bf(u1.y); o[6]=f2bf(u1.z); o[7]=f2bf(u1.w);
                *(ushort8*)((unsigned short*)Y + (size_t)(gr0 + rr) * N + bn + wc * 64 + c0) = o;
            }
        } else {
            #pragma unroll
            for (int s = 0; s < 4; ++s){
                const int rr = s * 4 + quad;
                const int c0 = l15 * 4;
                const float4 u = *(const float4*)&myc[rr * 68 + c0];
                *(float4*)((float*)Y + (size_t)(gr0 + rr) * N + bn + wc * 64 + c0) = u;
            }
        }
    }
}

// ---------------- segmented scan, pass A ----------------
__global__ __launch_bounds__(256) void scan_passA(
    const float* __restrict__ kbuf, const float* __restrict__ vbuf,
    const int* __restrict__ start,
    float* __restrict__ chunkS, float* __restrict__ chunkZ, int* __restrict__ chunkFlag)
{
    const int c   = blockIdx.x;
    const int tid = threadIdx.x;
    const int j   = tid >> 2;
    const int i0  = (tid & 3) * 16;
    __shared__ float k_lds[64], v_lds[64];
    float s_loc[16];
    #pragma unroll
    for (int e = 0; e < 16; ++e) s_loc[e] = 0.f;
    float z_loc = 0.f;
    int flag = 0;
    const int t0 = c * CLEN;
    for (int tt = 0; tt < CLEN; ++tt){
        const int t = t0 + tt;
        if (tid < 64)       k_lds[tid]      = kbuf[(size_t)t*K_DIM + tid];
        else if (tid < 128) v_lds[tid - 64] = vbuf[(size_t)t*V_DIM + tid - 64];
        __syncthreads();
        const int st = start[t];
        if (st){
            #pragma unroll
            for (int e = 0; e < 16; ++e) s_loc[e] = 0.f;
            z_loc = 0.f;
            flag = 1;
        }
        const float vj = v_lds[j];
        #pragma unroll
        for (int e = 0; e < 16; ++e) s_loc[e] += k_lds[i0 + e] * vj;
        if (tid < 64) z_loc += k_lds[tid];
        __syncthreads();
    }
    #pragma unroll
    for (int e = 0; e < 16; ++e) chunkS[(size_t)c*4096 + (i0 + e)*64 + j] = s_loc[e];
    if (tid < 64) chunkZ[c*64 + tid] = z_loc;
    if (tid == 0) chunkFlag[c] = flag;
}

// ---------------- pass B: exclusive cross-chunk combine (64 blocks x 64 thr) ----------------
__global__ __launch_bounds__(64) void scan_passB(
    const float* __restrict__ chunkS, const float* __restrict__ chunkZ, const int* __restrict__ chunkFlag,
    const float* __restrict__ s0, const float* __restrict__ z0,
    float* __restrict__ carryS, float* __restrict__ carryZ)
{
    const int ij = blockIdx.x * 64 + threadIdx.x;
    float e = s0[ij];
    for (int c = 0; c < CHUNKS; ++c){
        carryS[(size_t)c*4096 + ij] = e;
        const int f   = chunkFlag[c];
        const float s = chunkS[(size_t)c*4096 + ij];
        e = f ? s : (e + s);
    }
    if (ij < 64){
        float ez = z0[ij];
        for (int c = 0; c < CHUNKS; ++c){
            carryZ[c*64 + ij] = ez;
            const int f   = chunkFlag[c];
            const float z = chunkZ[c*64 + ij];
            ez = f ? z : (ez + z);
        }
    }
}

// ---------------- pass C: replay with carry; emit s[t], z[t], att out (bf16) ----------------
__global__ __launch_bounds__(256) void scan_passC(
    const float* __restrict__ kbuf, const float* __restrict__ vbuf, const float* __restrict__ qbuf,
    const int* __restrict__ start,
    const float* __restrict__ carryS, const float* __restrict__ carryZ,
    float* __restrict__ s_out, float* __restrict__ z_out, unsigned short* __restrict__ attout)
{
    const int c   = blockIdx.x;
    const int tid = threadIdx.x;
    const int j   = tid >> 2;
    const int g   = tid & 3;
    const int i0  = g * 16;
    __shared__ float k_lds[64], v_lds[64], q_lds[64];
    __shared__ float numer_lds[64];
    __shared__ float stage[4096];
    float s_loc[16];
    #pragma unroll
    for (int e = 0; e < 16; ++e) s_loc[e] = carryS[(size_t)c*4096 + (i0 + e)*64 + j];
    float z_loc = (tid < 64) ? carryZ[c*64 + tid] : 0.f;

    const int t0 = c * CLEN;
    for (int tt = 0; tt < CLEN; ++tt){
        const int t = t0 + tt;
        if (tid < 64)       k_lds[tid]       = kbuf[(size_t)t*K_DIM + tid];
        else if (tid < 128) v_lds[tid - 64]  = vbuf[(size_t)t*V_DIM + tid - 64];
        else if (tid < 192) q_lds[tid - 128] = qbuf[(size_t)t*K_DIM + tid - 128];
        __syncthreads();
        const int st = start[t];
        if (st){
            #pragma unroll
            for (int e = 0; e < 16; ++e) s_loc[e] = 0.f;
        }
        const float vj = v_lds[j];
        float np = 0.f;
        #pragma unroll
        for (int e = 0; e < 16; ++e){
            s_loc[e] += k_lds[i0 + e] * vj;
            np += s_loc[e] * q_lds[i0 + e];
        }
        np += __shfl_down(np, 1, 64);
        np += __shfl_down(np, 2, 64);
        if (g == 0) numer_lds[j] = np;
        float denom = 1.f;
        if (tid < 64){
            z_loc = (st ? 0.f : z_loc) + k_lds[tid];
            z_out[(size_t)t*K_DIM + tid] = z_loc;
            float zs = z_loc;
            float qs = q_lds[tid];
            #pragma unroll
            for (int o = 32; o > 0; o >>= 1){
                zs += __shfl_down(zs, o, 64);
                qs += __shfl_down(qs, o, 64);
            }
            zs = __shfl(zs, 0, 64);
            qs = __shfl(qs, 0, 64);
            denom = fmaxf(zs * qs, 1e-6f);
        }
        #pragma unroll
        for (int e = 0; e < 16; ++e) stage[(i0 + e)*64 + j] = s_loc[e];
        __syncthreads();
        float4* so = (float4*)(s_out + (size_t)t*4096);
        const float4* stv = (const float4*)stage;
        #pragma unroll
        for (int r = 0; r < 4; ++r) so[tid + 256*r] = stv[tid + 256*r];
        if (tid < 64) attout[(size_t)t*V_DIM + tid] = f2bf(numer_lds[tid] / denom);
        __syncthreads();
    }
}

// ---------------- LayerNorm over H=4096, in place ----------------
__global__ __launch_bounds__(256) void ln_kernel(
    float* __restrict__ h, const float* __restrict__ g, const float* __restrict__ b)
{
    __shared__ float sm[4];
    const int t   = blockIdx.x;
    const int tid = threadIdx.x;
    float* row = h + (size_t)t * H_DIM;
    float4 v[4];
    float s = 0.f;
    #pragma unroll
    for (int r = 0; r < 4; ++r){
        v[r] = ((const float4*)row)[tid + 256*r];
        s += v[r].x + v[r].y + v[r].z + v[r].w;
    }
    #pragma unroll
    for (int o = 32; o > 0; o >>= 1) s += __shfl_down(s, o, 64);
    if ((tid & 63) == 0) sm[tid >> 6] = s;
    __syncthreads();
    const float mu = (sm[0] + sm[1] + sm[2] + sm[3]) * (1.f / H_DIM);
    __syncthreads();
    float sq = 0.f;
    #pragma unroll
    for (int r = 0; r < 4; ++r){
        float dx = v[r].x - mu, dy = v[r].y - mu, dz = v[r].z - mu, dw = v[r].w - mu;
        sq += dx*dx + dy*dy + dz*dz + dw*dw;
    }
    #pragma unroll
    for (int o = 32; o > 0; o >>= 1) sq += __shfl_down(sq, o, 64);
    if ((tid & 63) == 0) sm[tid >> 6] = sq;
    __syncthreads();
    const float var = (sm[0] + sm[1] + sm[2] + sm[3]) * (1.f / H_DIM);
    const float inv = rsqrtf(var + 1e-5f);
    #pragma unroll
    for (int r = 0; r < 4; ++r){
        const int i4 = tid + 256*r;
        const float4 gg = ((const float4*)g)[i4];
        const float4 bb = ((const float4*)b)[i4];
        float4 o;
        o.x = (v[r].x - mu) * inv * gg.x + bb.x;
        o.y = (v[r].y - mu) * inv * gg.y + bb.y;
        o.z = (v[r].z - mu) * inv * gg.z + bb.z;
        o.w = (v[r].w - mu) * inv * gg.w + bb.w;
        ((float4*)row)[i4] = o;
    }
}

extern "C" void kernel_launch(void* const* d_in, const int* in_sizes, int n_in,
                              void* d_out, int out_size, void* d_ws, size_t ws_size,
                              hipStream_t stream)
{
    (void)in_sizes; (void)n_in; (void)out_size; (void)ws_size;
    const float* x     = (const float*)d_in[0];
    const float* s0    = (const float*)d_in[1];
    const float* z0    = (const float*)d_in[2];
    const int*   start = (const int*)d_in[3];
    const float* Wk    = (const float*)d_in[5];
    const float* Wq    = (const float*)d_in[6];
    const float* Wv    = (const float*)d_in[7];
    const float* bv    = (const float*)d_in[8];
    const float* Wskip = (const float*)d_in[9];
    const float* bskip = (const float*)d_in[10];
    const float* W1    = (const float*)d_in[11];
    const float* b1    = (const float*)d_in[12];
    const float* W2    = (const float*)d_in[13];
    const float* b2    = (const float*)d_in[14];
    const float* W3    = (const float*)d_in[15];
    const float* b3    = (const float*)d_in[16];
    const float* ln_g  = (const float*)d_in[17];
    const float* ln_b  = (const float*)d_in[18];

    // ---- workspace carve (256B-aligned), total ~148 MB ----
    char* p = (char*)d_ws;
    auto alloc = [&](size_t bytes) -> void* {
        void* r = (void*)p; p += (bytes + 255) & ~(size_t)255; return r;
    };
    float* kbuf  = (float*)alloc((size_t)T_DIM * K_DIM * 4);
    float* qbuf  = (float*)alloc((size_t)T_DIM * K_DIM * 4);
    float* vbuf  = (float*)alloc((size_t)T_DIM * V_DIM * 4);
    float* chS   = (float*)alloc((size_t)CHUNKS * 4096 * 4);
    float* chZ   = (float*)alloc((size_t)CHUNKS * 64 * 4);
    float* caS   = (float*)alloc((size_t)CHUNKS * 4096 * 4);
    float* caZ   = (float*)alloc((size_t)CHUNKS * 64 * 4);
    int*   flags = (int*)  alloc((size_t)CHUNKS * 4);
    unsigned short* xb     = (unsigned short*)alloc((size_t)T_DIM * IN_DIM * 2);
    unsigned short* Wskipb = (unsigned short*)alloc((size_t)H_DIM * IN_DIM * 2);
    unsigned short* W1b    = (unsigned short*)alloc((size_t)H_DIM * V_DIM * 2);
    unsigned short* W2b    = (unsigned short*)alloc((size_t)H_DIM * H_DIM * 2);
    unsigned short* W3b    = (unsigned short*)alloc((size_t)H_DIM * H_DIM * 2);
    unsigned short* attb   = (unsigned short*)alloc((size_t)T_DIM * V_DIM * 2);
    unsigned short* h1b    = (unsigned short*)alloc((size_t)T_DIM * H_DIM * 2);
    unsigned short* h2b    = (unsigned short*)alloc((size_t)T_DIM * H_DIM * 2);

    float* hn  = (float*)d_out;                          // (T,H)
    float* s_o = hn  + (size_t)T_DIM * H_DIM;            // (T,K,V)
    float* z_o = s_o + (size_t)T_DIM * K_DIM * V_DIM;    // (T,1,K)

    // 0) prep: 3 projections + 5 bf16 conversions in ONE dispatch
    prep_kernel<<<2048, 256, 0, stream>>>(x, Wk, Wq, Wv, bv, kbuf, qbuf, vbuf,
                                          Wskip, W1, W2, W3, xb, Wskipb, W1b, W2b, W3b);

    // 1) segmented scan (3 passes); pass C emits att in bf16
    scan_passA<<<CHUNKS, 256, 0, stream>>>(kbuf, vbuf, start, chS, chZ, flags);
    scan_passB<<<64, 64, 0, stream>>>(chS, chZ, flags, s0, z0, caS, caZ);
    scan_passC<<<CHUNKS, 256, 0, stream>>>(kbuf, vbuf, qbuf, start, caS, caZ, s_o, z_o, attb);

    // 2) MLP: all three GEMMs on the wave-pipelined 256^2 kernel
    gemm256p<<<dim3(16, 16), 512, 0, stream>>>(
        attb, W1b, K_DIM, nullptr, nullptr, 0, b1, nullptr, h1b, H_DIM, 2, 1);
    gemm256p<<<dim3(16, 16), 512, 0, stream>>>(
        h1b, W2b, H_DIM, nullptr, nullptr, 0, b2, nullptr, h2b, H_DIM, 2, 1);
    // GEMM3 fused with skip: hn = h2@W3^T + x@Wskip^T + b3 + bskip (fp32 out)
    gemm256p<<<dim3(16, 16), 512, 0, stream>>>(
        h2b, W3b, H_DIM, xb, Wskipb, IN_DIM, b3, bskip, hn, H_DIM, 0, 0);

    // 3) LayerNorm in place on d_out
    ln_kernel<<<T_DIM, 256, 0, stream>>>(hn, ln_g, ln_b);
}

// Round 8
// 758.597 us; speedup vs baseline: 1.3675x; 1.0594x over previous
//
#include <hip/hip_runtime.h>
#include <math.h>

// Problem constants (from reference): T=4096, IN=512, K=64, V=64, H=4096
#define T_DIM 4096
#define IN_DIM 512
#define K_DIM 64
#define V_DIM 64
#define H_DIM 4096
#define CHUNKS 256
#define CLEN 16   // T_DIM / CHUNKS

typedef __attribute__((ext_vector_type(8))) short short8;           // 8 bf16 = 4 VGPRs
typedef __attribute__((ext_vector_type(4))) float f32x4;

// ---------------- activations ----------------
__device__ __forceinline__ float phi_act(float v){
    return v > 0.f ? (v + 1.f) : (expm1f(v) + 1.f);
}
__device__ __forceinline__ float mish_act(float v){
    float sp = fmaxf(v, 0.f) + log1pf(expf(-fabsf(v)));
    return v * tanhf(sp);
}
// fp32 -> bf16 round-to-nearest-even (bit trick)
__device__ __forceinline__ unsigned short f2bf(float f){
    union { float f; unsigned int u; } x; x.f = f;
    unsigned int u = x.u + 0x7fffu + ((x.u >> 16) & 1u);
    return (unsigned short)(u >> 16);
}

// async 16B global->LDS (dest = wave-uniform base + lane*16; layout must be contiguous per lane)
__device__ __forceinline__ void async16(const unsigned short* g, unsigned short* l){
    __builtin_amdgcn_global_load_lds(
        (const __attribute__((address_space(1))) unsigned int*)g,
        (__attribute__((address_space(3))) unsigned int*)l,
        16, 0, 0);
}

// inline-asm ds_read_b128 with compile-time immediate offset. Opaque to the
// compiler's waitcnt insertion -> we control lgkmcnt/vmcnt entirely; offset:imm
// keeps address VALU at zero inside the K-loop.
__device__ __forceinline__ short8 dsr128o(unsigned addr, int off){
    short8 d;
    asm volatile("ds_read_b128 %0, %1 offset:%2" : "=v"(d) : "v"(addr), "i"(off));
    return d;
}

#define LGKM(n)  asm volatile("s_waitcnt lgkmcnt(" #n ")" ::: "memory")
#define VMCNT(n) asm volatile("s_waitcnt vmcnt(" #n ")" ::: "memory")
#define SB0()    __builtin_amdgcn_sched_barrier(0)

// ---------------- prep kernel: 3 fp32 projections + 5 bf16 conversions, ONE dispatch -----
// blocks 0..191: projection (which = bid>>6): {k=phi(x@Wk^T), q=phi(x@Wq^T), v=x@Wv^T+bv}
// blocks 192.. : grid-stride bf16 conversion over {x, Wskip, W1, W2, W3} (9502720 float4s)
#define CVT_X4   524288          // T*IN/4
#define CVT_WS   524288          // H*IN/4
#define CVT_W1   65536           // H*V/4
#define CVT_W2   4194304         // H*H/4
#define CVT_TOT  9502720
__global__ __launch_bounds__(256) void prep_kernel(
    const float* __restrict__ x,
    const float* __restrict__ Wk, const float* __restrict__ Wq, const float* __restrict__ Wv,
    const float* __restrict__ bv,
    float* __restrict__ kbuf, float* __restrict__ qbuf, float* __restrict__ vbuf,
    const float* __restrict__ Wskip, const float* __restrict__ W1,
    const float* __restrict__ W2, const float* __restrict__ W3,
    unsigned short* __restrict__ xb, unsigned short* __restrict__ Wskipb,
    unsigned short* __restrict__ W1b, unsigned short* __restrict__ W2b,
    unsigned short* __restrict__ W3b)
{
    __shared__ float As[16][68];
    __shared__ float Bs[16][68];
    const int bid = blockIdx.x;
    const int tid = threadIdx.x;

    if (bid < 192){
        // ---- projection path (uniform per block; __syncthreads is block-uniform) ----
        const int which = bid >> 6;
        const float* B0 = which == 0 ? Wk : which == 1 ? Wq : Wv;
        float* Y        = which == 0 ? kbuf : which == 1 ? qbuf : vbuf;
        const int actp  = which < 2;
        const int bm    = (bid & 63) * 64;
        const int lrow  = tid >> 2;
        const int lk4   = (tid & 3) * 4;
        const int tm    = (tid >> 4) * 4;
        const int tn    = (tid & 15) * 4;
        float acc[4][4] = {};
        const float* aptr = x  + (size_t)(bm + lrow) * IN_DIM + lk4;
        const float* bptr = B0 + (size_t)lrow * IN_DIM + lk4;
        for (int k0 = 0; k0 < IN_DIM; k0 += 16){
            const float4 av  = *(const float4*)(aptr + k0);
            const float4 bv4 = *(const float4*)(bptr + k0);
            __syncthreads();
            As[lk4+0][lrow]=av.x;  As[lk4+1][lrow]=av.y;  As[lk4+2][lrow]=av.z;  As[lk4+3][lrow]=av.w;
            Bs[lk4+0][lrow]=bv4.x; Bs[lk4+1][lrow]=bv4.y; Bs[lk4+2][lrow]=bv4.z; Bs[lk4+3][lrow]=bv4.w;
            __syncthreads();
            #pragma unroll
            for (int kk = 0; kk < 16; ++kk){
                const float4 a = *(const float4*)&As[kk][tm];
                const float4 b = *(const float4*)&Bs[kk][tn];
                acc[0][0] += a.x*b.x; acc[0][1] += a.x*b.y; acc[0][2] += a.x*b.z; acc[0][3] += a.x*b.w;
                acc[1][0] += a.y*b.x; acc[1][1] += a.y*b.y; acc[1][2] += a.y*b.z; acc[1][3] += a.y*b.w;
                acc[2][0] += a.z*b.x; acc[2][1] += a.z*b.y; acc[2][2] += a.z*b.z; acc[2][3] += a.z*b.w;
                acc[3][0] += a.w*b.x; acc[3][1] += a.w*b.y; acc[3][2] += a.w*b.z; acc[3][3] += a.w*b.w;
            }
        }
        float badd[4] = {0.f, 0.f, 0.f, 0.f};
        if (which == 2){
            badd[0] = bv[tn+0]; badd[1] = bv[tn+1]; badd[2] = bv[tn+2]; badd[3] = bv[tn+3];
        }
        #pragma unroll
        for (int i = 0; i < 4; ++i){
            float r0 = acc[i][0] + badd[0];
            float r1 = acc[i][1] + badd[1];
            float r2 = acc[i][2] + badd[2];
            float r3 = acc[i][3] + badd[3];
            if (actp){ r0 = phi_act(r0); r1 = phi_act(r1); r2 = phi_act(r2); r3 = phi_act(r3); }
            *(float4*)&Y[(size_t)(bm + tm + i) * 64 + tn] = make_float4(r0, r1, r2, r3);
        }
        return;
    }

    // ---- conversion path: grid-stride over 5 segments ----
    const int nb = gridDim.x - 192;
    for (int i = (bid - 192) * 256 + tid; i < CVT_TOT; i += nb * 256){
        const float* src; unsigned short* dst; int off;
        if      (i < CVT_X4)                          { src = x;     dst = xb;     off = i; }
        else if (i < CVT_X4 + CVT_WS)                 { src = Wskip; dst = Wskipb; off = i - CVT_X4; }
        else if (i < CVT_X4 + CVT_WS + CVT_W1)        { src = W1;    dst = W1b;    off = i - CVT_X4 - CVT_WS; }
        else if (i < CVT_X4 + CVT_WS + CVT_W1 + CVT_W2){ src = W2;   dst = W2b;    off = i - CVT_X4 - CVT_WS - CVT_W1; }
        else                                          { src = W3;    dst = W3b;    off = i - CVT_X4 - CVT_WS - CVT_W1 - CVT_W2; }
        float4 v = ((const float4*)src)[off];
        ushort4 o;
        o.x = f2bf(v.x); o.y = f2bf(v.y); o.z = f2bf(v.z); o.w = f2bf(v.w);
        ((ushort4*)dst)[off] = o;
    }
}

// ---------------- 256x256 wave-pipelined bf16 MFMA GEMM (round-4 structure, laddered waits) ----
// BM=BN=256, BK=64, double-buffered LDS (128 KiB, 1 block/CU). 512 threads = 8 waves
// (2M x 4N); per-wave output 128x64 = acc f32x4[8][4] (AGPR).
// ONE barrier per K-tile; per-wave counted lgkmcnt LADDER (DS completes in-order/wave):
//   issue fb0(ops1-4), fa0(5-8); stage 8 loads of tile t+1 (vmcnt, not lgkm); fa1(9-12)
//   LGKM(7)->mi0 MFMA  LGKM(6)->mi1  LGKM(5)->mi2  LGKM(4)->mi3      (acc[0:4] x fb0)
//   issue fb1(13-16), fa0'(17-20)
//   LGKM(11)->mi0 ... LGKM(8)->mi3                                    (acc[4:8] x fb0, fa1)
//   issue fa1'(21-24)
//   LGKM(7)->mi0 ... LGKM(4)->mi3                                     (acc[0:4] x fb1, fa0')
//   LGKM(3)->mi0 ... LGKM(0)->mi3                                     (acc[4:8] x fb1, fa1')
//   VMCNT(0) ; s_barrier   (boundary: own tile-t+1 loads aged a full tile)
// Each sub-cluster releases exactly when its fragment retired -- correct AND earlier than
// a single conservative wait. Swizzle (measured 0-conflict): slot s of row r holds
// k-chunk s^(r&7); linear LDS dest, pre-swizzled global source, reads XOR the same.
// Two K-segments (A0,B0,K0)+(A1,B1,K1) accumulate into the same acc (fuses skip-GEMM).
// Epilogue: DIRECT stores (round-6 form; the LDS-staged variant measured +18us/GEMM and
// 164MB writes -- reverted).
__global__ __launch_bounds__(512, 2) void gemm256p(
    const unsigned short* __restrict__ A0, const unsigned short* __restrict__ B0, int K0,
    const unsigned short* __restrict__ A1, const unsigned short* __restrict__ B1, int K1,
    const float* __restrict__ bias0, const float* __restrict__ bias1,
    void* __restrict__ Y, int N, int act, int out_bf16)
{
    __shared__ unsigned short As[2][16384];   // 2 x 32 KiB
    __shared__ unsigned short Bs[2][16384];   // 2 x 32 KiB
    const int tid  = threadIdx.x;
    const int lane = tid & 63;
    const int w    = tid >> 6;          // wave 0..7
    const int wr   = w >> 2;            // 0..1  (M half)
    const int wc   = w & 3;             // 0..3  (N quarter)
    const int l15  = lane & 15;
    const int quad = lane >> 4;

    // Bijective XCD-aware swizzle for the 16x16 grid: XCD x owns a 4(M) x 8(N) patch.
    int bx = blockIdx.x, by = blockIdx.y;
    if (gridDim.x == 16 && gridDim.y == 16){
        const int id  = by * 16 + bx;       // dispatch-linear (blockIdx.x fastest)
        const int xcd = id & 7;             // default round-robin XCD assignment
        const int loc = id >> 3;            // 0..31 within XCD
        bx = (xcd & 3) * 4 + (loc & 3);
        by = (xcd >> 2) * 8 + (loc >> 2);
    }
    const int bm = bx * 256;
    const int bn = by * 256;

    // staging geometry: thread owns chunk g*512+tid of each 2048-chunk tile (16 B each);
    // row = g*64 + (tid>>3), swizzled k-chunk kc = (tid&7) ^ (row&7).
    const int r0 = tid >> 3;
    const int kc = (tid & 7) ^ (r0 & 7);

    // loop-invariant LDS read bases (buffer 0); frag mi at +mi*2048 B, buffer 1 at +32768 B.
    const unsigned asB = (unsigned)(size_t)&As[0][0];
    const unsigned bsB = (unsigned)(size_t)&Bs[0][0];
    const unsigned bA0 = asB + (unsigned)(((wr * 128 + l15) * 8 + ((0 + quad) ^ (l15 & 7))) * 16);
    const unsigned bA1 = asB + (unsigned)(((wr * 128 + l15) * 8 + ((4 + quad) ^ (l15 & 7))) * 16);
    const unsigned bB0 = bsB + (unsigned)(((wc * 64  + l15) * 8 + ((0 + quad) ^ (l15 & 7))) * 16);
    const unsigned bB1 = bsB + (unsigned)(((wc * 64  + l15) * 8 + ((4 + quad) ^ (l15 & 7))) * 16);

    f32x4 acc[8][4] = {};

    for (int seg = 0; seg < 2; ++seg){
        const unsigned short* A = seg ? A1 : A0;
        const unsigned short* B = seg ? B1 : B0;
        const int Kd = seg ? K1 : K0;
        if (Kd <= 0 || A == nullptr) continue;
        const int NT = Kd / 64;
        const size_t gstride = (size_t)64 * Kd;
        const unsigned short* pA = A + (size_t)bm * Kd + (size_t)r0 * Kd + kc * 8;
        const unsigned short* pB = B + (size_t)bn * Kd + (size_t)r0 * Kd + kc * 8;

        // ---- prologue: stage tile 0 into buf0, drain, publish ----
        #pragma unroll
        for (int g = 0; g < 4; ++g) async16(pA + g * gstride, &As[0][(g * 512 + tid) * 8]);
        #pragma unroll
        for (int g = 0; g < 4; ++g) async16(pB + g * gstride, &Bs[0][(g * 512 + tid) * 8]);
        VMCNT(0);
        __builtin_amdgcn_s_barrier();

        for (int t = 0; t < NT; ++t){
            const unsigned bo = (unsigned)(t & 1) * 32768u;
            const unsigned aA0 = bA0 + bo, aA1 = bA1 + bo, aB0 = bB0 + bo, aB1 = bB1 + bo;
            short8 fa0[4], fa1[4], fb0[4], fb1[4];

            // issue fb0 (ops 1-4), fa0 (5-8); stage tile t+1 (vmcnt); fa1 (9-12)
            #pragma unroll
            for (int ni = 0; ni < 4; ++ni) fb0[ni] = dsr128o(aB0, ni * 2048);
            #pragma unroll
            for (int mi = 0; mi < 4; ++mi) fa0[mi] = dsr128o(aA0, mi * 2048);
            if (t + 1 < NT){
                const int bi = (t + 1) & 1;
                const int kn = (t + 1) * 64;
                #pragma unroll
                for (int g = 0; g < 4; ++g) async16(pA + g * gstride + kn, &As[bi][(g * 512 + tid) * 8]);
                #pragma unroll
                for (int g = 0; g < 4; ++g) async16(pB + g * gstride + kn, &Bs[bi][(g * 512 + tid) * 8]);
            }
            #pragma unroll
            for (int mi = 0; mi < 4; ++mi) fa1[mi] = dsr128o(aA0, (4 + mi) * 2048);

            // cluster 0: acc[0:4] x fb0 (needs ops 1-8), laddered per mi
            __builtin_amdgcn_s_setprio(1);
            LGKM(7); SB0();
            #pragma unroll
            for (int ni = 0; ni < 4; ++ni)
                acc[0][ni] = __builtin_amdgcn_mfma_f32_16x16x32_bf16(fa0[0], fb0[ni], acc[0][ni], 0, 0, 0);
            LGKM(6); SB0();
            #pragma unroll
            for (int ni = 0; ni < 4; ++ni)
                acc[1][ni] = __builtin_amdgcn_mfma_f32_16x16x32_bf16(fa0[1], fb0[ni], acc[1][ni], 0, 0, 0);
            LGKM(5); SB0();
            #pragma unroll
            for (int ni = 0; ni < 4; ++ni)
                acc[2][ni] = __builtin_amdgcn_mfma_f32_16x16x32_bf16(fa0[2], fb0[ni], acc[2][ni], 0, 0, 0);
            LGKM(4); SB0();
            #pragma unroll
            for (int ni = 0; ni < 4; ++ni)
                acc[3][ni] = __builtin_amdgcn_mfma_f32_16x16x32_bf16(fa0[3], fb0[ni], acc[3][ni], 0, 0, 0);
            __builtin_amdgcn_s_setprio(0);

            // issue fb1 (13-16), fa0' (17-20)  -- execute under cluster-0/1 MFMA
            #pragma unroll
            for (int ni = 0; ni < 4; ++ni) fb1[ni] = dsr128o(aB1, ni * 2048);
            #pragma unroll
            for (int mi = 0; mi < 4; ++mi) fa0[mi] = dsr128o(aA1, mi * 2048);

            // cluster 1: acc[4:8] x fb0 (needs fa1 = ops 9-12), laddered
            __builtin_amdgcn_s_setprio(1);
            LGKM(11); SB0();
            #pragma unroll
            for (int ni = 0; ni < 4; ++ni)
                acc[4][ni] = __builtin_amdgcn_mfma_f32_16x16x32_bf16(fa1[0], fb0[ni], acc[4][ni], 0, 0, 0);
            LGKM(10); SB0();
            #pragma unroll
            for (int ni = 0; ni < 4; ++ni)
                acc[5][ni] = __builtin_amdgcn_mfma_f32_16x16x32_bf16(fa1[1], fb0[ni], acc[5][ni], 0, 0, 0);
            LGKM(9); SB0();
            #pragma unroll
            for (int ni = 0; ni < 4; ++ni)
                acc[6][ni] = __builtin_amdgcn_mfma_f32_16x16x32_bf16(fa1[2], fb0[ni], acc[6][ni], 0, 0, 0);
            LGKM(8); SB0();
            #pragma unroll
            for (int ni = 0; ni < 4; ++ni)
                acc[7][ni] = __builtin_amdgcn_mfma_f32_16x16x32_bf16(fa1[3], fb0[ni], acc[7][ni], 0, 0, 0);
            __builtin_amdgcn_s_setprio(0);

            // issue fa1' (21-24)
            #pragma unroll
            for (int mi = 0; mi < 4; ++mi) fa1[mi] = dsr128o(aA1, (4 + mi) * 2048);

            // cluster 2: acc[0:4] x fb1 (needs ops 13-20), laddered
            __builtin_amdgcn_s_setprio(1);
            LGKM(7); SB0();
            #pragma unroll
            for (int ni = 0; ni < 4; ++ni)
                acc[0][ni] = __builtin_amdgcn_mfma_f32_16x16x32_bf16(fa0[0], fb1[ni], acc[0][ni], 0, 0, 0);
            LGKM(6); SB0();
            #pragma unroll
            for (int ni = 0; ni < 4; ++ni)
                acc[1][ni] = __builtin_amdgcn_mfma_f32_16x16x32_bf16(fa0[1], fb1[ni], acc[1][ni], 0, 0, 0);
            LGKM(5); SB0();
            #pragma unroll
            for (int ni = 0; ni < 4; ++ni)
                acc[2][ni] = __builtin_amdgcn_mfma_f32_16x16x32_bf16(fa0[2], fb1[ni], acc[2][ni], 0, 0, 0);
            LGKM(4); SB0();
            #pragma unroll
            for (int ni = 0; ni < 4; ++ni)
                acc[3][ni] = __builtin_amdgcn_mfma_f32_16x16x32_bf16(fa0[3], fb1[ni], acc[3][ni], 0, 0, 0);

            // cluster 3: acc[4:8] x fb1 (needs ops 21-24), laddered
            LGKM(3); SB0();
            #pragma unroll
            for (int ni = 0; ni < 4; ++ni)
                acc[4][ni] = __builtin_amdgcn_mfma_f32_16x16x32_bf16(fa1[0], fb1[ni], acc[4][ni], 0, 0, 0);
            LGKM(2); SB0();
            #pragma unroll
            for (int ni = 0; ni < 4; ++ni)
                acc[5][ni] = __builtin_amdgcn_mfma_f32_16x16x32_bf16(fa1[1], fb1[ni], acc[5][ni], 0, 0, 0);
            LGKM(1); SB0();
            #pragma unroll
            for (int ni = 0; ni < 4; ++ni)
                acc[6][ni] = __builtin_amdgcn_mfma_f32_16x16x32_bf16(fa1[2], fb1[ni], acc[6][ni], 0, 0, 0);
            LGKM(0); SB0();
            #pragma unroll
            for (int ni = 0; ni < 4; ++ni)
                acc[7][ni] = __builtin_amdgcn_mfma_f32_16x16x32_bf16(fa1[3], fb1[ni], acc[7][ni], 0, 0, 0);
            __builtin_amdgcn_s_setprio(0);

            // tile boundary: own tile-t+1 loads drained (aged a full tile), then publish.
            if (t + 1 < NT){
                VMCNT(0);
                __builtin_amdgcn_s_barrier();
            }
        }
        // inter-segment: next prologue's VMCNT(0)+barrier is the rendezvous; buffer
        // written next (buf0) had its reads complete before the last boundary barrier.
    }

    // epilogue (direct stores): C/D mapping col=lane&15, row=quad*4+reg
    #pragma unroll
    for (int ni = 0; ni < 4; ++ni){
        const int col = bn + wc * 64 + ni * 16 + l15;
        float bb = 0.f;
        if (bias0) bb += bias0[col];
        if (bias1) bb += bias1[col];
        #pragma unroll
        for (int mi = 0; mi < 8; ++mi){
            #pragma unroll
            for (int r = 0; r < 4; ++r){
                const int row = bm + wr * 128 + mi * 16 + quad * 4 + r;
                float v = acc[mi][ni][r] + bb;
                if (act == 2) v = mish_act(v);
                if (out_bf16) ((unsigned short*)Y)[(size_t)row * N + col] = f2bf(v);
                else          ((float*)Y)[(size_t)row * N + col] = v;
            }
        }
    }
}

// ---------------- segmented scan, pass A ----------------
__global__ __launch_bounds__(256) void scan_passA(
    const float* __restrict__ kbuf, const float* __restrict__ vbuf,
    const int* __restrict__ start,
    float* __restrict__ chunkS, float* __restrict__ chunkZ, int* __restrict__ chunkFlag)
{
    const int c   = blockIdx.x;
    const int tid = threadIdx.x;
    const int j   = tid >> 2;
    const int i0  = (tid & 3) * 16;
    __shared__ float k_lds[64], v_lds[64];
    float s_loc[16];
    #pragma unroll
    for (int e = 0; e < 16; ++e) s_loc[e] = 0.f;
    float z_loc = 0.f;
    int flag = 0;
    const int t0 = c * CLEN;
    for (int tt = 0; tt < CLEN; ++tt){
        const int t = t0 + tt;
        if (tid < 64)       k_lds[tid]      = kbuf[(size_t)t*K_DIM + tid];
        else if (tid < 128) v_lds[tid - 64] = vbuf[(size_t)t*V_DIM + tid - 64];
        __syncthreads();
        const int st = start[t];
        if (st){
            #pragma unroll
            for (int e = 0; e < 16; ++e) s_loc[e] = 0.f;
            z_loc = 0.f;
            flag = 1;
        }
        const float vj = v_lds[j];
        #pragma unroll
        for (int e = 0; e < 16; ++e) s_loc[e] += k_lds[i0 + e] * vj;
        if (tid < 64) z_loc += k_lds[tid];
        __syncthreads();
    }
    #pragma unroll
    for (int e = 0; e < 16; ++e) chunkS[(size_t)c*4096 + (i0 + e)*64 + j] = s_loc[e];
    if (tid < 64) chunkZ[c*64 + tid] = z_loc;
    if (tid == 0) chunkFlag[c] = flag;
}

// ---------------- pass B: exclusive cross-chunk combine (64 blocks x 64 thr) ----------------
__global__ __launch_bounds__(64) void scan_passB(
    const float* __restrict__ chunkS, const float* __restrict__ chunkZ, const int* __restrict__ chunkFlag,
    const float* __restrict__ s0, const float* __restrict__ z0,
    float* __restrict__ carryS, float* __restrict__ carryZ)
{
    const int ij = blockIdx.x * 64 + threadIdx.x;
    float e = s0[ij];
    for (int c = 0; c < CHUNKS; ++c){
        carryS[(size_t)c*4096 + ij] = e;
        const int f   = chunkFlag[c];
        const float s = chunkS[(size_t)c*4096 + ij];
        e = f ? s : (e + s);
    }
    if (ij < 64){
        float ez = z0[ij];
        for (int c = 0; c < CHUNKS; ++c){
            carryZ[c*64 + ij] = ez;
            const int f   = chunkFlag[c];
            const float z = chunkZ[c*64 + ij];
            ez = f ? z : (ez + z);
        }
    }
}

// ---------------- pass C: replay with carry; emit s[t], z[t], att out (bf16) ----------------
__global__ __launch_bounds__(256) void scan_passC(
    const float* __restrict__ kbuf, const float* __restrict__ vbuf, const float* __restrict__ qbuf,
    const int* __restrict__ start,
    const float* __restrict__ carryS, const float* __restrict__ carryZ,
    float* __restrict__ s_out, float* __restrict__ z_out, unsigned short* __restrict__ attout)
{
    const int c   = blockIdx.x;
    const int tid = threadIdx.x;
    const int j   = tid >> 2;
    const int g   = tid & 3;
    const int i0  = g * 16;
    __shared__ float k_lds[64], v_lds[64], q_lds[64];
    __shared__ float numer_lds[64];
    __shared__ float stage[4096];
    float s_loc[16];
    #pragma unroll
    for (int e = 0; e < 16; ++e) s_loc[e] = carryS[(size_t)c*4096 + (i0 + e)*64 + j];
    float z_loc = (tid < 64) ? carryZ[c*64 + tid] : 0.f;

    const int t0 = c * CLEN;
    for (int tt = 0; tt < CLEN; ++tt){
        const int t = t0 + tt;
        if (tid < 64)       k_lds[tid]       = kbuf[(size_t)t*K_DIM + tid];
        else if (tid < 128) v_lds[tid - 64]  = vbuf[(size_t)t*V_DIM + tid - 64];
        else if (tid < 192) q_lds[tid - 128] = qbuf[(size_t)t*K_DIM + tid - 128];
        __syncthreads();
        const int st = start[t];
        if (st){
            #pragma unroll
            for (int e = 0; e < 16; ++e) s_loc[e] = 0.f;
        }
        const float vj = v_lds[j];
        float np = 0.f;
        #pragma unroll
        for (int e = 0; e < 16; ++e){
            s_loc[e] += k_lds[i0 + e] * vj;
            np += s_loc[e] * q_lds[i0 + e];
        }
        np += __shfl_down(np, 1, 64);
        np += __shfl_down(np, 2, 64);
        if (g == 0) numer_lds[j] = np;
        float denom = 1.f;
        if (tid < 64){
            z_loc = (st ? 0.f : z_loc) + k_lds[tid];
            z_out[(size_t)t*K_DIM + tid] = z_loc;
            float zs = z_loc;
            float qs = q_lds[tid];
            #pragma unroll
            for (int o = 32; o > 0; o >>= 1){
                zs += __shfl_down(zs, o, 64);
                qs += __shfl_down(qs, o, 64);
            }
            zs = __shfl(zs, 0, 64);
            qs = __shfl(qs, 0, 64);
            denom = fmaxf(zs * qs, 1e-6f);
        }
        #pragma unroll
        for (int e = 0; e < 16; ++e) stage[(i0 + e)*64 + j] = s_loc[e];
        __syncthreads();
        float4* so = (float4*)(s_out + (size_t)t*4096);
        const float4* stv = (const float4*)stage;
        #pragma unroll
        for (int r = 0; r < 4; ++r) so[tid + 256*r] = stv[tid + 256*r];
        if (tid < 64) attout[(size_t)t*V_DIM + tid] = f2bf(numer_lds[tid] / denom);
        __syncthreads();
    }
}

// ---------------- LayerNorm over H=4096, in place ----------------
__global__ __launch_bounds__(256) void ln_kernel(
    float* __restrict__ h, const float* __restrict__ g, const float* __restrict__ b)
{
    __shared__ float sm[4];
    const int t   = blockIdx.x;
    const int tid = threadIdx.x;
    float* row = h + (size_t)t * H_DIM;
    float4 v[4];
    float s = 0.f;
    #pragma unroll
    for (int r = 0; r < 4; ++r){
        v[r] = ((const float4*)row)[tid + 256*r];
        s += v[r].x + v[r].y + v[r].z + v[r].w;
    }
    #pragma unroll
    for (int o = 32; o > 0; o >>= 1) s += __shfl_down(s, o, 64);
    if ((tid & 63) == 0) sm[tid >> 6] = s;
    __syncthreads();
    const float mu = (sm[0] + sm[1] + sm[2] + sm[3]) * (1.f / H_DIM);
    __syncthreads();
    float sq = 0.f;
    #pragma unroll
    for (int r = 0; r < 4; ++r){
        float dx = v[r].x - mu, dy = v[r].y - mu, dz = v[r].z - mu, dw = v[r].w - mu;
        sq += dx*dx + dy*dy + dz*dz + dw*dw;
    }
    #pragma unroll
    for (int o = 32; o > 0; o >>= 1) sq += __shfl_down(sq, o, 64);
    if ((tid & 63) == 0) sm[tid >> 6] = sq;
    __syncthreads();
    const float var = (sm[0] + sm[1] + sm[2] + sm[3]) * (1.f / H_DIM);
    const float inv = rsqrtf(var + 1e-5f);
    #pragma unroll
    for (int r = 0; r < 4; ++r){
        const int i4 = tid + 256*r;
        const float4 gg = ((const float4*)g)[i4];
        const float4 bb = ((const float4*)b)[i4];
        float4 o;
        o.x = (v[r].x - mu) * inv * gg.x + bb.x;
        o.y = (v[r].y - mu) * inv * gg.y + bb.y;
        o.z = (v[r].z - mu) * inv * gg.z + bb.z;
        o.w = (v[r].w - mu) * inv * gg.w + bb.w;
        ((float4*)row)[i4] = o;
    }
}

extern "C" void kernel_launch(void* const* d_in, const int* in_sizes, int n_in,
                              void* d_out, int out_size, void* d_ws, size_t ws_size,
                              hipStream_t stream)
{
    (void)in_sizes; (void)n_in; (void)out_size; (void)ws_size;
    const float* x     = (const float*)d_in[0];
    const float* s0    = (const float*)d_in[1];
    const float* z0    = (const float*)d_in[2];
    const int*   start = (const int*)d_in[3];
    const float* Wk    = (const float*)d_in[5];
    const float* Wq    = (const float*)d_in[6];
    const float* Wv    = (const float*)d_in[7];
    const float* bv    = (const float*)d_in[8];
    const float* Wskip = (const float*)d_in[9];
    const float* bskip = (const float*)d_in[10];
    const float* W1    = (const float*)d_in[11];
    const float* b1    = (const float*)d_in[12];
    const float* W2    = (const float*)d_in[13];
    const float* b2    = (const float*)d_in[14];
    const float* W3    = (const float*)d_in[15];
    const float* b3    = (const float*)d_in[16];
    const float* ln_g  = (const float*)d_in[17];
    const float* ln_b  = (const float*)d_in[18];

    // ---- workspace carve (256B-aligned), total ~148 MB ----
    char* p = (char*)d_ws;
    auto alloc = [&](size_t bytes) -> void* {
        void* r = (void*)p; p += (bytes + 255) & ~(size_t)255; return r;
    };
    float* kbuf  = (float*)alloc((size_t)T_DIM * K_DIM * 4);
    float* qbuf  = (float*)alloc((size_t)T_DIM * K_DIM * 4);
    float* vbuf  = (float*)alloc((size_t)T_DIM * V_DIM * 4);
    float* chS   = (float*)alloc((size_t)CHUNKS * 4096 * 4);
    float* chZ   = (float*)alloc((size_t)CHUNKS * 64 * 4);
    float* caS   = (float*)alloc((size_t)CHUNKS * 4096 * 4);
    float* caZ   = (float*)alloc((size_t)CHUNKS * 64 * 4);
    int*   flags = (int*)  alloc((size_t)CHUNKS * 4);
    unsigned short* xb     = (unsigned short*)alloc((size_t)T_DIM * IN_DIM * 2);
    unsigned short* Wskipb = (unsigned short*)alloc((size_t)H_DIM * IN_DIM * 2);
    unsigned short* W1b    = (unsigned short*)alloc((size_t)H_DIM * V_DIM * 2);
    unsigned short* W2b    = (unsigned short*)alloc((size_t)H_DIM * H_DIM * 2);
    unsigned short* W3b    = (unsigned short*)alloc((size_t)H_DIM * H_DIM * 2);
    unsigned short* attb   = (unsigned short*)alloc((size_t)T_DIM * V_DIM * 2);
    unsigned short* h1b    = (unsigned short*)alloc((size_t)T_DIM * H_DIM * 2);
    unsigned short* h2b    = (unsigned short*)alloc((size_t)T_DIM * H_DIM * 2);

    float* hn  = (float*)d_out;                          // (T,H)
    float* s_o = hn  + (size_t)T_DIM * H_DIM;            // (T,K,V)
    float* z_o = s_o + (size_t)T_DIM * K_DIM * V_DIM;    // (T,1,K)

    // 0) prep: 3 projections + 5 bf16 conversions in ONE dispatch
    prep_kernel<<<2048, 256, 0, stream>>>(x, Wk, Wq, Wv, bv, kbuf, qbuf, vbuf,
                                          Wskip, W1, W2, W3, xb, Wskipb, W1b, W2b, W3b);

    // 1) segmented scan (3 passes); pass C emits att in bf16
    scan_passA<<<CHUNKS, 256, 0, stream>>>(kbuf, vbuf, start, chS, chZ, flags);
    scan_passB<<<64, 64, 0, stream>>>(chS, chZ, flags, s0, z0, caS, caZ);
    scan_passC<<<CHUNKS, 256, 0, stream>>>(kbuf, vbuf, qbuf, start, caS, caZ, s_o, z_o, attb);

    // 2) MLP: all three GEMMs on the wave-pipelined 256^2 kernel
    gemm256p<<<dim3(16, 16), 512, 0, stream>>>(
        attb, W1b, K_DIM, nullptr, nullptr, 0, b1, nullptr, h1b, H_DIM, 2, 1);
    gemm256p<<<dim3(16, 16), 512, 0, stream>>>(
        h1b, W2b, H_DIM, nullptr, nullptr, 0, b2, nullptr, h2b, H_DIM, 2, 1);
    // GEMM3 fused with skip: hn = h2@W3^T + x@Wskip^T + b3 + bskip (fp32 out)
    gemm256p<<<dim3(16, 16), 512, 0, stream>>>(
        h2b, W3b, H_DIM, xb, Wskipb, IN_DIM, b3, bskip, hn, H_DIM, 0, 0);

    // 3) LayerNorm in place on d_out
    ln_kernel<<<T_DIM, 256, 0, stream>>>(hn, ln_g, ln_b);
}

// Round 10
// 616.699 us; speedup vs baseline: 1.6821x; 1.2301x over previous
//
#include <hip/hip_runtime.h>
#include <math.h>

// Problem constants (from reference): T=4096, IN=512, K=64, V=64, H=4096
#define T_DIM 4096
#define IN_DIM 512
#define K_DIM 64
#define V_DIM 64
#define H_DIM 4096
#define CHUNKS 256
#define CLEN 16   // T_DIM / CHUNKS

typedef __attribute__((ext_vector_type(8))) short short8;           // 8 bf16 = 4 VGPRs
typedef __attribute__((ext_vector_type(4))) float f32x4;

// ---------------- activations ----------------
__device__ __forceinline__ float phi_act(float v){
    return v > 0.f ? (v + 1.f) : (expm1f(v) + 1.f);
}
// mish(x) = x*tanh(softplus(x)) = x*(1 - 2/(u*(u+2)+2)), u=e^x  (exact identity).
// Branch-free; limits: x->+inf -> x (2/inf=0), x->-inf -> x*e^x -> 0.
__device__ __forceinline__ float mish_act(float v){
    const float u = __expf(v);
    const float w = u * (u + 2.f);
    return v * (1.f - 2.f / (w + 2.f));
}
// fp32 -> bf16 round-to-nearest-even (bit trick)
__device__ __forceinline__ unsigned short f2bf(float f){
    union { float f; unsigned int u; } x; x.f = f;
    unsigned int u = x.u + 0x7fffu + ((x.u >> 16) & 1u);
    return (unsigned short)(u >> 16);
}

// async 16B global->LDS (dest = wave-uniform base + lane*16; layout must be contiguous per lane)
__device__ __forceinline__ void async16(const unsigned short* g, unsigned short* l){
    __builtin_amdgcn_global_load_lds(
        (const __attribute__((address_space(1))) unsigned int*)g,
        (__attribute__((address_space(3))) unsigned int*)l,
        16, 0, 0);
}

// inline-asm ds_read_b128 with compile-time immediate offset. Opaque to the
// compiler's waitcnt insertion -> we control lgkmcnt/vmcnt entirely; offset:imm
// keeps address VALU at zero inside the K-loop.
__device__ __forceinline__ short8 dsr128o(unsigned addr, int off){
    short8 d;
    asm volatile("ds_read_b128 %0, %1 offset:%2" : "=v"(d) : "v"(addr), "i"(off));
    return d;
}

#define LGKM(n)  asm volatile("s_waitcnt lgkmcnt(" #n ")" ::: "memory")
#define VMCNT(n) asm volatile("s_waitcnt vmcnt(" #n ")" ::: "memory")
#define SB0()    __builtin_amdgcn_sched_barrier(0)

// ---------------- prep kernel: 3 fp32 projections + 5 bf16 conversions, ONE dispatch -----
// blocks 0..191: projection (which = bid>>6): {k=phi(x@Wk^T), q=phi(x@Wq^T), v=x@Wv^T+bv}
// blocks 192.. : grid-stride bf16 conversion over {x, Wskip, W1, W2, W3} (9502720 float4s)
#define CVT_X4   524288          // T*IN/4
#define CVT_WS   524288          // H*IN/4
#define CVT_W1   65536           // H*V/4
#define CVT_W2   4194304         // H*H/4
#define CVT_TOT  9502720
__global__ __launch_bounds__(256) void prep_kernel(
    const float* __restrict__ x,
    const float* __restrict__ Wk, const float* __restrict__ Wq, const float* __restrict__ Wv,
    const float* __restrict__ bv,
    float* __restrict__ kbuf, float* __restrict__ qbuf, float* __restrict__ vbuf,
    const float* __restrict__ Wskip, const float* __restrict__ W1,
    const float* __restrict__ W2, const float* __restrict__ W3,
    unsigned short* __restrict__ xb, unsigned short* __restrict__ Wskipb,
    unsigned short* __restrict__ W1b, unsigned short* __restrict__ W2b,
    unsigned short* __restrict__ W3b)
{
    __shared__ float As[16][68];
    __shared__ float Bs[16][68];
    const int bid = blockIdx.x;
    const int tid = threadIdx.x;

    if (bid < 192){
        // ---- projection path (uniform per block; __syncthreads is block-uniform) ----
        const int which = bid >> 6;
        const float* B0 = which == 0 ? Wk : which == 1 ? Wq : Wv;
        float* Y        = which == 0 ? kbuf : which == 1 ? qbuf : vbuf;
        const int actp  = which < 2;
        const int bm    = (bid & 63) * 64;
        const int lrow  = tid >> 2;
        const int lk4   = (tid & 3) * 4;
        const int tm    = (tid >> 4) * 4;
        const int tn    = (tid & 15) * 4;
        float acc[4][4] = {};
        const float* aptr = x  + (size_t)(bm + lrow) * IN_DIM + lk4;
        const float* bptr = B0 + (size_t)lrow * IN_DIM + lk4;
        for (int k0 = 0; k0 < IN_DIM; k0 += 16){
            const float4 av  = *(const float4*)(aptr + k0);
            const float4 bv4 = *(const float4*)(bptr + k0);
            __syncthreads();
            As[lk4+0][lrow]=av.x;  As[lk4+1][lrow]=av.y;  As[lk4+2][lrow]=av.z;  As[lk4+3][lrow]=av.w;
            Bs[lk4+0][lrow]=bv4.x; Bs[lk4+1][lrow]=bv4.y; Bs[lk4+2][lrow]=bv4.z; Bs[lk4+3][lrow]=bv4.w;
            __syncthreads();
            #pragma unroll
            for (int kk = 0; kk < 16; ++kk){
                const float4 a = *(const float4*)&As[kk][tm];
                const float4 b = *(const float4*)&Bs[kk][tn];
                acc[0][0] += a.x*b.x; acc[0][1] += a.x*b.y; acc[0][2] += a.x*b.z; acc[0][3] += a.x*b.w;
                acc[1][0] += a.y*b.x; acc[1][1] += a.y*b.y; acc[1][2] += a.y*b.z; acc[1][3] += a.y*b.w;
                acc[2][0] += a.z*b.x; acc[2][1] += a.z*b.y; acc[2][2] += a.z*b.z; acc[2][3] += a.z*b.w;
                acc[3][0] += a.w*b.x; acc[3][1] += a.w*b.y; acc[3][2] += a.w*b.z; acc[3][3] += a.w*b.w;
            }
        }
        float badd[4] = {0.f, 0.f, 0.f, 0.f};
        if (which == 2){
            badd[0] = bv[tn+0]; badd[1] = bv[tn+1]; badd[2] = bv[tn+2]; badd[3] = bv[tn+3];
        }
        #pragma unroll
        for (int i = 0; i < 4; ++i){
            float r0 = acc[i][0] + badd[0];
            float r1 = acc[i][1] + badd[1];
            float r2 = acc[i][2] + badd[2];
            float r3 = acc[i][3] + badd[3];
            if (actp){ r0 = phi_act(r0); r1 = phi_act(r1); r2 = phi_act(r2); r3 = phi_act(r3); }
            *(float4*)&Y[(size_t)(bm + tm + i) * 64 + tn] = make_float4(r0, r1, r2, r3);
        }
        return;
    }

    // ---- conversion path: grid-stride over 5 segments ----
    const int nb = gridDim.x - 192;
    for (int i = (bid - 192) * 256 + tid; i < CVT_TOT; i += nb * 256){
        const float* src; unsigned short* dst; int off;
        if      (i < CVT_X4)                          { src = x;     dst = xb;     off = i; }
        else if (i < CVT_X4 + CVT_WS)                 { src = Wskip; dst = Wskipb; off = i - CVT_X4; }
        else if (i < CVT_X4 + CVT_WS + CVT_W1)        { src = W1;    dst = W1b;    off = i - CVT_X4 - CVT_WS; }
        else if (i < CVT_X4 + CVT_WS + CVT_W1 + CVT_W2){ src = W2;   dst = W2b;    off = i - CVT_X4 - CVT_WS - CVT_W1; }
        else                                          { src = W3;    dst = W3b;    off = i - CVT_X4 - CVT_WS - CVT_W1 - CVT_W2; }
        float4 v = ((const float4*)src)[off];
        ushort4 o;
        o.x = f2bf(v.x); o.y = f2bf(v.y); o.z = f2bf(v.z); o.w = f2bf(v.w);
        ((ushort4*)dst)[off] = o;
    }
}

// ---------------- 256x256 wave-pipelined bf16 MFMA GEMM (round-8 verified form) ----
// BM=BN=256, BK=64, double-buffered LDS (128 KiB, 1 block/CU). 512 threads = 8 waves
// (2M x 4N); per-wave output 128x64 = acc f32x4[8][4] (AGPR).
// ONE barrier per K-tile; per-wave counted lgkmcnt LADDER (DS completes in-order/wave).
// Each sub-cluster releases exactly when its fragment retired. Swizzle (measured
// 0-conflict): slot s of row r holds k-chunk s^(r&7); linear LDS dest, pre-swizzled
// global source, reads XOR the same. Direct-store epilogue (LDS-staged variant measured
// +18us/GEMM and 164MB writes -- rejected). Two K-segments accumulate (fuses skip-GEMM).
__global__ __launch_bounds__(512, 2) void gemm256p(
    const unsigned short* __restrict__ A0, const unsigned short* __restrict__ B0, int K0,
    const unsigned short* __restrict__ A1, const unsigned short* __restrict__ B1, int K1,
    const float* __restrict__ bias0, const float* __restrict__ bias1,
    void* __restrict__ Y, int N, int act, int out_bf16)
{
    __shared__ unsigned short As[2][16384];   // 2 x 32 KiB
    __shared__ unsigned short Bs[2][16384];   // 2 x 32 KiB
    const int tid  = threadIdx.x;
    const int lane = tid & 63;
    const int w    = tid >> 6;          // wave 0..7
    const int wr   = w >> 2;            // 0..1  (M half)
    const int wc   = w & 3;             // 0..3  (N quarter)
    const int l15  = lane & 15;
    const int quad = lane >> 4;

    // Bijective XCD-aware swizzle for the 16x16 grid: XCD x owns a 4(M) x 8(N) patch.
    int bx = blockIdx.x, by = blockIdx.y;
    if (gridDim.x == 16 && gridDim.y == 16){
        const int id  = by * 16 + bx;       // dispatch-linear (blockIdx.x fastest)
        const int xcd = id & 7;             // default round-robin XCD assignment
        const int loc = id >> 3;            // 0..31 within XCD
        bx = (xcd & 3) * 4 + (loc & 3);
        by = (xcd >> 2) * 8 + (loc >> 2);
    }
    const int bm = bx * 256;
    const int bn = by * 256;

    // staging geometry: thread owns chunk g*512+tid of each 2048-chunk tile (16 B each);
    // row = g*64 + (tid>>3), swizzled k-chunk kc = (tid&7) ^ (row&7).
    const int r0 = tid >> 3;
    const int kc = (tid & 7) ^ (r0 & 7);

    // loop-invariant LDS read bases (buffer 0); frag mi at +mi*2048 B, buffer 1 at +32768 B.
    const unsigned asB = (unsigned)(size_t)&As[0][0];
    const unsigned bsB = (unsigned)(size_t)&Bs[0][0];
    const unsigned bA0 = asB + (unsigned)(((wr * 128 + l15) * 8 + ((0 + quad) ^ (l15 & 7))) * 16);
    const unsigned bA1 = asB + (unsigned)(((wr * 128 + l15) * 8 + ((4 + quad) ^ (l15 & 7))) * 16);
    const unsigned bB0 = bsB + (unsigned)(((wc * 64  + l15) * 8 + ((0 + quad) ^ (l15 & 7))) * 16);
    const unsigned bB1 = bsB + (unsigned)(((wc * 64  + l15) * 8 + ((4 + quad) ^ (l15 & 7))) * 16);

    f32x4 acc[8][4] = {};

    for (int seg = 0; seg < 2; ++seg){
        const unsigned short* A = seg ? A1 : A0;
        const unsigned short* B = seg ? B1 : B0;
        const int Kd = seg ? K1 : K0;
        if (Kd <= 0 || A == nullptr) continue;
        const int NT = Kd / 64;
        const size_t gstride = (size_t)64 * Kd;
        const unsigned short* pA = A + (size_t)bm * Kd + (size_t)r0 * Kd + kc * 8;
        const unsigned short* pB = B + (size_t)bn * Kd + (size_t)r0 * Kd + kc * 8;

        // ---- prologue: stage tile 0 into buf0, drain, publish ----
        #pragma unroll
        for (int g = 0; g < 4; ++g) async16(pA + g * gstride, &As[0][(g * 512 + tid) * 8]);
        #pragma unroll
        for (int g = 0; g < 4; ++g) async16(pB + g * gstride, &Bs[0][(g * 512 + tid) * 8]);
        VMCNT(0);
        __builtin_amdgcn_s_barrier();

        for (int t = 0; t < NT; ++t){
            const unsigned bo = (unsigned)(t & 1) * 32768u;
            const unsigned aA0 = bA0 + bo, aA1 = bA1 + bo, aB0 = bB0 + bo, aB1 = bB1 + bo;
            short8 fa0[4], fa1[4], fb0[4], fb1[4];

            // issue fb0 (ops 1-4), fa0 (5-8); stage tile t+1 (vmcnt); fa1 (9-12)
            #pragma unroll
            for (int ni = 0; ni < 4; ++ni) fb0[ni] = dsr128o(aB0, ni * 2048);
            #pragma unroll
            for (int mi = 0; mi < 4; ++mi) fa0[mi] = dsr128o(aA0, mi * 2048);
            if (t + 1 < NT){
                const int bi = (t + 1) & 1;
                const int kn = (t + 1) * 64;
                #pragma unroll
                for (int g = 0; g < 4; ++g) async16(pA + g * gstride + kn, &As[bi][(g * 512 + tid) * 8]);
                #pragma unroll
                for (int g = 0; g < 4; ++g) async16(pB + g * gstride + kn, &Bs[bi][(g * 512 + tid) * 8]);
            }
            #pragma unroll
            for (int mi = 0; mi < 4; ++mi) fa1[mi] = dsr128o(aA0, (4 + mi) * 2048);

            // cluster 0: acc[0:4] x fb0 (needs ops 1-8), laddered per mi
            __builtin_amdgcn_s_setprio(1);
            LGKM(7); SB0();
            #pragma unroll
            for (int ni = 0; ni < 4; ++ni)
                acc[0][ni] = __builtin_amdgcn_mfma_f32_16x16x32_bf16(fa0[0], fb0[ni], acc[0][ni], 0, 0, 0);
            LGKM(6); SB0();
            #pragma unroll
            for (int ni = 0; ni < 4; ++ni)
                acc[1][ni] = __builtin_amdgcn_mfma_f32_16x16x32_bf16(fa0[1], fb0[ni], acc[1][ni], 0, 0, 0);
            LGKM(5); SB0();
            #pragma unroll
            for (int ni = 0; ni < 4; ++ni)
                acc[2][ni] = __builtin_amdgcn_mfma_f32_16x16x32_bf16(fa0[2], fb0[ni], acc[2][ni], 0, 0, 0);
            LGKM(4); SB0();
            #pragma unroll
            for (int ni = 0; ni < 4; ++ni)
                acc[3][ni] = __builtin_amdgcn_mfma_f32_16x16x32_bf16(fa0[3], fb0[ni], acc[3][ni], 0, 0, 0);
            __builtin_amdgcn_s_setprio(0);

            // issue fb1 (13-16), fa0' (17-20)  -- execute under cluster-0/1 MFMA
            #pragma unroll
            for (int ni = 0; ni < 4; ++ni) fb1[ni] = dsr128o(aB1, ni * 2048);
            #pragma unroll
            for (int mi = 0; mi < 4; ++mi) fa0[mi] = dsr128o(aA1, mi * 2048);

            // cluster 1: acc[4:8] x fb0 (needs fa1 = ops 9-12), laddered
            __builtin_amdgcn_s_setprio(1);
            LGKM(11); SB0();
            #pragma unroll
            for (int ni = 0; ni < 4; ++ni)
                acc[4][ni] = __builtin_amdgcn_mfma_f32_16x16x32_bf16(fa1[0], fb0[ni], acc[4][ni], 0, 0, 0);
            LGKM(10); SB0();
            #pragma unroll
            for (int ni = 0; ni < 4; ++ni)
                acc[5][ni] = __builtin_amdgcn_mfma_f32_16x16x32_bf16(fa1[1], fb0[ni], acc[5][ni], 0, 0, 0);
            LGKM(9); SB0();
            #pragma unroll
            for (int ni = 0; ni < 4; ++ni)
                acc[6][ni] = __builtin_amdgcn_mfma_f32_16x16x32_bf16(fa1[2], fb0[ni], acc[6][ni], 0, 0, 0);
            LGKM(8); SB0();
            #pragma unroll
            for (int ni = 0; ni < 4; ++ni)
                acc[7][ni] = __builtin_amdgcn_mfma_f32_16x16x32_bf16(fa1[3], fb0[ni], acc[7][ni], 0, 0, 0);
            __builtin_amdgcn_s_setprio(0);

            // issue fa1' (21-24)
            #pragma unroll
            for (int mi = 0; mi < 4; ++mi) fa1[mi] = dsr128o(aA1, (4 + mi) * 2048);

            // cluster 2: acc[0:4] x fb1 (needs ops 13-20), laddered
            __builtin_amdgcn_s_setprio(1);
            LGKM(7); SB0();
            #pragma unroll
            for (int ni = 0; ni < 4; ++ni)
                acc[0][ni] = __builtin_amdgcn_mfma_f32_16x16x32_bf16(fa0[0], fb1[ni], acc[0][ni], 0, 0, 0);
            LGKM(6); SB0();
            #pragma unroll
            for (int ni = 0; ni < 4; ++ni)
                acc[1][ni] = __builtin_amdgcn_mfma_f32_16x16x32_bf16(fa0[1], fb1[ni], acc[1][ni], 0, 0, 0);
            LGKM(5); SB0();
            #pragma unroll
            for (int ni = 0; ni < 4; ++ni)
                acc[2][ni] = __builtin_amdgcn_mfma_f32_16x16x32_bf16(fa0[2], fb1[ni], acc[2][ni], 0, 0, 0);
            LGKM(4); SB0();
            #pragma unroll
            for (int ni = 0; ni < 4; ++ni)
                acc[3][ni] = __builtin_amdgcn_mfma_f32_16x16x32_bf16(fa0[3], fb1[ni], acc[3][ni], 0, 0, 0);

            // cluster 3: acc[4:8] x fb1 (needs ops 21-24), laddered
            LGKM(3); SB0();
            #pragma unroll
            for (int ni = 0; ni < 4; ++ni)
                acc[4][ni] = __builtin_amdgcn_mfma_f32_16x16x32_bf16(fa1[0], fb1[ni], acc[4][ni], 0, 0, 0);
            LGKM(2); SB0();
            #pragma unroll
            for (int ni = 0; ni < 4; ++ni)
                acc[5][ni] = __builtin_amdgcn_mfma_f32_16x16x32_bf16(fa1[1], fb1[ni], acc[5][ni], 0, 0, 0);
            LGKM(1); SB0();
            #pragma unroll
            for (int ni = 0; ni < 4; ++ni)
                acc[6][ni] = __builtin_amdgcn_mfma_f32_16x16x32_bf16(fa1[2], fb1[ni], acc[6][ni], 0, 0, 0);
            LGKM(0); SB0();
            #pragma unroll
            for (int ni = 0; ni < 4; ++ni)
                acc[7][ni] = __builtin_amdgcn_mfma_f32_16x16x32_bf16(fa1[3], fb1[ni], acc[7][ni], 0, 0, 0);
            __builtin_amdgcn_s_setprio(0);

            // tile boundary: own tile-t+1 loads drained (aged a full tile), then publish.
            if (t + 1 < NT){
                VMCNT(0);
                __builtin_amdgcn_s_barrier();
            }
        }
        // inter-segment: next prologue's VMCNT(0)+barrier is the rendezvous; buffer
        // written next (buf0) had its reads complete before the last boundary barrier.
    }

    // epilogue (direct stores): C/D mapping col=lane&15, row=quad*4+reg
    #pragma unroll
    for (int ni = 0; ni < 4; ++ni){
        const int col = bn + wc * 64 + ni * 16 + l15;
        float bb = 0.f;
        if (bias0) bb += bias0[col];
        if (bias1) bb += bias1[col];
        #pragma unroll
        for (int mi = 0; mi < 8; ++mi){
            #pragma unroll
            for (int r = 0; r < 4; ++r){
                const int row = bm + wr * 128 + mi * 16 + quad * 4 + r;
                float v = acc[mi][ni][r] + bb;
                if (act == 2) v = mish_act(v);
                if (out_bf16) ((unsigned short*)Y)[(size_t)row * N + col] = f2bf(v);
                else          ((float*)Y)[(size_t)row * N + col] = v;
            }
        }
    }
}

// ---------------- segmented scan, pass A (one-shot LDS chunk load, barrier-free loop) ----
__global__ __launch_bounds__(256) void scan_passA(
    const float* __restrict__ kbuf, const float* __restrict__ vbuf,
    const int* __restrict__ start,
    float* __restrict__ chunkS, float* __restrict__ chunkZ, int* __restrict__ chunkFlag)
{
    const int c   = blockIdx.x;
    const int tid = threadIdx.x;
    const int j   = tid >> 2;
    const int i0  = (tid & 3) * 16;
    __shared__ float k_lds[CLEN][64], v_lds[CLEN][64];
    __shared__ int   st_lds[CLEN];
    // one-shot chunk load: 16 rows x 64 floats = 256 float4 (coalesced)
    ((float4*)&k_lds[0][0])[tid] = ((const float4*)(kbuf + (size_t)c * CLEN * K_DIM))[tid];
    ((float4*)&v_lds[0][0])[tid] = ((const float4*)(vbuf + (size_t)c * CLEN * V_DIM))[tid];
    if (tid < CLEN) st_lds[tid] = start[c * CLEN + tid];
    __syncthreads();

    float s_loc[16];
    #pragma unroll
    for (int e = 0; e < 16; ++e) s_loc[e] = 0.f;
    float z_loc = 0.f;
    int flag = 0;
    for (int tt = 0; tt < CLEN; ++tt){
        if (st_lds[tt]){
            #pragma unroll
            for (int e = 0; e < 16; ++e) s_loc[e] = 0.f;
            z_loc = 0.f;
            flag = 1;
        }
        const float vj = v_lds[tt][j];
        #pragma unroll
        for (int e = 0; e < 16; ++e) s_loc[e] += k_lds[tt][i0 + e] * vj;
        if (tid < 64) z_loc += k_lds[tt][tid];
    }
    #pragma unroll
    for (int e = 0; e < 16; ++e) chunkS[(size_t)c*4096 + (i0 + e)*64 + j] = s_loc[e];
    if (tid < 64) chunkZ[c*64 + tid] = z_loc;
    if (tid == 0) chunkFlag[c] = flag;
}

// ---------------- pass B: exclusive cross-chunk combine (64 blocks x 64 thr) ----------------
__global__ __launch_bounds__(64) void scan_passB(
    const float* __restrict__ chunkS, const float* __restrict__ chunkZ, const int* __restrict__ chunkFlag,
    const float* __restrict__ s0, const float* __restrict__ z0,
    float* __restrict__ carryS, float* __restrict__ carryZ)
{
    const int ij = blockIdx.x * 64 + threadIdx.x;
    float e = s0[ij];
    for (int c = 0; c < CHUNKS; ++c){
        carryS[(size_t)c*4096 + ij] = e;
        const int f   = chunkFlag[c];
        const float s = chunkS[(size_t)c*4096 + ij];
        e = f ? s : (e + s);
    }
    if (ij < 64){
        float ez = z0[ij];
        for (int c = 0; c < CHUNKS; ++c){
            carryZ[c*64 + ij] = ez;
            const int f   = chunkFlag[c];
            const float z = chunkZ[c*64 + ij];
            ez = f ? z : (ez + z);
        }
    }
}

// ---------------- pass C: replay with carry (one-shot LDS chunk load); emit s,z,att ----
__global__ __launch_bounds__(256) void scan_passC(
    const float* __restrict__ kbuf, const float* __restrict__ vbuf, const float* __restrict__ qbuf,
    const int* __restrict__ start,
    const float* __restrict__ carryS, const float* __restrict__ carryZ,
    float* __restrict__ s_out, float* __restrict__ z_out, unsigned short* __restrict__ attout)
{
    const int c   = blockIdx.x;
    const int tid = threadIdx.x;
    const int j   = tid >> 2;
    const int g   = tid & 3;
    const int i0  = g * 16;
    __shared__ float k_lds[CLEN][64], v_lds[CLEN][64], q_lds[CLEN][64];
    __shared__ int   st_lds[CLEN];
    __shared__ float numer_lds[64];
    __shared__ float stage[4096];
    // one-shot chunk load
    ((float4*)&k_lds[0][0])[tid] = ((const float4*)(kbuf + (size_t)c * CLEN * K_DIM))[tid];
    ((float4*)&v_lds[0][0])[tid] = ((const float4*)(vbuf + (size_t)c * CLEN * V_DIM))[tid];
    ((float4*)&q_lds[0][0])[tid] = ((const float4*)(qbuf + (size_t)c * CLEN * K_DIM))[tid];
    if (tid < CLEN) st_lds[tid] = start[c * CLEN + tid];

    float s_loc[16];
    #pragma unroll
    for (int e = 0; e < 16; ++e) s_loc[e] = carryS[(size_t)c*4096 + (i0 + e)*64 + j];
    float z_loc = (tid < 64) ? carryZ[c*64 + tid] : 0.f;
    __syncthreads();

    const int t0 = c * CLEN;
    for (int tt = 0; tt < CLEN; ++tt){
        const int t  = t0 + tt;
        const int st = st_lds[tt];
        if (st){
            #pragma unroll
            for (int e = 0; e < 16; ++e) s_loc[e] = 0.f;
        }
        const float vj = v_lds[tt][j];
        float np = 0.f;
        #pragma unroll
        for (int e = 0; e < 16; ++e){
            s_loc[e] += k_lds[tt][i0 + e] * vj;
            np += s_loc[e] * q_lds[tt][i0 + e];
        }
        np += __shfl_down(np, 1, 64);
        np += __shfl_down(np, 2, 64);
        if (g == 0) numer_lds[j] = np;
        float denom = 1.f;
        if (tid < 64){
            z_loc = (st ? 0.f : z_loc) + k_lds[tt][tid];
            z_out[(size_t)t*K_DIM + tid] = z_loc;
            float zs = z_loc;
            float qs = q_lds[tt][tid];
            #pragma unroll
            for (int o = 32; o > 0; o >>= 1){
                zs += __shfl_down(zs, o, 64);
                qs += __shfl_down(qs, o, 64);
            }
            zs = __shfl(zs, 0, 64);
            qs = __shfl(qs, 0, 64);
            denom = fmaxf(zs * qs, 1e-6f);
        }
        #pragma unroll
        for (int e = 0; e < 16; ++e) stage[(i0 + e)*64 + j] = s_loc[e];
        __syncthreads();
        float4* so = (float4*)(s_out + (size_t)t*4096);
        const float4* stv = (const float4*)stage;
        #pragma unroll
        for (int r = 0; r < 4; ++r) so[tid + 256*r] = stv[tid + 256*r];
        if (tid < 64) attout[(size_t)t*V_DIM + tid] = f2bf(numer_lds[tid] / denom);
        __syncthreads();
    }
}

// ---------------- LayerNorm over H=4096, in place ----------------
__global__ __launch_bounds__(256) void ln_kernel(
    float* __restrict__ h, const float* __restrict__ g, const float* __restrict__ b)
{
    __shared__ float sm[4];
    const int t   = blockIdx.x;
    const int tid = threadIdx.x;
    float* row = h + (size_t)t * H_DIM;
    float4 v[4];
    float s = 0.f;
    #pragma unroll
    for (int r = 0; r < 4; ++r){
        v[r] = ((const float4*)row)[tid + 256*r];
        s += v[r].x + v[r].y + v[r].z + v[r].w;
    }
    #pragma unroll
    for (int o = 32; o > 0; o >>= 1) s += __shfl_down(s, o, 64);
    if ((tid & 63) == 0) sm[tid >> 6] = s;
    __syncthreads();
    const float mu = (sm[0] + sm[1] + sm[2] + sm[3]) * (1.f / H_DIM);
    __syncthreads();
    float sq = 0.f;
    #pragma unroll
    for (int r = 0; r < 4; ++r){
        float dx = v[r].x - mu, dy = v[r].y - mu, dz = v[r].z - mu, dw = v[r].w - mu;
        sq += dx*dx + dy*dy + dz*dz + dw*dw;
    }
    #pragma unroll
    for (int o = 32; o > 0; o >>= 1) sq += __shfl_down(sq, o, 64);
    if ((tid & 63) == 0) sm[tid >> 6] = sq;
    __syncthreads();
    const float var = (sm[0] + sm[1] + sm[2] + sm[3]) * (1.f / H_DIM);
    const float inv = rsqrtf(var + 1e-5f);
    #pragma unroll
    for (int r = 0; r < 4; ++r){
        const int i4 = tid + 256*r;
        const float4 gg = ((const float4*)g)[i4];
        const float4 bb = ((const float4*)b)[i4];
        float4 o;
        o.x = (v[r].x - mu) * inv * gg.x + bb.x;
        o.y = (v[r].y - mu) * inv * gg.y + bb.y;
        o.z = (v[r].z - mu) * inv * gg.z + bb.z;
        o.w = (v[r].w - mu) * inv * gg.w + bb.w;
        ((float4*)row)[i4] = o;
    }
}

extern "C" void kernel_launch(void* const* d_in, const int* in_sizes, int n_in,
                              void* d_out, int out_size, void* d_ws, size_t ws_size,
                              hipStream_t stream)
{
    (void)in_sizes; (void)n_in; (void)out_size; (void)ws_size;
    const float* x     = (const float*)d_in[0];
    const float* s0    = (const float*)d_in[1];
    const float* z0    = (const float*)d_in[2];
    const int*   start = (const int*)d_in[3];
    const float* Wk    = (const float*)d_in[5];
    const float* Wq    = (const float*)d_in[6];
    const float* Wv    = (const float*)d_in[7];
    const float* bv    = (const float*)d_in[8];
    const float* Wskip = (const float*)d_in[9];
    const float* bskip = (const float*)d_in[10];
    const float* W1    = (const float*)d_in[11];
    const float* b1    = (const float*)d_in[12];
    const float* W2    = (const float*)d_in[13];
    const float* b2    = (const float*)d_in[14];
    const float* W3    = (const float*)d_in[15];
    const float* b3    = (const float*)d_in[16];
    const float* ln_g  = (const float*)d_in[17];
    const float* ln_b  = (const float*)d_in[18];

    // ---- workspace carve (256B-aligned), total ~148 MB ----
    char* p = (char*)d_ws;
    auto alloc = [&](size_t bytes) -> void* {
        void* r = (void*)p; p += (bytes + 255) & ~(size_t)255; return r;
    };
    float* kbuf  = (float*)alloc((size_t)T_DIM * K_DIM * 4);
    float* qbuf  = (float*)alloc((size_t)T_DIM * K_DIM * 4);
    float* vbuf  = (float*)alloc((size_t)T_DIM * V_DIM * 4);
    float* chS   = (float*)alloc((size_t)CHUNKS * 4096 * 4);
    float* chZ   = (float*)alloc((size_t)CHUNKS * 64 * 4);
    float* caS   = (float*)alloc((size_t)CHUNKS * 4096 * 4);
    float* caZ   = (float*)alloc((size_t)CHUNKS * 64 * 4);
    int*   flags = (int*)  alloc((size_t)CHUNKS * 4);
    unsigned short* xb     = (unsigned short*)alloc((size_t)T_DIM * IN_DIM * 2);
    unsigned short* Wskipb = (unsigned short*)alloc((size_t)H_DIM * IN_DIM * 2);
    unsigned short* W1b    = (unsigned short*)alloc((size_t)H_DIM * V_DIM * 2);
    unsigned short* W2b    = (unsigned short*)alloc((size_t)H_DIM * H_DIM * 2);
    unsigned short* W3b    = (unsigned short*)alloc((size_t)H_DIM * H_DIM * 2);
    unsigned short* attb   = (unsigned short*)alloc((size_t)T_DIM * V_DIM * 2);
    unsigned short* h1b    = (unsigned short*)alloc((size_t)T_DIM * H_DIM * 2);
    unsigned short* h2b    = (unsigned short*)alloc((size_t)T_DIM * H_DIM * 2);

    float* hn  = (float*)d_out;                          // (T,H)
    float* s_o = hn  + (size_t)T_DIM * H_DIM;            // (T,K,V)
    float* z_o = s_o + (size_t)T_DIM * K_DIM * V_DIM;    // (T,1,K)

    // 0) prep: 3 projections + 5 bf16 conversions in ONE dispatch
    prep_kernel<<<2048, 256, 0, stream>>>(x, Wk, Wq, Wv, bv, kbuf, qbuf, vbuf,
                                          Wskip, W1, W2, W3, xb, Wskipb, W1b, W2b, W3b);

    // 1) segmented scan (3 ordinary dispatches; cooperative launch is NOT graph-capturable)
    scan_passA<<<CHUNKS, 256, 0, stream>>>(kbuf, vbuf, start, chS, chZ, flags);
    scan_passB<<<64, 64, 0, stream>>>(chS, chZ, flags, s0, z0, caS, caZ);
    scan_passC<<<CHUNKS, 256, 0, stream>>>(kbuf, vbuf, qbuf, start, caS, caZ, s_o, z_o, attb);

    // 2) MLP: all three GEMMs on the wave-pipelined 256^2 kernel
    gemm256p<<<dim3(16, 16), 512, 0, stream>>>(
        attb, W1b, K_DIM, nullptr, nullptr, 0, b1, nullptr, h1b, H_DIM, 2, 1);
    gemm256p<<<dim3(16, 16), 512, 0, stream>>>(
        h1b, W2b, H_DIM, nullptr, nullptr, 0, b2, nullptr, h2b, H_DIM, 2, 1);
    // GEMM3 fused with skip: hn = h2@W3^T + x@Wskip^T + b3 + bskip (fp32 out)
    gemm256p<<<dim3(16, 16), 512, 0, stream>>>(
        h2b, W3b, H_DIM, xb, Wskipb, IN_DIM, b3, bskip, hn, H_DIM, 0, 0);

    // 3) LayerNorm in place on d_out
    ln_kernel<<<T_DIM, 256, 0, stream>>>(hn, ln_g, ln_b);
}